// Round 1
// baseline (1577.571 us; speedup 1.0000x reference)
//
#include <hip/hip_runtime.h>
#include <math.h>

#define EPSV 1e-5
#define SLOPE 0.1f

__device__ __forceinline__ float lrelu(float x){ return x >= 0.f ? x : SLOPE * x; }

// ---------------- direct 3x3 conv, pad=1 ----------------
template<int CI, int CO, int STRIDE, bool TANH>
__global__ __launch_bounds__(256) void conv3x3(const float* __restrict__ in, const float* __restrict__ w,
    const float* __restrict__ bias, float* __restrict__ out,
    int N, int IH, int IW, int OH, int OW){
  int idx = blockIdx.x * 256 + threadIdx.x;
  int total = N * CO * OH * OW;
  if (idx >= total) return;
  int ox = idx % OW;
  int oy = (idx / OW) % OH;
  int co = (idx / (OW * OH)) % CO;
  int n  = idx / (OW * OH * CO);
  // OW*OH is a multiple of 64 for every call site -> co,n wave-uniform
  co = __builtin_amdgcn_readfirstlane(co);
  n  = __builtin_amdgcn_readfirstlane(n);
  float acc = bias[co];
  const float* wp = w + co * CI * 9;
  #pragma unroll
  for (int ky = 0; ky < 3; ky++){
    int iy = oy * STRIDE - 1 + ky;
    if (iy < 0 || iy >= IH) continue;
    #pragma unroll
    for (int kx = 0; kx < 3; kx++){
      int ix = ox * STRIDE - 1 + kx;
      if (ix < 0 || ix >= IW) continue;
      #pragma unroll
      for (int ci = 0; ci < CI; ci++){
        acc = fmaf(in[(((size_t)n * CI + ci) * IH + iy) * IW + ix], wp[(ci * 3 + ky) * 3 + kx], acc);
      }
    }
  }
  if (TANH) acc = tanhf(acc);
  out[idx] = acc;
}

// ---------------- 3x3 conv, channel-fastest output (z layout: [pos][co]) ----------------
template<int CI, int CO>
__global__ __launch_bounds__(256) void conv3x3_cfast(const float* __restrict__ in, const float* __restrict__ w,
    const float* __restrict__ bias, float* __restrict__ out, int N, int H, int W){
  int idx = blockIdx.x * 256 + threadIdx.x;  // = sp*CO + co
  int total = N * H * W * CO;
  if (idx >= total) return;
  int co = idx % CO;           // CO==64 -> sp wave-uniform
  int sp = idx / CO;
  sp = __builtin_amdgcn_readfirstlane(sp);
  int x = sp % W; int y = (sp / W) % H; int n = sp / (W * H);
  float acc = bias[co];
  #pragma unroll
  for (int ky = 0; ky < 3; ky++){
    int iy = y - 1 + ky; if (iy < 0 || iy >= H) continue;
    #pragma unroll
    for (int kx = 0; kx < 3; kx++){
      int ix = x - 1 + kx; if (ix < 0 || ix >= W) continue;
      #pragma unroll
      for (int ci = 0; ci < CI; ci++){
        acc = fmaf(in[(((size_t)n * CI + ci) * H + iy) * W + ix], w[((co * CI + ci) * 3 + ky) * 3 + kx], acc);
      }
    }
  }
  out[idx] = acc;
}

// ---------------- postq conv: input gathered from codebook via idx ----------------
__global__ __launch_bounds__(256) void postq_conv(const float* __restrict__ cb, const int* __restrict__ idxmap,
    const float* __restrict__ w, const float* __restrict__ bias, float* __restrict__ out, int N, int H, int W){
  int idx = blockIdx.x * 256 + threadIdx.x;
  int total = N * 4 * H * W;
  if (idx >= total) return;
  int x = idx % W; int y = (idx / W) % H; int co = (idx / (W * H)) % 4; int n = idx / (W * H * 4);
  co = __builtin_amdgcn_readfirstlane(co);
  n  = __builtin_amdgcn_readfirstlane(n);
  float acc = bias[co];
  #pragma unroll
  for (int ky = 0; ky < 3; ky++){
    int iy = y - 1 + ky; if (iy < 0 || iy >= H) continue;
    #pragma unroll
    for (int kx = 0; kx < 3; kx++){
      int ix = x - 1 + kx; if (ix < 0 || ix >= W) continue;
      int code = idxmap[(n * H + iy) * W + ix];
      const float* cp = cb + (size_t)code * 64;
      const float* wp = w + (size_t)co * 64 * 9 + ky * 3 + kx;
      #pragma unroll
      for (int ci = 0; ci < 64; ci++) acc = fmaf(cp[ci], wp[ci * 9], acc);
    }
  }
  out[idx] = acc;
}

// ---------------- transposed conv k=3 s=2 p=1 outpad=1 (direct gather) ----------------
template<int CI, int CO>
__global__ __launch_bounds__(256) void convT3x3s2(const float* __restrict__ in, const float* __restrict__ w,
    const float* __restrict__ bias, float* __restrict__ out, int N, int IH, int IW){
  int OH = IH * 2, OW = IW * 2;
  int idx = blockIdx.x * 256 + threadIdx.x;
  int total = N * CO * OH * OW;
  if (idx >= total) return;
  int ox = idx % OW; int oy = (idx / OW) % OH; int co = (idx / (OW * OH)) % CO; int n = idx / (OW * OH * CO);
  co = __builtin_amdgcn_readfirstlane(co);
  n  = __builtin_amdgcn_readfirstlane(n);
  float acc = bias[co];
  #pragma unroll
  for (int ky = 0; ky < 3; ky++){
    int t = oy + 1 - ky; if (t & 1) continue; int iy = t >> 1; if (iy < 0 || iy >= IH) continue;
    #pragma unroll
    for (int kx = 0; kx < 3; kx++){
      int s = ox + 1 - kx; if (s & 1) continue; int ix = s >> 1; if (ix < 0 || ix >= IW) continue;
      #pragma unroll
      for (int ci = 0; ci < CI; ci++){
        acc = fmaf(in[(((size_t)n * CI + ci) * IH + iy) * IW + ix], w[((ci * CO + co) * 3 + ky) * 3 + kx], acc);
      }
    }
  }
  out[idx] = acc;
}

// ---------------- BN batch-stats: per-channel sum & sumsq (f64 partials + atomics) ----------------
__global__ __launch_bounds__(256) void bn_stats(const float* __restrict__ x, double* __restrict__ sums,
    int C, int HW, int N, int slabs){
  int c = blockIdx.x / slabs, s = blockIdx.x % slabs;
  double ls = 0, lq = 0;
  for (int n = 0; n < N; n++){
    const float* p = x + ((size_t)n * C + c) * HW;
    for (int i = s * 256 + threadIdx.x; i < HW; i += slabs * 256){
      float v = p[i];
      ls += (double)v;
      lq = fma((double)v, (double)v, lq);
    }
  }
  __shared__ double r0[256], r1[256];
  int t = threadIdx.x;
  r0[t] = ls; r1[t] = lq; __syncthreads();
  for (int o = 128; o > 0; o >>= 1){
    if (t < o){ r0[t] += r0[t + o]; r1[t] += r1[t + o]; }
    __syncthreads();
  }
  if (t == 0){ atomicAdd(&sums[c], r0[0]); atomicAdd(&sums[C + c], r1[0]); }
}

__global__ void bn_finalize(const double* __restrict__ sums, const float* __restrict__ g, const float* __restrict__ b,
    float* __restrict__ ss, int C, double count){
  int c = threadIdx.x;
  if (c >= C) return;
  double m = sums[c] / count;
  double var = sums[C + c] / count - m * m;
  double scale = (double)g[c] / sqrt(var + EPSV);
  ss[c] = (float)scale;
  ss[C + c] = (float)((double)b[c] - m * scale);
}

__global__ __launch_bounds__(256) void bn_apply_lrelu(float* __restrict__ x, const float* __restrict__ ss,
    int C, int HW, size_t total){
  size_t i = (size_t)blockIdx.x * 256 + threadIdx.x;
  if (i >= total) return;
  int c = (int)((i / (size_t)HW) % (size_t)C);
  float y = fmaf(x[i], ss[c], ss[C + c]);
  x[i] = lrelu(y);
}

// ---------------- VQ: codebook prep (f64 copy + norms) ----------------
__global__ void vq_prep(const float* __restrict__ cb, double* __restrict__ cb64, double* __restrict__ cbn){
  int k = blockIdx.x * 256 + threadIdx.x;
  if (k >= 1024) return;
  double s = 0;
  for (int d = 0; d < 64; d++){
    double v = (double)cb[k * 64 + d];
    cb64[(size_t)k * 64 + d] = v;
    s = fma(v, v, s);
  }
  cbn[k] = s;
}

// ---------------- VQ argmin (exact f64 scores) + loss accumulation ----------------
// block: 256 threads = 128 positions x 2 code-halves
__global__ __launch_bounds__(256) void vq_argmin(const float* __restrict__ z, const double* __restrict__ cb64,
    const double* __restrict__ cbn, int* __restrict__ idxout, double* __restrict__ lossacc){
  int t = threadIdx.x;
  int half = __builtin_amdgcn_readfirstlane(t >> 7);  // wave-uniform
  int p = t & 127;
  int pos = blockIdx.x * 128 + p;
  const float4* zp4 = (const float4*)(z + (size_t)pos * 64);
  double zd[64];
  #pragma unroll
  for (int j = 0; j < 16; j++){
    float4 v = zp4[j];
    zd[4 * j + 0] = (double)v.x; zd[4 * j + 1] = (double)v.y;
    zd[4 * j + 2] = (double)v.z; zd[4 * j + 3] = (double)v.w;
  }
  double best = 1e300; int bidx = 0;
  int k0 = half * 512;
  for (int k = k0; k < k0 + 512; k++){
    const double* c = cb64 + (size_t)k * 64;   // wave-uniform address -> scalar loads
    double a0 = 0, a1 = 0, a2 = 0, a3 = 0;
    #pragma unroll
    for (int d = 0; d < 64; d += 4){
      a0 = fma(c[d + 0], zd[d + 0], a0);
      a1 = fma(c[d + 1], zd[d + 1], a1);
      a2 = fma(c[d + 2], zd[d + 2], a2);
      a3 = fma(c[d + 3], zd[d + 3], a3);
    }
    double score = cbn[k] - 2.0 * ((a0 + a1) + (a2 + a3));  // == dist - ||z||^2, exact to ~1e-14
    if (score < best){ best = score; bidx = k; }
  }
  __shared__ double sb[256];
  __shared__ int si[256];
  sb[t] = best; si[t] = bidx;
  __syncthreads();
  double l = 0;
  if (half == 0){
    double ob = sb[t + 128]; int oi = si[t + 128];
    if (ob < best){ best = ob; bidx = oi; }   // strict < : ties keep lower index (first-min semantics)
    idxout[pos] = bidx;
    const double* c = cb64 + (size_t)bidx * 64;
    #pragma unroll
    for (int d = 0; d < 64; d++){
      double dz = zd[d] - c[d];
      l = fma(dz, dz, l);
    }
  }
  __syncthreads();
  sb[t] = l;
  __syncthreads();
  for (int o = 128; o > 0; o >>= 1){
    if (t < o) sb[t] += sb[t + o];
    __syncthreads();
  }
  if (t == 0) atomicAdd(lossacc, sb[0]);
}

__global__ void write_loss(const double* __restrict__ lossacc, float* __restrict__ out){
  out[0] = (float)(1.25 * lossacc[0] / (65536.0 * 64.0));
}

// ---------------- launch ----------------
extern "C" void kernel_launch(void* const* d_in, const int* in_sizes, int n_in,
                              void* d_out, int out_size, void* d_ws, size_t ws_size,
                              hipStream_t stream){
  const float* x      = (const float*)d_in[0];
  const float* cb     = (const float*)d_in[1];
  const float* e1_w   = (const float*)d_in[2];
  const float* e1_b   = (const float*)d_in[3];
  const float* bn1_g  = (const float*)d_in[4];
  const float* bn1_b  = (const float*)d_in[5];
  const float* e2_w   = (const float*)d_in[6];
  const float* e2_b   = (const float*)d_in[7];
  const float* bn2_g  = (const float*)d_in[8];
  const float* bn2_b  = (const float*)d_in[9];
  const float* preq_w = (const float*)d_in[10];
  const float* preq_b = (const float*)d_in[11];
  const float* postq_w= (const float*)d_in[12];
  const float* postq_b= (const float*)d_in[13];
  const float* d1_w   = (const float*)d_in[14];
  const float* d1_b   = (const float*)d_in[15];
  const float* bn3_g  = (const float*)d_in[16];
  const float* bn3_b  = (const float*)d_in[17];
  const float* d2_w   = (const float*)d_in[18];
  const float* d2_b   = (const float*)d_in[19];
  const float* bn4_g  = (const float*)d_in[20];
  const float* bn4_b  = (const float*)d_in[21];
  const float* d3_w   = (const float*)d_in[22];
  const float* d3_b   = (const float*)d_in[23];
  float* out = (float*)d_out;
  char* ws = (char*)d_ws;

  // workspace layout (offsets bytes)
  double* stats = (double*)ws;                         // 137 doubles (zeroed)
  float*  ss    = (float*)(ws + 2048);                 // per-BN scale/shift
  double* cb64  = (double*)(ws + 4096);                // 1024*64 f64
  double* cbn   = (double*)(ws + 4096 + 524288);       // 1024 f64
  int*    idx   = (int*)(ws + 536576);                 // 65536 int
  float*  A     = (float*)(ws + 798720);               // 16x16x128x128 (conv1/act1, reused for d1 out)
  float*  B     = (float*)(ws + 17575936);             // 16x4x64x64
  float*  Z     = (float*)(ws + 18624512);             // 65536x64 (pos-major)
  float*  D     = (float*)(ws + 35401728);             // 16x4x64x64 (postq out)
  float*  F     = (float*)(ws + 36450304);             // 16x32x256x256 (d2 out)

  double* sum1 = stats + 0;    // 32 doubles (sum16, sq16)
  double* sum2 = stats + 32;   // 8
  double* sum3 = stats + 40;   // 32
  double* sum4 = stats + 72;   // 64
  double* lossacc = stats + 136;
  float *ss1 = ss + 0, *ss2 = ss + 32, *ss3 = ss + 40, *ss4 = ss + 72;

  hipMemsetAsync(stats, 0, 2048, stream);
  vq_prep<<<4, 256, 0, stream>>>(cb, cb64, cbn);

  // encoder
  conv3x3<3, 16, 2, false><<<16384, 256, 0, stream>>>(x, e1_w, e1_b, A, 16, 256, 256, 128, 128);
  bn_stats<<<256, 256, 0, stream>>>(A, sum1, 16, 16384, 16, 16);
  bn_finalize<<<1, 32, 0, stream>>>(sum1, bn1_g, bn1_b, ss1, 16, 16.0 * 16384);
  bn_apply_lrelu<<<16384, 256, 0, stream>>>(A, ss1, 16, 16384, (size_t)4194304);

  conv3x3<16, 4, 2, false><<<1024, 256, 0, stream>>>(A, e2_w, e2_b, B, 16, 128, 128, 64, 64);
  bn_stats<<<64, 256, 0, stream>>>(B, sum2, 4, 4096, 16, 16);
  bn_finalize<<<1, 32, 0, stream>>>(sum2, bn2_g, bn2_b, ss2, 4, 16.0 * 4096);
  bn_apply_lrelu<<<1024, 256, 0, stream>>>(B, ss2, 4, 4096, (size_t)262144);

  conv3x3_cfast<4, 64><<<16384, 256, 0, stream>>>(B, preq_w, preq_b, Z, 16, 64, 64);

  // VQ
  vq_argmin<<<512, 256, 0, stream>>>(Z, cb64, cbn, idx, lossacc);

  // decoder
  postq_conv<<<1024, 256, 0, stream>>>(cb, idx, postq_w, postq_b, D, 16, 64, 64);

  convT3x3s2<4, 16><<<16384, 256, 0, stream>>>(D, d1_w, d1_b, A, 16, 64, 64);
  bn_stats<<<256, 256, 0, stream>>>(A, sum3, 16, 16384, 16, 16);
  bn_finalize<<<1, 32, 0, stream>>>(sum3, bn3_g, bn3_b, ss3, 16, 16.0 * 16384);
  bn_apply_lrelu<<<16384, 256, 0, stream>>>(A, ss3, 16, 16384, (size_t)4194304);

  convT3x3s2<16, 32><<<131072, 256, 0, stream>>>(A, d2_w, d2_b, F, 16, 128, 128);
  bn_stats<<<2048, 256, 0, stream>>>(F, sum4, 32, 65536, 16, 64);
  bn_finalize<<<1, 32, 0, stream>>>(sum4, bn4_g, bn4_b, ss4, 32, 16.0 * 65536);
  bn_apply_lrelu<<<131072, 256, 0, stream>>>(F, ss4, 32, 65536, (size_t)33554432);

  conv3x3<32, 3, 1, true><<<12288, 256, 0, stream>>>(F, d3_w, d3_b, out, 16, 256, 256, 256, 256);

  write_loss<<<1, 1, 0, stream>>>(lossacc, out + 3145728);
}

// Round 2
// 1577.234 us; speedup vs baseline: 1.0002x; 1.0002x over previous
//
#include <hip/hip_runtime.h>
#include <math.h>

#define EPSV 1e-5
#define SLOPE 0.1f

__device__ __forceinline__ float lrelu(float x){ return x >= 0.f ? x : SLOPE * x; }

// ---------------- co-batched direct 3x3 conv: thread = (n,oy,ox), computes all CO ----------------
template<int CI, int CO, int S, bool TANH>
__global__ __launch_bounds__(256) void conv_cobatch(const float* __restrict__ in, const float* __restrict__ w,
    const float* __restrict__ bias, float* __restrict__ out, int N, int IH, int IW, int OH, int OW){
  int idx = blockIdx.x * 256 + threadIdx.x;
  int total = N * OH * OW;
  if (idx >= total) return;
  int ox = idx % OW, oy = (idx / OW) % OH, n = idx / (OW * OH);
  float acc[CO];
  #pragma unroll
  for (int j = 0; j < CO; j++) acc[j] = bias[j];
  int iy0 = oy * S - 1, ix0 = ox * S - 1;
  const float* ip = in + (size_t)n * CI * IH * IW;
  if (iy0 >= 0 && iy0 <= IH - 3 && ix0 >= 0 && ix0 <= IW - 3){
    #pragma unroll
    for (int ky = 0; ky < 3; ky++){
      #pragma unroll
      for (int kx = 0; kx < 3; kx++){
        const float* r = ip + (iy0 + ky) * IW + (ix0 + kx);
        #pragma unroll
        for (int ci = 0; ci < CI; ci++){
          float v = r[ci * IH * IW];
          #pragma unroll
          for (int co = 0; co < CO; co++)
            acc[co] = fmaf(v, w[(co * CI + ci) * 9 + ky * 3 + kx], acc[co]);
        }
      }
    }
  } else {
    #pragma unroll
    for (int ky = 0; ky < 3; ky++){
      int iy = iy0 + ky; if ((unsigned)iy >= (unsigned)IH) continue;
      #pragma unroll
      for (int kx = 0; kx < 3; kx++){
        int ix = ix0 + kx; if ((unsigned)ix >= (unsigned)IW) continue;
        const float* r = ip + iy * IW + ix;
        #pragma unroll
        for (int ci = 0; ci < CI; ci++){
          float v = r[ci * IH * IW];
          #pragma unroll
          for (int co = 0; co < CO; co++)
            acc[co] = fmaf(v, w[(co * CI + ci) * 9 + ky * 3 + kx], acc[co]);
        }
      }
    }
  }
  #pragma unroll
  for (int co = 0; co < CO; co++){
    float v = acc[co];
    if (TANH) v = tanhf(v);
    out[(((size_t)n * CO + co) * OH + oy) * OW + ox] = v;
  }
}

// ---------------- preq conv: output to plane layout Zq[coq][pos][4] ----------------
__global__ __launch_bounds__(256) void preq_conv(const float* __restrict__ in, const float* __restrict__ w,
    const float* __restrict__ bias, float* __restrict__ Zq){
  int idx = blockIdx.x * 256 + threadIdx.x;   // coq*65536 + sp
  int sp = idx & 65535;
  int coq = idx >> 16;                         // wave-uniform
  int x = sp & 63, y = (sp >> 6) & 63, n = sp >> 12;
  float a0 = bias[coq * 4 + 0], a1 = bias[coq * 4 + 1], a2 = bias[coq * 4 + 2], a3 = bias[coq * 4 + 3];
  const float* ip = in + (size_t)n * 4 * 4096;
  #pragma unroll
  for (int ky = 0; ky < 3; ky++){
    int iy = y - 1 + ky; if ((unsigned)iy >= 64u) continue;
    #pragma unroll
    for (int kx = 0; kx < 3; kx++){
      int ix = x - 1 + kx; if ((unsigned)ix >= 64u) continue;
      #pragma unroll
      for (int ci = 0; ci < 4; ci++){
        float v = ip[ci * 4096 + iy * 64 + ix];
        const float* wp = w + ((coq * 4) * 4 + ci) * 9 + ky * 3 + kx;
        a0 = fmaf(v, wp[0], a0);
        a1 = fmaf(v, wp[36], a1);
        a2 = fmaf(v, wp[72], a2);
        a3 = fmaf(v, wp[108], a3);
      }
    }
  }
  float4 o; o.x = a0; o.y = a1; o.z = a2; o.w = a3;
  ((float4*)Zq)[coq * 65536 + sp] = o;
}

// ---------------- VQ screen: f32 distances, codebook staged in LDS ----------------
__global__ __launch_bounds__(256) void vq_screen(const float* __restrict__ Zq, const float* __restrict__ cb,
    const float* __restrict__ cbn32, int* __restrict__ idxout, int* __restrict__ flagcnt, int* __restrict__ flaglist){
  __shared__ float lcb[128 * 64];
  __shared__ float lcn[128];
  int t = threadIdx.x;
  int pos = blockIdx.x * 256 + t;
  float zr[64];
  #pragma unroll
  for (int q = 0; q < 16; q++){
    float4 v = ((const float4*)Zq)[q * 65536 + pos];
    zr[4 * q] = v.x; zr[4 * q + 1] = v.y; zr[4 * q + 2] = v.z; zr[4 * q + 3] = v.w;
  }
  float best = 3.0e38f, sec = 3.0e38f; int bi = 0;
  for (int chunk = 0; chunk < 8; chunk++){
    __syncthreads();
    const float4* src = (const float4*)(cb + chunk * 8192);
    #pragma unroll
    for (int j = 0; j < 8; j++) ((float4*)lcb)[t + 256 * j] = src[t + 256 * j];
    if (t < 128) lcn[t] = cbn32[chunk * 128 + t];
    __syncthreads();
    for (int kk = 0; kk < 128; kk++){
      const float* c = lcb + (kk << 6);
      float a0 = 0.f, a1 = 0.f, a2 = 0.f, a3 = 0.f;
      #pragma unroll
      for (int d = 0; d < 64; d += 4){
        a0 = fmaf(c[d], zr[d], a0);
        a1 = fmaf(c[d + 1], zr[d + 1], a1);
        a2 = fmaf(c[d + 2], zr[d + 2], a2);
        a3 = fmaf(c[d + 3], zr[d + 3], a3);
      }
      float s = lcn[kk] - 2.f * ((a0 + a1) + (a2 + a3));
      if (s < best){ sec = best; best = s; bi = chunk * 128 + kk; }
      else if (s < sec) sec = s;
    }
  }
  idxout[pos] = bi;
  if (sec - best < 4e-3f){
    int slot = atomicAdd(flagcnt, 1);
    flaglist[slot] = pos;
  }
}

// ---------------- VQ refine: exact f64 re-rank for near-ties (one wave per position) ----------------
__global__ __launch_bounds__(256) void vq_refine(const float* __restrict__ Zq, const double* __restrict__ cb64,
    const double* __restrict__ cbn64, const int* __restrict__ flagcnt, const int* __restrict__ flaglist,
    int* __restrict__ idxout){
  int gw = (blockIdx.x * 256 + threadIdx.x) >> 6;    // global wave id, 256 waves
  int lane = threadIdx.x & 63;
  int nf = flagcnt[0];
  for (int f = gw; f < nf; f += 256){
    int pos = flaglist[f];
    float zr[64];
    #pragma unroll
    for (int q = 0; q < 16; q++){
      float4 v = ((const float4*)Zq)[q * 65536 + pos];
      zr[4 * q] = v.x; zr[4 * q + 1] = v.y; zr[4 * q + 2] = v.z; zr[4 * q + 3] = v.w;
    }
    double best = 1e300; int bi = 1 << 30;
    for (int k = lane; k < 1024; k += 64){
      const double* c = cb64 + (size_t)k * 64;
      double a0 = 0, a1 = 0, a2 = 0, a3 = 0;
      #pragma unroll
      for (int d = 0; d < 64; d += 4){
        a0 = fma(c[d], (double)zr[d], a0);
        a1 = fma(c[d + 1], (double)zr[d + 1], a1);
        a2 = fma(c[d + 2], (double)zr[d + 2], a2);
        a3 = fma(c[d + 3], (double)zr[d + 3], a3);
      }
      double s = cbn64[k] - 2.0 * ((a0 + a1) + (a2 + a3));
      if (s < best){ best = s; bi = k; }   // per-lane k ascending -> first-min
    }
    #pragma unroll
    for (int o = 32; o > 0; o >>= 1){
      double ob = __shfl_xor(best, o);
      int oi = __shfl_xor(bi, o);
      if (ob < best || (ob == best && oi < bi)){ best = ob; bi = oi; }
    }
    if (lane == 0) idxout[pos] = bi;
  }
}

// ---------------- gather q rows into plane layout + loss ----------------
__global__ __launch_bounds__(256) void vq_gather_loss(const float* __restrict__ Zq, const float* __restrict__ cb,
    const int* __restrict__ idxv, float* __restrict__ ZQq, double* __restrict__ lossacc){
  int t = threadIdx.x;
  int pos = blockIdx.x * 256 + t;
  int k = idxv[pos];
  const float4* c4 = (const float4*)(cb + (k << 6));
  double l = 0;
  #pragma unroll
  for (int q = 0; q < 16; q++){
    float4 z = ((const float4*)Zq)[q * 65536 + pos];
    float4 c = c4[q];
    ((float4*)ZQq)[q * 65536 + pos] = c;
    float d0 = z.x - c.x, d1 = z.y - c.y, d2 = z.z - c.z, d3 = z.w - c.w;
    l += (double)d0 * d0 + (double)d1 * d1 + (double)d2 * d2 + (double)d3 * d3;
  }
  __shared__ double sb[256];
  sb[t] = l; __syncthreads();
  for (int o = 128; o > 0; o >>= 1){
    if (t < o) sb[t] += sb[t + o];
    __syncthreads();
  }
  if (t == 0) atomicAdd(lossacc, sb[0]);
}

// ---------------- postq weight transpose: wT[t][ci][co] ----------------
__global__ void postq_wt(const float* __restrict__ w, float* __restrict__ wT){
  int i = blockIdx.x * 256 + threadIdx.x;
  if (i >= 2304) return;
  int co = i & 3, ci = (i >> 2) & 63, t = i >> 8;
  wT[i] = w[(co * 64 + ci) * 9 + t];
}

// ---------------- postq conv from ZQ planes, all 4 co per thread ----------------
__global__ __launch_bounds__(256) void postq_conv(const float* __restrict__ ZQq, const float* __restrict__ wT,
    const float* __restrict__ bias, float* __restrict__ out){
  int idx = blockIdx.x * 256 + threadIdx.x;   // sp over 65536
  int x = idx & 63, y = (idx >> 6) & 63, n = idx >> 12;
  float a0 = bias[0], a1 = bias[1], a2 = bias[2], a3 = bias[3];
  #pragma unroll
  for (int ky = 0; ky < 3; ky++){
    int iy = y - 1 + ky; if ((unsigned)iy >= 64u) continue;
    #pragma unroll
    for (int kx = 0; kx < 3; kx++){
      int ix = x - 1 + kx; if ((unsigned)ix >= 64u) continue;
      int spt = (n << 12) + (iy << 6) + ix;
      const float4* wt4 = (const float4*)(wT + (ky * 3 + kx) * 256);
      #pragma unroll
      for (int q = 0; q < 16; q++){
        float4 zv = ((const float4*)ZQq)[q * 65536 + spt];
        float4 w0 = wt4[q * 4], w1 = wt4[q * 4 + 1], w2 = wt4[q * 4 + 2], w3 = wt4[q * 4 + 3];
        a0 = fmaf(zv.x, w0.x, a0); a1 = fmaf(zv.x, w0.y, a1); a2 = fmaf(zv.x, w0.z, a2); a3 = fmaf(zv.x, w0.w, a3);
        a0 = fmaf(zv.y, w1.x, a0); a1 = fmaf(zv.y, w1.y, a1); a2 = fmaf(zv.y, w1.z, a2); a3 = fmaf(zv.y, w1.w, a3);
        a0 = fmaf(zv.z, w2.x, a0); a1 = fmaf(zv.z, w2.y, a1); a2 = fmaf(zv.z, w2.z, a2); a3 = fmaf(zv.z, w2.w, a3);
        a0 = fmaf(zv.w, w3.x, a0); a1 = fmaf(zv.w, w3.y, a1); a2 = fmaf(zv.w, w3.z, a2); a3 = fmaf(zv.w, w3.w, a3);
      }
    }
  }
  int base = ((n * 4) * 64 + y) * 64 + x;
  out[base] = a0; out[base + 4096] = a1; out[base + 8192] = a2; out[base + 12288] = a3;
}

// ---------------- transposed conv k=3 s=2 p=1 op=1: parity-quad form ----------------
// thread = (n,co,iy,ix); computes out(2iy+{0,1}, 2ix+{0,1}), exactly 9 FMA per ci
template<int CI, int CO>
__global__ __launch_bounds__(256) void convT_quad(const float* __restrict__ in, const float* __restrict__ w,
    const float* __restrict__ bias, float* __restrict__ out, int N, int IH, int IW){
  int OW = IW * 2;
  int idx = blockIdx.x * 256 + threadIdx.x;
  int total = N * CO * IH * IW;
  if (idx >= total) return;
  int ix = idx % IW, iy = (idx / IW) % IH;
  int co = (idx / (IW * IH)) % CO, n = idx / (IW * IH * CO);
  co = __builtin_amdgcn_readfirstlane(co);
  n  = __builtin_amdgcn_readfirstlane(n);
  float b = bias[co];
  float a00 = b, a01 = b, a10 = b, a11 = b;
  bool okx = (ix + 1 < IW), oky = (iy + 1 < IH);
  int ixp = okx ? ix + 1 : ix, iyp = oky ? iy + 1 : iy;
  const float* ip = in + (size_t)n * CI * IH * IW;
  #pragma unroll
  for (int ci = 0; ci < CI; ci++){
    const float* p = ip + ci * IH * IW;
    float v00 = p[iy * IW + ix];
    float v01 = p[iy * IW + ixp];  if (!okx) v01 = 0.f;
    float v10 = p[iyp * IW + ix];  if (!oky) v10 = 0.f;
    float v11 = p[iyp * IW + ixp]; if (!(okx && oky)) v11 = 0.f;
    const float* wp = w + ((size_t)ci * CO + co) * 9;   // [ky][kx], co wave-uniform -> scalar
    a00 = fmaf(wp[4], v00, a00);                          // (1,1)
    a01 = fmaf(wp[3], v01, a01); a01 = fmaf(wp[5], v00, a01);   // (1,0),(1,2)
    a10 = fmaf(wp[1], v10, a10); a10 = fmaf(wp[7], v00, a10);   // (0,1),(2,1)
    a11 = fmaf(wp[0], v11, a11); a11 = fmaf(wp[2], v10, a11);   // (0,0),(0,2)
    a11 = fmaf(wp[6], v01, a11); a11 = fmaf(wp[8], v00, a11);   // (2,0),(2,2)
  }
  float* o = out + (((size_t)n * CO + co) * (IH * 2) + 2 * iy) * OW + 2 * ix;
  float2 r0; r0.x = a00; r0.y = a01;
  float2 r1; r1.x = a10; r1.y = a11;
  *(float2*)o = r0;
  *(float2*)(o + OW) = r1;
}

// ---------------- BN stats (float4, f64 accum) ----------------
__global__ __launch_bounds__(256) void bn_stats(const float* __restrict__ x, double* __restrict__ sums,
    int C, int HW4, int N, int slabs){
  int c = blockIdx.x / slabs, s = blockIdx.x % slabs;
  const float4* xp = (const float4*)x;
  double ls = 0, lq = 0;
  for (int n = 0; n < N; n++){
    const float4* p = xp + (size_t)(n * C + c) * HW4;
    for (int i = s * 256 + threadIdx.x; i < HW4; i += slabs * 256){
      float4 v = p[i];
      ls += (double)v.x + (double)v.y + (double)v.z + (double)v.w;
      lq = fma((double)v.x, (double)v.x, lq);
      lq = fma((double)v.y, (double)v.y, lq);
      lq = fma((double)v.z, (double)v.z, lq);
      lq = fma((double)v.w, (double)v.w, lq);
    }
  }
  __shared__ double r0[256], r1[256];
  int t = threadIdx.x;
  r0[t] = ls; r1[t] = lq; __syncthreads();
  for (int o = 128; o > 0; o >>= 1){
    if (t < o){ r0[t] += r0[t + o]; r1[t] += r1[t + o]; }
    __syncthreads();
  }
  if (t == 0){ atomicAdd(&sums[c], r0[0]); atomicAdd(&sums[C + c], r1[0]); }
}

__global__ void bn_finalize(const double* __restrict__ sums, const float* __restrict__ g, const float* __restrict__ b,
    float* __restrict__ ss, int C, double count){
  int c = threadIdx.x;
  if (c >= C) return;
  double m = sums[c] / count;
  double var = sums[C + c] / count - m * m;
  double scale = (double)g[c] / sqrt(var + EPSV);
  ss[c] = (float)scale;
  ss[C + c] = (float)((double)b[c] - m * scale);
}

__global__ __launch_bounds__(256) void bn_apply4(float* __restrict__ x, const float* __restrict__ ss,
    int C, int HW4, int total4){
  int i = blockIdx.x * 256 + threadIdx.x;
  if (i >= total4) return;
  int c = (i / HW4) % C;
  float sc = ss[c], sh = ss[C + c];
  float4 v = ((float4*)x)[i];
  v.x = lrelu(fmaf(v.x, sc, sh));
  v.y = lrelu(fmaf(v.y, sc, sh));
  v.z = lrelu(fmaf(v.z, sc, sh));
  v.w = lrelu(fmaf(v.w, sc, sh));
  ((float4*)x)[i] = v;
}

// ---------------- VQ prep: f64 codebook + norms ----------------
__global__ void vq_prep(const float* __restrict__ cb, double* __restrict__ cb64, double* __restrict__ cbn64,
    float* __restrict__ cbn32){
  int k = blockIdx.x * 256 + threadIdx.x;
  if (k >= 1024) return;
  double s = 0;
  for (int d = 0; d < 64; d++){
    double v = (double)cb[k * 64 + d];
    cb64[(size_t)k * 64 + d] = v;
    s = fma(v, v, s);
  }
  cbn64[k] = s;
  cbn32[k] = (float)s;
}

__global__ void write_loss(const double* __restrict__ lossacc, float* __restrict__ out){
  out[0] = (float)(1.25 * lossacc[0] / (65536.0 * 64.0));
}

// ---------------- launch ----------------
extern "C" void kernel_launch(void* const* d_in, const int* in_sizes, int n_in,
                              void* d_out, int out_size, void* d_ws, size_t ws_size,
                              hipStream_t stream){
  const float* x      = (const float*)d_in[0];
  const float* cb     = (const float*)d_in[1];
  const float* e1_w   = (const float*)d_in[2];
  const float* e1_b   = (const float*)d_in[3];
  const float* bn1_g  = (const float*)d_in[4];
  const float* bn1_b  = (const float*)d_in[5];
  const float* e2_w   = (const float*)d_in[6];
  const float* e2_b   = (const float*)d_in[7];
  const float* bn2_g  = (const float*)d_in[8];
  const float* bn2_b  = (const float*)d_in[9];
  const float* preq_w = (const float*)d_in[10];
  const float* preq_b = (const float*)d_in[11];
  const float* postq_w= (const float*)d_in[12];
  const float* postq_b= (const float*)d_in[13];
  const float* d1_w   = (const float*)d_in[14];
  const float* d1_b   = (const float*)d_in[15];
  const float* bn3_g  = (const float*)d_in[16];
  const float* bn3_b  = (const float*)d_in[17];
  const float* d2_w   = (const float*)d_in[18];
  const float* d2_b   = (const float*)d_in[19];
  const float* bn4_g  = (const float*)d_in[20];
  const float* bn4_b  = (const float*)d_in[21];
  const float* d3_w   = (const float*)d_in[22];
  const float* d3_b   = (const float*)d_in[23];
  float* out = (float*)d_out;
  char* ws = (char*)d_ws;

  // workspace layout (bytes)
  double* stats = (double*)ws;                 // zeroed each call
  float*  ss    = (float*)(ws + 2048);
  double* cb64  = (double*)(ws + 4096);        // 512 KB
  double* cbn64 = (double*)(ws + 528384);      // 8 KB
  float*  cbn32 = (float*)(ws + 536576);       // 4 KB
  float*  wT    = (float*)(ws + 540672);       // 9216 B
  int*    flaglist = (int*)(ws + 549888);      // 256 KB
  int*    idx   = (int*)(ws + 812032);         // 256 KB
  float*  A     = (float*)(ws + 1074176);      // 16.7 MB (e1 out; later ZQ planes; later d1 out)
  float*  B     = (float*)(ws + 17851392);     // 1 MB (e2 out; later postq out)
  float*  Zq    = (float*)(ws + 18899968);     // 16.7 MB (preq out, plane layout)
  float*  F     = (float*)(ws + 35677184);     // 134 MB (d2 out)
  float*  ZQq   = A;                           // alias: A is dead after e2
  float*  D     = B;                           // alias: B is dead after preq

  double* sum1 = stats + 0;     // 32
  double* sum2 = stats + 32;    // 8 (pad to 16)
  double* sum3 = stats + 48;    // 32
  double* sum4 = stats + 80;    // 64
  double* lossacc = stats + 144;
  int*    flagcnt = (int*)(stats + 146);
  float *ss1 = ss + 0, *ss2 = ss + 32, *ss3 = ss + 48, *ss4 = ss + 80;

  hipMemsetAsync(stats, 0, 2048, stream);
  vq_prep<<<4, 256, 0, stream>>>(cb, cb64, cbn64, cbn32);
  postq_wt<<<9, 256, 0, stream>>>(postq_w, wT);

  // encoder
  conv_cobatch<3, 16, 2, false><<<1024, 256, 0, stream>>>(x, e1_w, e1_b, A, 16, 256, 256, 128, 128);
  bn_stats<<<256, 256, 0, stream>>>(A, sum1, 16, 4096, 16, 16);
  bn_finalize<<<1, 32, 0, stream>>>(sum1, bn1_g, bn1_b, ss1, 16, 16.0 * 16384);
  bn_apply4<<<4096, 256, 0, stream>>>(A, ss1, 16, 4096, 1048576);

  conv_cobatch<16, 4, 2, false><<<256, 256, 0, stream>>>(A, e2_w, e2_b, B, 16, 128, 128, 64, 64);
  bn_stats<<<16, 256, 0, stream>>>(B, sum2, 4, 1024, 16, 4);
  bn_finalize<<<1, 32, 0, stream>>>(sum2, bn2_g, bn2_b, ss2, 4, 16.0 * 4096);
  bn_apply4<<<256, 256, 0, stream>>>(B, ss2, 4, 1024, 65536);

  preq_conv<<<4096, 256, 0, stream>>>(B, preq_w, preq_b, Zq);

  // VQ: f32 screen -> f64 refine of near-ties -> gather + loss
  vq_screen<<<256, 256, 0, stream>>>(Zq, cb, cbn32, idx, flagcnt, flaglist);
  vq_refine<<<64, 256, 0, stream>>>(Zq, cb64, cbn64, flagcnt, flaglist, idx);
  vq_gather_loss<<<256, 256, 0, stream>>>(Zq, cb, idx, ZQq, lossacc);

  // decoder
  postq_conv<<<256, 256, 0, stream>>>(ZQq, wT, postq_b, D);

  convT_quad<4, 16><<<4096, 256, 0, stream>>>(D, d1_w, d1_b, A, 16, 64, 64);
  bn_stats<<<256, 256, 0, stream>>>(A, sum3, 16, 4096, 16, 16);
  bn_finalize<<<1, 32, 0, stream>>>(sum3, bn3_g, bn3_b, ss3, 16, 16.0 * 16384);
  bn_apply4<<<4096, 256, 0, stream>>>(A, ss3, 16, 4096, 1048576);

  convT_quad<16, 32><<<32768, 256, 0, stream>>>(A, d2_w, d2_b, F, 16, 128, 128);
  bn_stats<<<2048, 256, 0, stream>>>(F, sum4, 32, 16384, 16, 64);
  bn_finalize<<<1, 32, 0, stream>>>(sum4, bn4_g, bn4_b, ss4, 32, 16.0 * 65536);
  bn_apply4<<<32768, 256, 0, stream>>>(F, ss4, 32, 16384, 8388608);

  conv_cobatch<32, 3, 1, true><<<4096, 256, 0, stream>>>(F, d3_w, d3_b, out, 16, 256, 256, 256, 256);

  write_loss<<<1, 1, 0, stream>>>(lossacc, out + 3145728);
}

// Round 3
// 605.657 us; speedup vs baseline: 2.6047x; 2.6042x over previous
//
#include <hip/hip_runtime.h>
#include <math.h>

#define EPSV 1e-5
#define SLOPE 0.1f

__device__ __forceinline__ float lrelu(float x){ return x >= 0.f ? x : SLOPE * x; }
__device__ __forceinline__ float tanh_fast(float x){
  float e = __expf(2.f * x);          // v_exp_f32 path; overflow -> inf -> tanh=1, underflow -> -1
  return 1.f - 2.f / (e + 1.f);
}

// ---------------- e1: 3->16, stride 2, 256->128, thread = 2 x-outputs, all 16 co ----------------
__global__ __launch_bounds__(256) void e1_conv(const float* __restrict__ x, const float* __restrict__ w,
    const float* __restrict__ bias, float* __restrict__ out){
  int idx = blockIdx.x * 256 + threadIdx.x;     // 131072 threads
  int ox2 = idx & 63, oy = (idx >> 6) & 127, n = idx >> 13;
  float acc[16][2];
  #pragma unroll
  for (int co = 0; co < 16; co++){ float b = bias[co]; acc[co][0] = b; acc[co][1] = b; }
  int ix0 = 4 * ox2 - 1;
  int lclamp = (ox2 > 0) ? ix0 : 0;
  const float* xp = x + (size_t)n * 3 * 65536;
  #pragma unroll
  for (int ci = 0; ci < 3; ci++){
    const float* pl = xp + ci * 65536;
    #pragma unroll
    for (int ky = 0; ky < 3; ky++){
      int iy = 2 * oy - 1 + ky;                 // max 255, only iy<0 possible OOB
      if (iy >= 0){
        const float* row = pl + iy * 256;
        float l = row[lclamp];
        float4 m = *(const float4*)(row + ix0 + 1);   // aligned: 4*ox2
        float v0 = (ox2 > 0) ? l : 0.f;
        #pragma unroll
        for (int co = 0; co < 16; co++){
          const float* wp = w + ((co * 3 + ci) * 3 + ky) * 3;
          acc[co][0] = fmaf(v0,  wp[0], acc[co][0]);
          acc[co][0] = fmaf(m.x, wp[1], acc[co][0]);
          acc[co][0] = fmaf(m.y, wp[2], acc[co][0]);
          acc[co][1] = fmaf(m.y, wp[0], acc[co][1]);
          acc[co][1] = fmaf(m.z, wp[1], acc[co][1]);
          acc[co][1] = fmaf(m.w, wp[2], acc[co][1]);
        }
      }
    }
  }
  #pragma unroll
  for (int co = 0; co < 16; co++){
    float2 st; st.x = acc[co][0]; st.y = acc[co][1];
    *(float2*)(out + ((size_t)(n * 16 + co) * 128 + oy) * 128 + 2 * ox2) = st;
  }
}

// ---------------- co-batched direct 3x3 conv (e2 only) ----------------
template<int CI, int CO, int S>
__global__ __launch_bounds__(256) void conv_cobatch(const float* __restrict__ in, const float* __restrict__ w,
    const float* __restrict__ bias, float* __restrict__ out, int N, int IH, int IW, int OH, int OW){
  int idx = blockIdx.x * 256 + threadIdx.x;
  int total = N * OH * OW;
  if (idx >= total) return;
  int ox = idx % OW, oy = (idx / OW) % OH, n = idx / (OW * OH);
  float acc[CO];
  #pragma unroll
  for (int j = 0; j < CO; j++) acc[j] = bias[j];
  int iy0 = oy * S - 1, ix0 = ox * S - 1;
  const float* ip = in + (size_t)n * CI * IH * IW;
  #pragma unroll
  for (int ky = 0; ky < 3; ky++){
    int iy = iy0 + ky; if ((unsigned)iy >= (unsigned)IH) continue;
    #pragma unroll
    for (int kx = 0; kx < 3; kx++){
      int ix = ix0 + kx; if ((unsigned)ix >= (unsigned)IW) continue;
      const float* r = ip + iy * IW + ix;
      #pragma unroll
      for (int ci = 0; ci < CI; ci++){
        float v = r[ci * IH * IW];
        #pragma unroll
        for (int co = 0; co < CO; co++)
          acc[co] = fmaf(v, w[(co * CI + ci) * 9 + ky * 3 + kx], acc[co]);
      }
    }
  }
  #pragma unroll
  for (int co = 0; co < CO; co++)
    out[(((size_t)n * CO + co) * OH + oy) * OW + ox] = acc[co];
}

// ---------------- preq conv: output to plane layout Zq[coq][pos][4] ----------------
__global__ __launch_bounds__(256) void preq_conv(const float* __restrict__ in, const float* __restrict__ w,
    const float* __restrict__ bias, float* __restrict__ Zq){
  int idx = blockIdx.x * 256 + threadIdx.x;   // coq*65536 + sp
  int sp = idx & 65535;
  int coq = idx >> 16;                         // block-uniform
  int x = sp & 63, y = (sp >> 6) & 63, n = sp >> 12;
  float a0 = bias[coq * 4 + 0], a1 = bias[coq * 4 + 1], a2 = bias[coq * 4 + 2], a3 = bias[coq * 4 + 3];
  const float* ip = in + (size_t)n * 4 * 4096;
  #pragma unroll
  for (int ky = 0; ky < 3; ky++){
    int iy = y - 1 + ky; if ((unsigned)iy >= 64u) continue;
    #pragma unroll
    for (int kx = 0; kx < 3; kx++){
      int ix = x - 1 + kx; if ((unsigned)ix >= 64u) continue;
      #pragma unroll
      for (int ci = 0; ci < 4; ci++){
        float v = ip[ci * 4096 + iy * 64 + ix];
        const float* wp = w + ((coq * 4) * 4 + ci) * 9 + ky * 3 + kx;
        a0 = fmaf(v, wp[0], a0);
        a1 = fmaf(v, wp[36], a1);
        a2 = fmaf(v, wp[72], a2);
        a3 = fmaf(v, wp[108], a3);
      }
    }
  }
  float4 o; o.x = a0; o.y = a1; o.z = a2; o.w = a3;
  ((float4*)Zq)[coq * 65536 + sp] = o;
}

// ---------------- VQ screen, split-K: block = 256 positions x 256 codes ----------------
__global__ __launch_bounds__(256) void vq_screen(const float* __restrict__ Zq, const float* __restrict__ cb,
    const float* __restrict__ cbn32, float* __restrict__ best4, float* __restrict__ sec4, int* __restrict__ idx4){
  __shared__ float lcb[128 * 64];
  __shared__ float lcn[128];
  int t = threadIdx.x;
  int posblk = blockIdx.x >> 2, kc = blockIdx.x & 3;
  int pos = posblk * 256 + t;
  float zr[64];
  #pragma unroll
  for (int q = 0; q < 16; q++){
    float4 v = ((const float4*)Zq)[q * 65536 + pos];
    zr[4 * q] = v.x; zr[4 * q + 1] = v.y; zr[4 * q + 2] = v.z; zr[4 * q + 3] = v.w;
  }
  float best = 3.0e38f, sec = 3.0e38f; int bi = 0;
  for (int sub = 0; sub < 2; sub++){
    __syncthreads();
    int kb = kc * 256 + sub * 128;
    const float4* src = (const float4*)(cb + kb * 64);
    #pragma unroll
    for (int j = 0; j < 8; j++) ((float4*)lcb)[t + 256 * j] = src[t + 256 * j];
    if (t < 128) lcn[t] = cbn32[kb + t];
    __syncthreads();
    for (int kk = 0; kk < 128; kk++){
      const float* c = lcb + (kk << 6);
      float a0 = 0.f, a1 = 0.f, a2 = 0.f, a3 = 0.f;
      #pragma unroll
      for (int d = 0; d < 64; d += 4){
        a0 = fmaf(c[d], zr[d], a0);
        a1 = fmaf(c[d + 1], zr[d + 1], a1);
        a2 = fmaf(c[d + 2], zr[d + 2], a2);
        a3 = fmaf(c[d + 3], zr[d + 3], a3);
      }
      float s = lcn[kk] - 2.f * ((a0 + a1) + (a2 + a3));
      if (s < best){ sec = best; best = s; bi = kb + kk; }
      else if (s < sec) sec = s;
    }
  }
  best4[kc * 65536 + pos] = best;
  sec4[kc * 65536 + pos] = sec;
  idx4[kc * 65536 + pos] = bi;
}

// ---------------- VQ merge: combine 4 chunks, flag near-ties, compute loss ----------------
__global__ __launch_bounds__(256) void vq_merge(const float* __restrict__ best4, const float* __restrict__ sec4,
    const int* __restrict__ idx4, const float* __restrict__ Zq, const float* __restrict__ cb,
    int* __restrict__ idxout, int* __restrict__ flagcnt, int* __restrict__ flaglist, double* __restrict__ lossacc){
  int t = threadIdx.x;
  int pos = blockIdx.x * 256 + t;
  float gb = 3.0e38f, gs = 3.0e38f; int gi = 0;
  #pragma unroll
  for (int c = 0; c < 4; c++){
    float b = best4[c * 65536 + pos];
    float s = sec4[c * 65536 + pos];
    int i = idx4[c * 65536 + pos];
    if (b < gb){ gs = gb; gb = b; gi = i; } else if (b < gs) gs = b;
    if (s < gs) gs = s;
  }
  idxout[pos] = gi;
  if (gs - gb < 4e-3f){
    int slot = atomicAdd(flagcnt, 1);
    flaglist[slot] = pos;
  }
  const float4* c4 = (const float4*)(cb + (gi << 6));
  double l = 0;
  #pragma unroll
  for (int q = 0; q < 16; q++){
    float4 z = ((const float4*)Zq)[q * 65536 + pos];
    float4 c = c4[q];
    float d0 = z.x - c.x, d1 = z.y - c.y, d2 = z.z - c.z, d3 = z.w - c.w;
    l += (double)d0 * d0 + (double)d1 * d1 + (double)d2 * d2 + (double)d3 * d3;
  }
  __shared__ double sb[256];
  sb[t] = l; __syncthreads();
  for (int o = 128; o > 0; o >>= 1){
    if (t < o) sb[t] += sb[t + o];
    __syncthreads();
  }
  if (t == 0) atomicAdd(lossacc, sb[0]);
}

// ---------------- VQ refine: exact f64 re-rank for near-ties (one wave per position) ----------------
__global__ __launch_bounds__(256) void vq_refine(const float* __restrict__ Zq, const double* __restrict__ cb64,
    const double* __restrict__ cbn64, const int* __restrict__ flagcnt, const int* __restrict__ flaglist,
    int* __restrict__ idxout){
  int gw = (blockIdx.x * 256 + threadIdx.x) >> 6;
  int lane = threadIdx.x & 63;
  int nf = flagcnt[0];
  for (int f = gw; f < nf; f += 256){
    int pos = flaglist[f];
    float zr[64];
    #pragma unroll
    for (int q = 0; q < 16; q++){
      float4 v = ((const float4*)Zq)[q * 65536 + pos];
      zr[4 * q] = v.x; zr[4 * q + 1] = v.y; zr[4 * q + 2] = v.z; zr[4 * q + 3] = v.w;
    }
    double best = 1e300; int bi = 1 << 30;
    for (int k = lane; k < 1024; k += 64){
      const double* c = cb64 + (size_t)k * 64;
      double a0 = 0, a1 = 0, a2 = 0, a3 = 0;
      #pragma unroll
      for (int d = 0; d < 64; d += 4){
        a0 = fma(c[d], (double)zr[d], a0);
        a1 = fma(c[d + 1], (double)zr[d + 1], a1);
        a2 = fma(c[d + 2], (double)zr[d + 2], a2);
        a3 = fma(c[d + 3], (double)zr[d + 3], a3);
      }
      double s = cbn64[k] - 2.0 * ((a0 + a1) + (a2 + a3));
      if (s < best){ best = s; bi = k; }
    }
    #pragma unroll
    for (int o = 32; o > 0; o >>= 1){
      double ob = __shfl_xor(best, o);
      int oi = __shfl_xor(bi, o);
      if (ob < best || (ob == best && oi < bi)){ best = ob; bi = oi; }
    }
    if (lane == 0) idxout[pos] = bi;
  }
}

// ---------------- postq: conv over quantized field, input = cb[idx], thread = (pos, co) ----------------
__global__ __launch_bounds__(256) void postq_conv(const float* __restrict__ cb, const int* __restrict__ idxm,
    const float* __restrict__ w, const float* __restrict__ bias, float* __restrict__ out){
  int gid = blockIdx.x * 256 + threadIdx.x;     // 262144 = 4co x 65536
  int sp = gid & 65535;
  int co = gid >> 16;                            // block-uniform
  co = __builtin_amdgcn_readfirstlane(co);
  int xx = sp & 63, yy = (sp >> 6) & 63, n = sp >> 12;
  float a0 = bias[co], a1 = 0.f, a2 = 0.f, a3 = 0.f;
  const float* wb = w + co * 576;                // (co*64+ci)*9 + t
  #pragma unroll
  for (int ky = 0; ky < 3; ky++){
    int iy = yy - 1 + ky; if ((unsigned)iy >= 64u) continue;
    #pragma unroll
    for (int kx = 0; kx < 3; kx++){
      int ix = xx - 1 + kx; if ((unsigned)ix >= 64u) continue;
      int spt = (n << 12) + (iy << 6) + ix;
      int k = idxm[spt];
      const float4* c4 = (const float4*)(cb + (k << 6));
      int tp = ky * 3 + kx;
      #pragma unroll
      for (int q = 0; q < 16; q += 4){
        float4 ca = c4[q], cb2 = c4[q + 1], cc = c4[q + 2], cd = c4[q + 3];
        a0 = fmaf(ca.x, wb[(4*q+0)*9+tp], a0);  a1 = fmaf(ca.y, wb[(4*q+1)*9+tp], a1);
        a2 = fmaf(ca.z, wb[(4*q+2)*9+tp], a2);  a3 = fmaf(ca.w, wb[(4*q+3)*9+tp], a3);
        a0 = fmaf(cb2.x, wb[(4*q+4)*9+tp], a0); a1 = fmaf(cb2.y, wb[(4*q+5)*9+tp], a1);
        a2 = fmaf(cb2.z, wb[(4*q+6)*9+tp], a2); a3 = fmaf(cb2.w, wb[(4*q+7)*9+tp], a3);
        a0 = fmaf(cc.x, wb[(4*q+8)*9+tp], a0);  a1 = fmaf(cc.y, wb[(4*q+9)*9+tp], a1);
        a2 = fmaf(cc.z, wb[(4*q+10)*9+tp], a2); a3 = fmaf(cc.w, wb[(4*q+11)*9+tp], a3);
        a0 = fmaf(cd.x, wb[(4*q+12)*9+tp], a0); a1 = fmaf(cd.y, wb[(4*q+13)*9+tp], a1);
        a2 = fmaf(cd.z, wb[(4*q+14)*9+tp], a2); a3 = fmaf(cd.w, wb[(4*q+15)*9+tp], a3);
      }
    }
  }
  out[((size_t)(n * 4 + co) << 12) + (yy << 6) + xx] = (a0 + a1) + (a2 + a3);
}

// ---------------- transposed conv k=3 s=2 p=1 op=1, 8 co per thread ----------------
template<int CI, int CO>
__global__ __launch_bounds__(256) void convT_cob8(const float* __restrict__ in, const float* __restrict__ w,
    const float* __restrict__ bias, float* __restrict__ out, int N, int IH, int IW){
  int OW = IW * 2;
  int idx = blockIdx.x * 256 + threadIdx.x;
  int ix = idx % IW, iy = (idx / IW) % IH;
  int cog = (idx / (IW * IH)) % (CO / 8), n = idx / (IW * IH * (CO / 8));
  cog = __builtin_amdgcn_readfirstlane(cog);
  n   = __builtin_amdgcn_readfirstlane(n);
  float a00[8], a01[8], a10[8], a11[8];
  #pragma unroll
  for (int j = 0; j < 8; j++){ float b = bias[cog * 8 + j]; a00[j] = b; a01[j] = b; a10[j] = b; a11[j] = b; }
  bool okx = (ix + 1 < IW), oky = (iy + 1 < IH);
  int ixp = okx ? ix + 1 : ix, iyp = oky ? iy + 1 : iy;
  const float* ip = in + (size_t)n * CI * IH * IW;
  #pragma unroll 4
  for (int ci = 0; ci < CI; ci++){
    const float* p = ip + ci * IH * IW;
    float v00 = p[iy * IW + ix];
    float v01 = p[iy * IW + ixp];  if (!okx) v01 = 0.f;
    float v10 = p[iyp * IW + ix];  if (!oky) v10 = 0.f;
    float v11 = p[iyp * IW + ixp]; if (!(okx && oky)) v11 = 0.f;
    const float* wp = w + ((size_t)ci * CO + cog * 8) * 9;
    #pragma unroll
    for (int j = 0; j < 8; j++){
      const float* q = wp + j * 9;
      a00[j] = fmaf(q[4], v00, a00[j]);
      a01[j] = fmaf(q[3], v01, a01[j]); a01[j] = fmaf(q[5], v00, a01[j]);
      a10[j] = fmaf(q[1], v10, a10[j]); a10[j] = fmaf(q[7], v00, a10[j]);
      a11[j] = fmaf(q[0], v11, a11[j]); a11[j] = fmaf(q[2], v10, a11[j]);
      a11[j] = fmaf(q[6], v01, a11[j]); a11[j] = fmaf(q[8], v00, a11[j]);
    }
  }
  #pragma unroll
  for (int j = 0; j < 8; j++){
    float* o = out + (((size_t)n * CO + cog * 8 + j) * (IH * 2) + 2 * iy) * OW + 2 * ix;
    float2 r0; r0.x = a00[j]; r0.y = a01[j];
    float2 r1; r1.x = a10[j]; r1.y = a11[j];
    *(float2*)o = r0;
    *(float2*)(o + OW) = r1;
  }
}

// ---------------- d3: 32->3 @256x256, 8-wide x, fused bn4-apply+lrelu on loads, tanh ----------------
__global__ __launch_bounds__(256) void d3_conv(const float* __restrict__ F, const float* __restrict__ w,
    const float* __restrict__ bias, const float* __restrict__ ss, float* __restrict__ out){
  int idx = blockIdx.x * 256 + threadIdx.x;     // 131072
  int ox8 = idx & 31, oy = (idx >> 5) & 255, n = idx >> 13;
  int ox0 = ox8 * 8;
  float acc[3][8];
  #pragma unroll
  for (int co = 0; co < 3; co++){
    float b = bias[co];
    #pragma unroll
    for (int j = 0; j < 8; j++) acc[co][j] = b;
  }
  const float* base = F + (size_t)n * 32 * 65536;
  bool x0ok = (ox8 > 0), x9ok = (ox8 < 31);
  int offL = x0ok ? -1 : 0;
  int offR = x9ok ? 8 : 0;
  #pragma unroll 2
  for (int ci = 0; ci < 32; ci++){
    const float* pl = base + ci * 65536;
    float sc = ss[ci], sh = ss[32 + ci];
    #pragma unroll
    for (int ky = 0; ky < 3; ky++){
      int iy = oy - 1 + ky;
      if (iy >= 0 && iy <= 255){
        const float* row = pl + iy * 256 + ox0;
        float l  = row[offL];
        float4 m = *(const float4*)row;
        float4 r = *(const float4*)(row + 4);
        float t8 = row[offR];
        float u[10];
        u[0] = x0ok ? lrelu(fmaf(l, sc, sh)) : 0.f;
        u[1] = lrelu(fmaf(m.x, sc, sh)); u[2] = lrelu(fmaf(m.y, sc, sh));
        u[3] = lrelu(fmaf(m.z, sc, sh)); u[4] = lrelu(fmaf(m.w, sc, sh));
        u[5] = lrelu(fmaf(r.x, sc, sh)); u[6] = lrelu(fmaf(r.y, sc, sh));
        u[7] = lrelu(fmaf(r.z, sc, sh)); u[8] = lrelu(fmaf(r.w, sc, sh));
        u[9] = x9ok ? lrelu(fmaf(t8, sc, sh)) : 0.f;
        #pragma unroll
        for (int co = 0; co < 3; co++){
          const float* wp = w + ((co * 32 + ci) * 9) + ky * 3;
          #pragma unroll
          for (int j = 0; j < 8; j++){
            acc[co][j] = fmaf(u[j],     wp[0], acc[co][j]);
            acc[co][j] = fmaf(u[j + 1], wp[1], acc[co][j]);
            acc[co][j] = fmaf(u[j + 2], wp[2], acc[co][j]);
          }
        }
      }
    }
  }
  #pragma unroll
  for (int co = 0; co < 3; co++){
    float4 s0, s1;
    s0.x = tanh_fast(acc[co][0]); s0.y = tanh_fast(acc[co][1]);
    s0.z = tanh_fast(acc[co][2]); s0.w = tanh_fast(acc[co][3]);
    s1.x = tanh_fast(acc[co][4]); s1.y = tanh_fast(acc[co][5]);
    s1.z = tanh_fast(acc[co][6]); s1.w = tanh_fast(acc[co][7]);
    float* o = out + ((size_t)(n * 3 + co) * 256 + oy) * 256 + ox0;
    *(float4*)o = s0;
    *(float4*)(o + 4) = s1;
  }
}

// ---------------- BN stats (float4, f64 accum) ----------------
__global__ __launch_bounds__(256) void bn_stats(const float* __restrict__ x, double* __restrict__ sums,
    int C, int HW4, int N, int slabs){
  int c = blockIdx.x / slabs, s = blockIdx.x % slabs;
  const float4* xp = (const float4*)x;
  double ls = 0, lq = 0;
  for (int n = 0; n < N; n++){
    const float4* p = xp + (size_t)(n * C + c) * HW4;
    for (int i = s * 256 + threadIdx.x; i < HW4; i += slabs * 256){
      float4 v = p[i];
      ls += (double)v.x + (double)v.y + (double)v.z + (double)v.w;
      lq = fma((double)v.x, (double)v.x, lq);
      lq = fma((double)v.y, (double)v.y, lq);
      lq = fma((double)v.z, (double)v.z, lq);
      lq = fma((double)v.w, (double)v.w, lq);
    }
  }
  __shared__ double r0[256], r1[256];
  int t = threadIdx.x;
  r0[t] = ls; r1[t] = lq; __syncthreads();
  for (int o = 128; o > 0; o >>= 1){
    if (t < o){ r0[t] += r0[t + o]; r1[t] += r1[t + o]; }
    __syncthreads();
  }
  if (t == 0){ atomicAdd(&sums[c], r0[0]); atomicAdd(&sums[C + c], r1[0]); }
}

__global__ void bn_finalize(const double* __restrict__ sums, const float* __restrict__ g, const float* __restrict__ b,
    float* __restrict__ ss, int C, double count){
  int c = threadIdx.x;
  if (c >= C) return;
  double m = sums[c] / count;
  double var = sums[C + c] / count - m * m;
  double scale = (double)g[c] / sqrt(var + EPSV);
  ss[c] = (float)scale;
  ss[C + c] = (float)((double)b[c] - m * scale);
}

__global__ __launch_bounds__(256) void bn_apply4(float* __restrict__ x, const float* __restrict__ ss,
    int C, int HW4, int total4){
  int i = blockIdx.x * 256 + threadIdx.x;
  if (i >= total4) return;
  int c = (i / HW4) % C;
  float sc = ss[c], sh = ss[C + c];
  float4 v = ((float4*)x)[i];
  v.x = lrelu(fmaf(v.x, sc, sh));
  v.y = lrelu(fmaf(v.y, sc, sh));
  v.z = lrelu(fmaf(v.z, sc, sh));
  v.w = lrelu(fmaf(v.w, sc, sh));
  ((float4*)x)[i] = v;
}

// ---------------- VQ prep: f64 codebook + norms ----------------
__global__ void vq_prep(const float* __restrict__ cb, double* __restrict__ cb64, double* __restrict__ cbn64,
    float* __restrict__ cbn32){
  int k = blockIdx.x * 256 + threadIdx.x;
  if (k >= 1024) return;
  double s = 0;
  for (int d = 0; d < 64; d++){
    double v = (double)cb[k * 64 + d];
    cb64[(size_t)k * 64 + d] = v;
    s = fma(v, v, s);
  }
  cbn64[k] = s;
  cbn32[k] = (float)s;
}

__global__ void write_loss(const double* __restrict__ lossacc, float* __restrict__ out){
  out[0] = (float)(1.25 * lossacc[0] / (65536.0 * 64.0));
}

// ---------------- launch ----------------
extern "C" void kernel_launch(void* const* d_in, const int* in_sizes, int n_in,
                              void* d_out, int out_size, void* d_ws, size_t ws_size,
                              hipStream_t stream){
  const float* x      = (const float*)d_in[0];
  const float* cb     = (const float*)d_in[1];
  const float* e1_w   = (const float*)d_in[2];
  const float* e1_b   = (const float*)d_in[3];
  const float* bn1_g  = (const float*)d_in[4];
  const float* bn1_b  = (const float*)d_in[5];
  const float* e2_w   = (const float*)d_in[6];
  const float* e2_b   = (const float*)d_in[7];
  const float* bn2_g  = (const float*)d_in[8];
  const float* bn2_b  = (const float*)d_in[9];
  const float* preq_w = (const float*)d_in[10];
  const float* preq_b = (const float*)d_in[11];
  const float* postq_w= (const float*)d_in[12];
  const float* postq_b= (const float*)d_in[13];
  const float* d1_w   = (const float*)d_in[14];
  const float* d1_b   = (const float*)d_in[15];
  const float* bn3_g  = (const float*)d_in[16];
  const float* bn3_b  = (const float*)d_in[17];
  const float* d2_w   = (const float*)d_in[18];
  const float* d2_b   = (const float*)d_in[19];
  const float* bn4_g  = (const float*)d_in[20];
  const float* bn4_b  = (const float*)d_in[21];
  const float* d3_w   = (const float*)d_in[22];
  const float* d3_b   = (const float*)d_in[23];
  float* out = (float*)d_out;
  char* ws = (char*)d_ws;

  // workspace layout (bytes)
  double* stats = (double*)ws;                   // [0, 2048)
  float*  ss    = (float*)(ws + 2048);           // [2048, 4096)
  double* cb64  = (double*)(ws + 4096);          // [4096, 528384)
  double* cbn64 = (double*)(ws + 528384);        // 8 KB
  float*  cbn32 = (float*)(ws + 536576);         // 4 KB
  int*    flaglist = (int*)(ws + 540672);        // 256 KB
  int*    idx   = (int*)(ws + 802816);           // 256 KB
  float*  A     = (float*)(ws + 1064960);        // 16.78 MB (e1 out; screen partials alias; d1 out)
  float*  B     = (float*)(ws + 17842176);       // 1 MB (e2 out; postq out)
  float*  Zq    = (float*)(ws + 18890752);       // 16.78 MB (preq out, plane layout)
  float*  F     = (float*)(ws + 35667968);       // 134.2 MB (d2 out) -> ends 169885696
  // screen partials alias A (dead between e2 and d1)
  float*  best4 = A;
  float*  sec4  = A + 262144;
  int*    idx4  = (int*)(A + 524288);
  float*  D     = B;

  double* sum1 = stats + 0;
  double* sum2 = stats + 32;
  double* sum3 = stats + 48;
  double* sum4 = stats + 80;
  double* lossacc = stats + 144;
  int*    flagcnt = (int*)(stats + 146);
  float *ss1 = ss + 0, *ss2 = ss + 32, *ss3 = ss + 48, *ss4 = ss + 80;

  hipMemsetAsync(stats, 0, 2048, stream);
  vq_prep<<<4, 256, 0, stream>>>(cb, cb64, cbn64, cbn32);

  // encoder
  e1_conv<<<512, 256, 0, stream>>>(x, e1_w, e1_b, A);
  bn_stats<<<256, 256, 0, stream>>>(A, sum1, 16, 4096, 16, 16);
  bn_finalize<<<1, 32, 0, stream>>>(sum1, bn1_g, bn1_b, ss1, 16, 262144.0);
  bn_apply4<<<4096, 256, 0, stream>>>(A, ss1, 16, 4096, 1048576);

  conv_cobatch<16, 4, 2><<<256, 256, 0, stream>>>(A, e2_w, e2_b, B, 16, 128, 128, 64, 64);
  bn_stats<<<16, 256, 0, stream>>>(B, sum2, 4, 1024, 16, 4);
  bn_finalize<<<1, 32, 0, stream>>>(sum2, bn2_g, bn2_b, ss2, 4, 65536.0);
  bn_apply4<<<256, 256, 0, stream>>>(B, ss2, 4, 1024, 65536);

  preq_conv<<<4096, 256, 0, stream>>>(B, preq_w, preq_b, Zq);

  // VQ
  vq_screen<<<1024, 256, 0, stream>>>(Zq, cb, cbn32, best4, sec4, idx4);
  vq_merge<<<256, 256, 0, stream>>>(best4, sec4, idx4, Zq, cb, idx, flagcnt, flaglist, lossacc);
  vq_refine<<<64, 256, 0, stream>>>(Zq, cb64, cbn64, flagcnt, flaglist, idx);

  // decoder
  postq_conv<<<1024, 256, 0, stream>>>(cb, idx, postq_w, postq_b, D);

  convT_cob8<4, 16><<<512, 256, 0, stream>>>(D, d1_w, d1_b, A, 16, 64, 64);
  bn_stats<<<256, 256, 0, stream>>>(A, sum3, 16, 4096, 16, 16);
  bn_finalize<<<1, 32, 0, stream>>>(sum3, bn3_g, bn3_b, ss3, 16, 262144.0);
  bn_apply4<<<4096, 256, 0, stream>>>(A, ss3, 16, 4096, 1048576);

  convT_cob8<16, 32><<<4096, 256, 0, stream>>>(A, d2_w, d2_b, F, 16, 128, 128);
  bn_stats<<<2048, 256, 0, stream>>>(F, sum4, 32, 16384, 16, 64);
  bn_finalize<<<1, 32, 0, stream>>>(sum4, bn4_g, bn4_b, ss4, 32, 1048576.0);

  // d3 with fused bn4-apply
  d3_conv<<<512, 256, 0, stream>>>(F, d3_w, d3_b, ss4, out);

  write_loss<<<1, 1, 0, stream>>>(lossacc, out + 3145728);
}

// Round 4
// 414.106 us; speedup vs baseline: 3.8096x; 1.4626x over previous
//
#include <hip/hip_runtime.h>
#include <math.h>

#define EPSV 1e-5
#define SLOPE 0.1f

typedef __attribute__((ext_vector_type(4))) float f32x4;
typedef __attribute__((ext_vector_type(8))) short short8x;

__device__ __forceinline__ float lrelu(float x){ return x >= 0.f ? x : SLOPE * x; }
__device__ __forceinline__ float tanh_fast(float x){
  float e = __expf(2.f * x);
  return 1.f - 2.f / (e + 1.f);
}
__device__ __forceinline__ unsigned bf16rne(float f){
  unsigned u = __float_as_uint(f);
  u += 0x7fff + ((u >> 16) & 1);
  return u >> 16;
}

// ---- block BN-stats epilogue: per-thread CL channel sums/sqs -> f64 partials ----
template<int CL>
__device__ __forceinline__ void stats_epilogue(const float* sums, const float* sqs,
    double* __restrict__ part, int chbase, int P, int p, float* sred){
  const int C2 = 2 * CL;
  int t = threadIdx.x;
  #pragma unroll
  for (int c = 0; c < CL; c++){
    sred[t * C2 + c] = sums[c];
    sred[t * C2 + CL + c] = sqs[c];
  }
  __syncthreads();
  if (t < 64){
    int c = t % C2;
    int g = t / C2;
    const int G = 64 / C2;
    const int R = 256 / G;
    double s = 0;
    for (int r = g * R; r < (g + 1) * R; r++) s += (double)sred[r * C2 + c];
    #pragma unroll
    for (int off = C2; off < 64; off <<= 1) s += __shfl_xor(s, off);
    if (t < C2){
      int ch = chbase + (c < CL ? c : c - CL);
      part[(size_t)ch * 2 * P + (c < CL ? 0 : P) + p] = s;
    }
  }
}

// ---- reduce partials + finalize scale/shift ----
__global__ __launch_bounds__(256) void bn_red_fin(const double* __restrict__ part, int P,
    const float* __restrict__ g, const float* __restrict__ b, float* __restrict__ ss, int C, double count){
  int c = blockIdx.x;
  __shared__ double r0[256], r1[256];
  int t = threadIdx.x;
  double s = 0, q = 0;
  for (int p = t; p < P; p += 256){
    s += part[(size_t)c * 2 * P + p];
    q += part[(size_t)c * 2 * P + P + p];
  }
  r0[t] = s; r1[t] = q; __syncthreads();
  for (int o = 128; o > 0; o >>= 1){
    if (t < o){ r0[t] += r0[t + o]; r1[t] += r1[t + o]; }
    __syncthreads();
  }
  if (t == 0){
    double m = r0[0] / count;
    double var = r1[0] / count - m * m;
    double scale = (double)g[c] / sqrt(var + EPSV);
    ss[c] = (float)scale;
    ss[C + c] = (float)((double)b[c] - m * scale);
  }
}

// ---------------- e1: 3->16 s2, 256->128, 2 x-outputs/thread, fused bn1-stats ----------------
__global__ __launch_bounds__(256) void e1_conv(const float* __restrict__ x, const float* __restrict__ w,
    const float* __restrict__ bias, float* __restrict__ out, double* __restrict__ part){
  int idx = blockIdx.x * 256 + threadIdx.x;
  int ox2 = idx & 63, oy = (idx >> 6) & 127, n = idx >> 13;
  float acc[16][2];
  #pragma unroll
  for (int co = 0; co < 16; co++){ float b = bias[co]; acc[co][0] = b; acc[co][1] = b; }
  int ix0 = 4 * ox2 - 1;
  int lclamp = (ox2 > 0) ? ix0 : 0;
  const float* xp = x + (size_t)n * 3 * 65536;
  #pragma unroll
  for (int ci = 0; ci < 3; ci++){
    const float* pl = xp + ci * 65536;
    #pragma unroll
    for (int ky = 0; ky < 3; ky++){
      int iy = 2 * oy - 1 + ky;
      if (iy >= 0){
        const float* row = pl + iy * 256;
        float l = row[lclamp];
        float4 m = *(const float4*)(row + ix0 + 1);
        float v0 = (ox2 > 0) ? l : 0.f;
        #pragma unroll
        for (int co = 0; co < 16; co++){
          const float* wp = w + ((co * 3 + ci) * 3 + ky) * 3;
          acc[co][0] = fmaf(v0,  wp[0], acc[co][0]);
          acc[co][0] = fmaf(m.x, wp[1], acc[co][0]);
          acc[co][0] = fmaf(m.y, wp[2], acc[co][0]);
          acc[co][1] = fmaf(m.y, wp[0], acc[co][1]);
          acc[co][1] = fmaf(m.z, wp[1], acc[co][1]);
          acc[co][1] = fmaf(m.w, wp[2], acc[co][1]);
        }
      }
    }
  }
  float sums[16], sqs[16];
  #pragma unroll
  for (int co = 0; co < 16; co++){
    float2 st; st.x = acc[co][0]; st.y = acc[co][1];
    *(float2*)(out + ((size_t)(n * 16 + co) * 128 + oy) * 128 + 2 * ox2) = st;
    sums[co] = acc[co][0] + acc[co][1];
    sqs[co] = acc[co][0] * acc[co][0] + acc[co][1] * acc[co][1];
  }
  __shared__ float sred[256 * 32];
  stats_epilogue<16>(sums, sqs, part, 0, 512, blockIdx.x, sred);
}

// ---------------- e2: 16->4 s2 with fused bn1-apply on loads + bn2-stats ----------------
__global__ __launch_bounds__(256) void e2_conv(const float* __restrict__ in, const float* __restrict__ w,
    const float* __restrict__ bias, const float* __restrict__ ssIn, float* __restrict__ out,
    double* __restrict__ part){
  int idx = blockIdx.x * 256 + threadIdx.x;
  int ox = idx & 63, oy = (idx >> 6) & 63, n = idx >> 12;
  float acc[4];
  #pragma unroll
  for (int j = 0; j < 4; j++) acc[j] = bias[j];
  int iy0 = oy * 2 - 1, ix0 = ox * 2 - 1;
  const float* ip = in + (size_t)n * 16 * 16384;
  #pragma unroll
  for (int ky = 0; ky < 3; ky++){
    int iy = iy0 + ky; if ((unsigned)iy >= 128u) continue;
    #pragma unroll
    for (int kx = 0; kx < 3; kx++){
      int ix = ix0 + kx; if ((unsigned)ix >= 128u) continue;
      const float* r = ip + iy * 128 + ix;
      #pragma unroll
      for (int ci = 0; ci < 16; ci++){
        float v = lrelu(fmaf(r[ci * 16384], ssIn[ci], ssIn[16 + ci]));
        #pragma unroll
        for (int co = 0; co < 4; co++)
          acc[co] = fmaf(v, w[(co * 16 + ci) * 9 + ky * 3 + kx], acc[co]);
      }
    }
  }
  float sums[4], sqs[4];
  #pragma unroll
  for (int co = 0; co < 4; co++){
    out[(((size_t)n * 4 + co) * 64 + oy) * 64 + ox] = acc[co];
    sums[co] = acc[co];
    sqs[co] = acc[co] * acc[co];
  }
  __shared__ float sred[256 * 8];
  stats_epilogue<4>(sums, sqs, part, 0, 256, blockIdx.x, sred);
}

// ---------------- preq: fused bn2-apply, output plane layout Zq[coq][pos][4] ----------------
__global__ __launch_bounds__(256) void preq_conv(const float* __restrict__ in, const float* __restrict__ w,
    const float* __restrict__ bias, const float* __restrict__ ssIn, float* __restrict__ Zq){
  int idx = blockIdx.x * 256 + threadIdx.x;
  int sp = idx & 65535;
  int coq = idx >> 16;
  int x = sp & 63, y = (sp >> 6) & 63, n = sp >> 12;
  float scv[4] = {ssIn[0], ssIn[1], ssIn[2], ssIn[3]};
  float shv[4] = {ssIn[4], ssIn[5], ssIn[6], ssIn[7]};
  float a0 = bias[coq * 4 + 0], a1 = bias[coq * 4 + 1], a2 = bias[coq * 4 + 2], a3 = bias[coq * 4 + 3];
  const float* ip = in + (size_t)n * 4 * 4096;
  #pragma unroll
  for (int ky = 0; ky < 3; ky++){
    int iy = y - 1 + ky; if ((unsigned)iy >= 64u) continue;
    #pragma unroll
    for (int kx = 0; kx < 3; kx++){
      int ix = x - 1 + kx; if ((unsigned)ix >= 64u) continue;
      #pragma unroll
      for (int ci = 0; ci < 4; ci++){
        float v = lrelu(fmaf(ip[ci * 4096 + iy * 64 + ix], scv[ci], shv[ci]));
        const float* wp = w + ((coq * 4) * 4 + ci) * 9 + ky * 3 + kx;
        a0 = fmaf(v, wp[0], a0);
        a1 = fmaf(v, wp[36], a1);
        a2 = fmaf(v, wp[72], a2);
        a3 = fmaf(v, wp[108], a3);
      }
    }
  }
  float4 o; o.x = a0; o.y = a1; o.z = a2; o.w = a3;
  ((float4*)Zq)[coq * 65536 + sp] = o;
}

// ---------------- VQ prep: f64 codebook + norms + split-bf16 codebook ----------------
__global__ void vq_prep(const float* __restrict__ cb, double* __restrict__ cb64, double* __restrict__ cbn64,
    float* __restrict__ cbn32, unsigned short* __restrict__ cbh, unsigned short* __restrict__ cbl){
  int k = blockIdx.x * 256 + threadIdx.x;
  if (k >= 1024) return;
  double s = 0;
  for (int d = 0; d < 64; d++){
    float v = cb[k * 64 + d];
    cb64[(size_t)k * 64 + d] = (double)v;
    s = fma((double)v, (double)v, s);
    unsigned h = bf16rne(v);
    float hf = __uint_as_float(h << 16);
    unsigned l = bf16rne(v - hf);
    cbh[k * 64 + d] = (unsigned short)h;
    cbl[k * 64 + d] = (unsigned short)l;
  }
  cbn64[k] = s;
  cbn32[k] = (float)s;
}

// ---------------- VQ screen via MFMA (split-bf16, exact-enough scores + tie flags) ----------------
// block = 256 thr = 4 waves; wave = 16 positions x all 1024 codes
__global__ __launch_bounds__(256) void vq_screen_mfma(const float* __restrict__ Zq,
    const unsigned short* __restrict__ cbh, const unsigned short* __restrict__ cbl,
    const float* __restrict__ cbn32, int* __restrict__ idxout,
    int* __restrict__ flagcnt, int* __restrict__ flaglist){
  __shared__ unsigned short lcb[32 * 64 * 8];   // 32 KB staged A-fragments
  __shared__ float lcn[128];
  int t = threadIdx.x;
  int lane = t & 63;
  int w = t >> 6;
  int col = lane & 15, hg = lane >> 4;
  int pos0 = blockIdx.x * 64 + w * 16;
  int pos = pos0 + col;
  const float4* Zq4 = (const float4*)Zq;
  short8x zh[2], zl[2];
  #pragma unroll
  for (int kc = 0; kc < 2; kc++){
    float4 f0 = Zq4[(size_t)(8 * kc + 2 * hg) * 65536 + pos];
    float4 f1 = Zq4[(size_t)(8 * kc + 2 * hg + 1) * 65536 + pos];
    float zv[8] = {f0.x, f0.y, f0.z, f0.w, f1.x, f1.y, f1.z, f1.w};
    union { unsigned u[4]; short8x v; } H, L;
    #pragma unroll
    for (int j = 0; j < 4; j++){
      unsigned h0 = bf16rne(zv[2 * j]);
      unsigned h1 = bf16rne(zv[2 * j + 1]);
      float hf0 = __uint_as_float(h0 << 16);
      float hf1 = __uint_as_float(h1 << 16);
      unsigned l0 = bf16rne(zv[2 * j] - hf0);
      unsigned l1 = bf16rne(zv[2 * j + 1] - hf1);
      H.u[j] = h0 | (h1 << 16);
      L.u[j] = l0 | (l1 << 16);
    }
    zh[kc] = H.v; zl[kc] = L.v;
  }
  float best = 3.0e38f, sec = 3.0e38f; int bidx = 0;
  for (int step = 0; step < 8; step++){
    int code0 = step * 128;
    __syncthreads();
    #pragma unroll
    for (int i = 0; i < 8; i++){
      int piece = i * 256 + t;
      int fb = piece >> 6, pl = piece & 63;
      int g = fb >> 2, kc = (fb >> 1) & 1, sp = fb & 1;
      const unsigned short* src = (sp ? cbl : cbh)
          + ((size_t)(code0 + g * 16 + (pl & 15)) << 6) + kc * 32 + ((pl >> 4) << 3);
      *(uint4*)&lcb[piece * 8] = *(const uint4*)src;
    }
    if (t < 128) lcn[t] = cbn32[code0 + t];
    __syncthreads();
    #pragma unroll 2
    for (int g = 0; g < 8; g++){
      f32x4 acc = {0.f, 0.f, 0.f, 0.f};
      const short8x* lc8 = (const short8x*)lcb;
      short8x Ah0 = lc8[(g * 4 + 0) * 64 + lane];
      short8x Al0 = lc8[(g * 4 + 1) * 64 + lane];
      short8x Ah1 = lc8[(g * 4 + 2) * 64 + lane];
      short8x Al1 = lc8[(g * 4 + 3) * 64 + lane];
      acc = __builtin_amdgcn_mfma_f32_16x16x32_bf16(Ah0, zh[0], acc, 0, 0, 0);
      acc = __builtin_amdgcn_mfma_f32_16x16x32_bf16(Ah1, zh[1], acc, 0, 0, 0);
      acc = __builtin_amdgcn_mfma_f32_16x16x32_bf16(Ah0, zl[0], acc, 0, 0, 0);
      acc = __builtin_amdgcn_mfma_f32_16x16x32_bf16(Ah1, zl[1], acc, 0, 0, 0);
      acc = __builtin_amdgcn_mfma_f32_16x16x32_bf16(Al0, zh[0], acc, 0, 0, 0);
      acc = __builtin_amdgcn_mfma_f32_16x16x32_bf16(Al1, zh[1], acc, 0, 0, 0);
      int cbase = code0 + g * 16 + 4 * hg;
      #pragma unroll
      for (int r = 0; r < 4; r++){
        float s = fmaf(acc[r], -2.0f, lcn[g * 16 + 4 * hg + r]);
        float mx = fmaxf(s, best);
        sec = fminf(sec, mx);
        if (s < best){ best = s; bidx = cbase + r; }
      }
    }
  }
  #pragma unroll
  for (int off = 16; off <= 32; off <<= 1){
    float ob = __shfl_xor(best, off);
    float os = __shfl_xor(sec, off);
    int oi = __shfl_xor(bidx, off);
    sec = fminf(fminf(sec, os), fmaxf(best, ob));
    if (ob < best){ best = ob; bidx = oi; }
  }
  if (hg == 0){
    idxout[pos] = bidx;
    if (sec - best < 1.2e-2f){
      int slot = atomicAdd(flagcnt, 1);
      flaglist[slot] = pos;
    }
  }
}

// ---------------- VQ refine: exact f64 re-rank of near-ties ----------------
__global__ __launch_bounds__(256) void vq_refine(const float* __restrict__ Zq, const double* __restrict__ cb64,
    const double* __restrict__ cbn64, const int* __restrict__ flagcnt, const int* __restrict__ flaglist,
    int* __restrict__ idxout){
  int gw = (blockIdx.x * 256 + threadIdx.x) >> 6;
  int lane = threadIdx.x & 63;
  int nf = flagcnt[0];
  for (int f = gw; f < nf; f += 512){
    int pos = flaglist[f];
    float zr[64];
    #pragma unroll
    for (int q = 0; q < 16; q++){
      float4 v = ((const float4*)Zq)[q * 65536 + pos];
      zr[4 * q] = v.x; zr[4 * q + 1] = v.y; zr[4 * q + 2] = v.z; zr[4 * q + 3] = v.w;
    }
    double best = 1e300; int bi = 1 << 30;
    for (int k = lane; k < 1024; k += 64){
      const double* c = cb64 + (size_t)k * 64;
      double a0 = 0, a1 = 0, a2 = 0, a3 = 0;
      #pragma unroll
      for (int d = 0; d < 64; d += 4){
        a0 = fma(c[d], (double)zr[d], a0);
        a1 = fma(c[d + 1], (double)zr[d + 1], a1);
        a2 = fma(c[d + 2], (double)zr[d + 2], a2);
        a3 = fma(c[d + 3], (double)zr[d + 3], a3);
      }
      double s = cbn64[k] - 2.0 * ((a0 + a1) + (a2 + a3));
      if (s < best){ best = s; bi = k; }
    }
    #pragma unroll
    for (int o = 32; o > 0; o >>= 1){
      double ob = __shfl_xor(best, o);
      int oi = __shfl_xor(bi, o);
      if (ob < best || (ob == best && oi < bi)){ best = ob; bi = oi; }
    }
    if (lane == 0) idxout[pos] = bi;
  }
}

// ---------------- loss (uses final idx), deterministic block partials ----------------
__global__ __launch_bounds__(256) void vq_loss(const float* __restrict__ Zq, const float* __restrict__ cb,
    const int* __restrict__ idxv, double* __restrict__ losspart){
  int t = threadIdx.x;
  int pos = blockIdx.x * 256 + t;
  int k = idxv[pos];
  const float4* c4 = (const float4*)(cb + (k << 6));
  double l = 0;
  #pragma unroll
  for (int q = 0; q < 16; q++){
    float4 z = ((const float4*)Zq)[q * 65536 + pos];
    float4 c = c4[q];
    float d0 = z.x - c.x, d1 = z.y - c.y, d2 = z.z - c.z, d3 = z.w - c.w;
    l += (double)d0 * d0 + (double)d1 * d1 + (double)d2 * d2 + (double)d3 * d3;
  }
  __shared__ double sb[256];
  sb[t] = l; __syncthreads();
  for (int o = 128; o > 0; o >>= 1){
    if (t < o) sb[t] += sb[t + o];
    __syncthreads();
  }
  if (t == 0) losspart[blockIdx.x] = sb[0];
}

__global__ void write_loss(const double* __restrict__ losspart, float* __restrict__ out){
  __shared__ double sb[256];
  int t = threadIdx.x;
  sb[t] = losspart[t];
  __syncthreads();
  for (int o = 128; o > 0; o >>= 1){
    if (t < o) sb[t] += sb[t + o];
    __syncthreads();
  }
  if (t == 0) out[0] = (float)(1.25 * sb[0] / (65536.0 * 64.0));
}

// ---------------- postq: conv over cb[idx] field ----------------
__global__ __launch_bounds__(256) void postq_conv(const float* __restrict__ cb, const int* __restrict__ idxm,
    const float* __restrict__ w, const float* __restrict__ bias, float* __restrict__ out){
  int gid = blockIdx.x * 256 + threadIdx.x;
  int sp = gid & 65535;
  int co = gid >> 16;
  co = __builtin_amdgcn_readfirstlane(co);
  int xx = sp & 63, yy = (sp >> 6) & 63, n = sp >> 12;
  float a0 = bias[co], a1 = 0.f, a2 = 0.f, a3 = 0.f;
  const float* wb = w + co * 576;
  #pragma unroll
  for (int ky = 0; ky < 3; ky++){
    int iy = yy - 1 + ky; if ((unsigned)iy >= 64u) continue;
    #pragma unroll
    for (int kx = 0; kx < 3; kx++){
      int ix = xx - 1 + kx; if ((unsigned)ix >= 64u) continue;
      int spt = (n << 12) + (iy << 6) + ix;
      int k = idxm[spt];
      const float4* c4 = (const float4*)(cb + (k << 6));
      int tp = ky * 3 + kx;
      #pragma unroll
      for (int q = 0; q < 16; q += 4){
        float4 ca = c4[q], cb2 = c4[q + 1], cc = c4[q + 2], cd = c4[q + 3];
        a0 = fmaf(ca.x, wb[(4*q+0)*9+tp], a0);  a1 = fmaf(ca.y, wb[(4*q+1)*9+tp], a1);
        a2 = fmaf(ca.z, wb[(4*q+2)*9+tp], a2);  a3 = fmaf(ca.w, wb[(4*q+3)*9+tp], a3);
        a0 = fmaf(cb2.x, wb[(4*q+4)*9+tp], a0); a1 = fmaf(cb2.y, wb[(4*q+5)*9+tp], a1);
        a2 = fmaf(cb2.z, wb[(4*q+6)*9+tp], a2); a3 = fmaf(cb2.w, wb[(4*q+7)*9+tp], a3);
        a0 = fmaf(cc.x, wb[(4*q+8)*9+tp], a0);  a1 = fmaf(cc.y, wb[(4*q+9)*9+tp], a1);
        a2 = fmaf(cc.z, wb[(4*q+10)*9+tp], a2); a3 = fmaf(cc.w, wb[(4*q+11)*9+tp], a3);
        a0 = fmaf(cd.x, wb[(4*q+12)*9+tp], a0); a1 = fmaf(cd.y, wb[(4*q+13)*9+tp], a1);
        a2 = fmaf(cd.z, wb[(4*q+14)*9+tp], a2); a3 = fmaf(cd.w, wb[(4*q+15)*9+tp], a3);
      }
    }
  }
  out[((size_t)(n * 4 + co) << 12) + (yy << 6) + xx] = (a0 + a1) + (a2 + a3);
}

// ---------------- transposed conv k3 s2 p1 op1, 8 co/thread, optional input-BN, fused stats ----------------
template<int CI, int CO, int IHt, int IWt, bool APPLY>
__global__ __launch_bounds__(256) void convT_cob8(const float* __restrict__ in, const float* __restrict__ w,
    const float* __restrict__ bias, const float* __restrict__ ssIn, float* __restrict__ out,
    double* __restrict__ part){
  constexpr int SB = IHt * IWt / 256;
  constexpr int COG = CO / 8;
  constexpr int P = 16 * SB;
  const int OW = IWt * 2;
  int idx = blockIdx.x * 256 + threadIdx.x;
  int ix = idx % IWt, iy = (idx / IWt) % IHt;
  int cog = (idx / (IWt * IHt)) % COG, n = idx / (IWt * IHt * COG);
  cog = __builtin_amdgcn_readfirstlane(cog);
  n   = __builtin_amdgcn_readfirstlane(n);
  float a00[8], a01[8], a10[8], a11[8];
  #pragma unroll
  for (int j = 0; j < 8; j++){ float b = bias[cog * 8 + j]; a00[j] = b; a01[j] = b; a10[j] = b; a11[j] = b; }
  bool okx = (ix + 1 < IWt), oky = (iy + 1 < IHt);
  int ixp = okx ? ix + 1 : ix, iyp = oky ? iy + 1 : iy;
  const float* ip = in + (size_t)n * CI * IHt * IWt;
  #pragma unroll 4
  for (int ci = 0; ci < CI; ci++){
    const float* p = ip + ci * IHt * IWt;
    float v00 = p[iy * IWt + ix];
    float v01 = p[iy * IWt + ixp];
    float v10 = p[iyp * IWt + ix];
    float v11 = p[iyp * IWt + ixp];
    if (APPLY){
      float sc = ssIn[ci], sh = ssIn[CI + ci];
      v00 = lrelu(fmaf(v00, sc, sh));
      v01 = lrelu(fmaf(v01, sc, sh));
      v10 = lrelu(fmaf(v10, sc, sh));
      v11 = lrelu(fmaf(v11, sc, sh));
    }
    if (!okx) v01 = 0.f;
    if (!oky) v10 = 0.f;
    if (!(okx && oky)) v11 = 0.f;
    const float* wp = w + ((size_t)ci * CO + cog * 8) * 9;
    #pragma unroll
    for (int j = 0; j < 8; j++){
      const float* q = wp + j * 9;
      a00[j] = fmaf(q[4], v00, a00[j]);
      a01[j] = fmaf(q[3], v01, a01[j]); a01[j] = fmaf(q[5], v00, a01[j]);
      a10[j] = fmaf(q[1], v10, a10[j]); a10[j] = fmaf(q[7], v00, a10[j]);
      a11[j] = fmaf(q[0], v11, a11[j]); a11[j] = fmaf(q[2], v10, a11[j]);
      a11[j] = fmaf(q[6], v01, a11[j]); a11[j] = fmaf(q[8], v00, a11[j]);
    }
  }
  float sums[8], sqs[8];
  #pragma unroll
  for (int j = 0; j < 8; j++){
    float* o = out + (((size_t)n * CO + cog * 8 + j) * (IHt * 2) + 2 * iy) * OW + 2 * ix;
    float2 r0; r0.x = a00[j]; r0.y = a01[j];
    float2 r1; r1.x = a10[j]; r1.y = a11[j];
    *(float2*)o = r0;
    *(float2*)(o + OW) = r1;
    sums[j] = (a00[j] + a01[j]) + (a10[j] + a11[j]);
    sqs[j] = (a00[j] * a00[j] + a01[j] * a01[j]) + (a10[j] * a10[j] + a11[j] * a11[j]);
  }
  __shared__ float sred[256 * 16];
  int sb = blockIdx.x % SB;
  stats_epilogue<8>(sums, sqs, part, cog * 8, P, n * SB + sb, sred);
}

// ---------------- d3: 32->3 @256x256, 8-wide, fused bn4-apply, tanh ----------------
__global__ __launch_bounds__(256) void d3_conv(const float* __restrict__ F, const float* __restrict__ w,
    const float* __restrict__ bias, const float* __restrict__ ss, float* __restrict__ out){
  int idx = blockIdx.x * 256 + threadIdx.x;
  int ox8 = idx & 31, oy = (idx >> 5) & 255, n = idx >> 13;
  int ox0 = ox8 * 8;
  float acc[3][8];
  #pragma unroll
  for (int co = 0; co < 3; co++){
    float b = bias[co];
    #pragma unroll
    for (int j = 0; j < 8; j++) acc[co][j] = b;
  }
  const float* base = F + (size_t)n * 32 * 65536;
  bool x0ok = (ox8 > 0), x9ok = (ox8 < 31);
  int offL = x0ok ? -1 : 0;
  int offR = x9ok ? 8 : 0;
  #pragma unroll 2
  for (int ci = 0; ci < 32; ci++){
    const float* pl = base + ci * 65536;
    float sc = ss[ci], sh = ss[32 + ci];
    #pragma unroll
    for (int ky = 0; ky < 3; ky++){
      int iy = oy - 1 + ky;
      if (iy >= 0 && iy <= 255){
        const float* row = pl + iy * 256 + ox0;
        float l  = row[offL];
        float4 m = *(const float4*)row;
        float4 r = *(const float4*)(row + 4);
        float t8 = row[offR];
        float u[10];
        u[0] = x0ok ? lrelu(fmaf(l, sc, sh)) : 0.f;
        u[1] = lrelu(fmaf(m.x, sc, sh)); u[2] = lrelu(fmaf(m.y, sc, sh));
        u[3] = lrelu(fmaf(m.z, sc, sh)); u[4] = lrelu(fmaf(m.w, sc, sh));
        u[5] = lrelu(fmaf(r.x, sc, sh)); u[6] = lrelu(fmaf(r.y, sc, sh));
        u[7] = lrelu(fmaf(r.z, sc, sh)); u[8] = lrelu(fmaf(r.w, sc, sh));
        u[9] = x9ok ? lrelu(fmaf(t8, sc, sh)) : 0.f;
        #pragma unroll
        for (int co = 0; co < 3; co++){
          const float* wp = w + ((co * 32 + ci) * 9) + ky * 3;
          #pragma unroll
          for (int j = 0; j < 8; j++){
            acc[co][j] = fmaf(u[j],     wp[0], acc[co][j]);
            acc[co][j] = fmaf(u[j + 1], wp[1], acc[co][j]);
            acc[co][j] = fmaf(u[j + 2], wp[2], acc[co][j]);
          }
        }
      }
    }
  }
  #pragma unroll
  for (int co = 0; co < 3; co++){
    float4 s0, s1;
    s0.x = tanh_fast(acc[co][0]); s0.y = tanh_fast(acc[co][1]);
    s0.z = tanh_fast(acc[co][2]); s0.w = tanh_fast(acc[co][3]);
    s1.x = tanh_fast(acc[co][4]); s1.y = tanh_fast(acc[co][5]);
    s1.z = tanh_fast(acc[co][6]); s1.w = tanh_fast(acc[co][7]);
    float* o = out + ((size_t)(n * 3 + co) * 256 + oy) * 256 + ox0;
    *(float4*)o = s0;
    *(float4*)(o + 4) = s1;
  }
}

// ---------------- launch ----------------
extern "C" void kernel_launch(void* const* d_in, const int* in_sizes, int n_in,
                              void* d_out, int out_size, void* d_ws, size_t ws_size,
                              hipStream_t stream){
  const float* x      = (const float*)d_in[0];
  const float* cb     = (const float*)d_in[1];
  const float* e1_w   = (const float*)d_in[2];
  const float* e1_b   = (const float*)d_in[3];
  const float* bn1_g  = (const float*)d_in[4];
  const float* bn1_b  = (const float*)d_in[5];
  const float* e2_w   = (const float*)d_in[6];
  const float* e2_b   = (const float*)d_in[7];
  const float* bn2_g  = (const float*)d_in[8];
  const float* bn2_b  = (const float*)d_in[9];
  const float* preq_w = (const float*)d_in[10];
  const float* preq_b = (const float*)d_in[11];
  const float* postq_w= (const float*)d_in[12];
  const float* postq_b= (const float*)d_in[13];
  const float* d1_w   = (const float*)d_in[14];
  const float* d1_b   = (const float*)d_in[15];
  const float* bn3_g  = (const float*)d_in[16];
  const float* bn3_b  = (const float*)d_in[17];
  const float* d2_w   = (const float*)d_in[18];
  const float* d2_b   = (const float*)d_in[19];
  const float* bn4_g  = (const float*)d_in[20];
  const float* bn4_b  = (const float*)d_in[21];
  const float* d3_w   = (const float*)d_in[22];
  const float* d3_b   = (const float*)d_in[23];
  float* out = (float*)d_out;
  char* ws = (char*)d_ws;

  double* losspart = (double*)ws;                        // 2048 B
  int*    flagcnt  = (int*)(ws + 2048);                  // 64 B zeroed
  float*  ss       = (float*)(ws + 4096);                // 576 B
  double* cb64     = (double*)(ws + 8192);               // 512 KB
  double* cbn64    = (double*)(ws + 532480);             // 8 KB
  float*  cbn32    = (float*)(ws + 540672);              // 4 KB
  unsigned short* cbh = (unsigned short*)(ws + 544768);  // 128 KB
  unsigned short* cbl = (unsigned short*)(ws + 675840);  // 128 KB
  int*    flaglist = (int*)(ws + 806912);                // 256 KB
  int*    idx      = (int*)(ws + 1069056);               // 256 KB
  double* part_e1  = (double*)(ws + 1331200);            // 128 KB
  double* part_e2  = (double*)(ws + 1462272);            // 16 KB
  double* part_d1  = (double*)(ws + 1478656);            // 64 KB
  double* part_d2  = (double*)(ws + 1544192);            // 512 KB
  float*  A        = (float*)(ws + 2097152);             // 16.78 MB
  float*  B        = (float*)(ws + 18874368);            // 1 MB
  float*  Zq       = (float*)(ws + 19922944);            // 16.78 MB
  float*  F        = (float*)(ws + 36700160);            // 134.2 MB

  float *ss1 = ss + 0, *ss2 = ss + 32, *ss3 = ss + 48, *ss4 = ss + 80;
  float* D = B;   // B dead after preq

  hipMemsetAsync(flagcnt, 0, 64, stream);
  vq_prep<<<4, 256, 0, stream>>>(cb, cb64, cbn64, cbn32, cbh, cbl);

  // encoder
  e1_conv<<<512, 256, 0, stream>>>(x, e1_w, e1_b, A, part_e1);
  bn_red_fin<<<16, 256, 0, stream>>>(part_e1, 512, bn1_g, bn1_b, ss1, 16, 262144.0);
  e2_conv<<<256, 256, 0, stream>>>(A, e2_w, e2_b, ss1, B, part_e2);
  bn_red_fin<<<4, 256, 0, stream>>>(part_e2, 256, bn2_g, bn2_b, ss2, 4, 65536.0);
  preq_conv<<<4096, 256, 0, stream>>>(B, preq_w, preq_b, ss2, Zq);

  // VQ
  vq_screen_mfma<<<1024, 256, 0, stream>>>(Zq, cbh, cbl, cbn32, idx, flagcnt, flaglist);
  vq_refine<<<128, 256, 0, stream>>>(Zq, cb64, cbn64, flagcnt, flaglist, idx);
  vq_loss<<<256, 256, 0, stream>>>(Zq, cb, idx, losspart);

  // decoder
  postq_conv<<<1024, 256, 0, stream>>>(cb, idx, postq_w, postq_b, D);
  convT_cob8<4, 16, 64, 64, false><<<512, 256, 0, stream>>>(D, d1_w, d1_b, nullptr, A, part_d1);
  bn_red_fin<<<16, 256, 0, stream>>>(part_d1, 256, bn3_g, bn3_b, ss3, 16, 262144.0);
  convT_cob8<16, 32, 128, 128, true><<<4096, 256, 0, stream>>>(A, d2_w, d2_b, ss3, F, part_d2);
  bn_red_fin<<<32, 256, 0, stream>>>(part_d2, 1024, bn4_g, bn4_b, ss4, 32, 1048576.0);
  d3_conv<<<512, 256, 0, stream>>>(F, d3_w, d3_b, ss4, out);

  write_loss<<<1, 256, 0, stream>>>(losspart, out + 3145728);
}

// Round 5
// 410.644 us; speedup vs baseline: 3.8417x; 1.0084x over previous
//
#include <hip/hip_runtime.h>
#include <math.h>

#define EPSV 1e-5
#define SLOPE 0.1f

typedef __attribute__((ext_vector_type(4))) float f32x4;
typedef __attribute__((ext_vector_type(8))) short short8x;

__device__ __forceinline__ float lrelu(float x){ return x >= 0.f ? x : SLOPE * x; }
__device__ __forceinline__ float tanh_fast(float x){
  float e = __expf(2.f * x);
  return 1.f - 2.f / (e + 1.f);
}
__device__ __forceinline__ unsigned bf16rne(float f){
  unsigned u = __float_as_uint(f);
  u += 0x7fff + ((u >> 16) & 1);
  return u >> 16;
}

// ---- block BN-stats epilogue: per-thread CL channel sums/sqs -> f64 partials ----
template<int CL>
__device__ __forceinline__ void stats_epilogue(const float* sums, const float* sqs,
    double* __restrict__ part, int chbase, int P, int p, float* sred){
  const int C2 = 2 * CL;
  int t = threadIdx.x;
  #pragma unroll
  for (int c = 0; c < CL; c++){
    sred[t * C2 + c] = sums[c];
    sred[t * C2 + CL + c] = sqs[c];
  }
  __syncthreads();
  if (t < 64){
    int c = t % C2;
    int g = t / C2;
    const int G = 64 / C2;
    const int R = 256 / G;
    double s = 0;
    for (int r = g * R; r < (g + 1) * R; r++) s += (double)sred[r * C2 + c];
    #pragma unroll
    for (int off = C2; off < 64; off <<= 1) s += __shfl_xor(s, off);
    if (t < C2){
      int ch = chbase + (c < CL ? c : c - CL);
      part[(size_t)ch * 2 * P + (c < CL ? 0 : P) + p] = s;
    }
  }
}

// ---- reduce partials + finalize scale/shift ----
__global__ __launch_bounds__(256) void bn_red_fin(const double* __restrict__ part, int P,
    const float* __restrict__ g, const float* __restrict__ b, float* __restrict__ ss, int C, double count){
  int c = blockIdx.x;
  __shared__ double r0[256], r1[256];
  int t = threadIdx.x;
  double s = 0, q = 0;
  for (int p = t; p < P; p += 256){
    s += part[(size_t)c * 2 * P + p];
    q += part[(size_t)c * 2 * P + P + p];
  }
  r0[t] = s; r1[t] = q; __syncthreads();
  for (int o = 128; o > 0; o >>= 1){
    if (t < o){ r0[t] += r0[t + o]; r1[t] += r1[t + o]; }
    __syncthreads();
  }
  if (t == 0){
    double m = r0[0] / count;
    double var = r1[0] / count - m * m;
    double scale = (double)g[c] / sqrt(var + EPSV);
    ss[c] = (float)scale;
    ss[C + c] = (float)((double)b[c] - m * scale);
  }
}

// ---------------- e1: 3->16 s2, 256->128, 2 x-outputs/thread, fused bn1-stats ----------------
__global__ __launch_bounds__(256) void e1_conv(const float* __restrict__ x, const float* __restrict__ w,
    const float* __restrict__ bias, float* __restrict__ out, double* __restrict__ part){
  int idx = blockIdx.x * 256 + threadIdx.x;
  int ox2 = idx & 63, oy = (idx >> 6) & 127, n = idx >> 13;
  float acc[16][2];
  #pragma unroll
  for (int co = 0; co < 16; co++){ float b = bias[co]; acc[co][0] = b; acc[co][1] = b; }
  int ix0 = 4 * ox2 - 1;
  int lclamp = (ox2 > 0) ? ix0 : 0;
  const float* xp = x + (size_t)n * 3 * 65536;
  #pragma unroll
  for (int ci = 0; ci < 3; ci++){
    const float* pl = xp + ci * 65536;
    #pragma unroll
    for (int ky = 0; ky < 3; ky++){
      int iy = 2 * oy - 1 + ky;
      if (iy >= 0){
        const float* row = pl + iy * 256;
        float l = row[lclamp];
        float4 m = *(const float4*)(row + ix0 + 1);
        float v0 = (ox2 > 0) ? l : 0.f;
        #pragma unroll
        for (int co = 0; co < 16; co++){
          const float* wp = w + ((co * 3 + ci) * 3 + ky) * 3;
          acc[co][0] = fmaf(v0,  wp[0], acc[co][0]);
          acc[co][0] = fmaf(m.x, wp[1], acc[co][0]);
          acc[co][0] = fmaf(m.y, wp[2], acc[co][0]);
          acc[co][1] = fmaf(m.y, wp[0], acc[co][1]);
          acc[co][1] = fmaf(m.z, wp[1], acc[co][1]);
          acc[co][1] = fmaf(m.w, wp[2], acc[co][1]);
        }
      }
    }
  }
  float sums[16], sqs[16];
  #pragma unroll
  for (int co = 0; co < 16; co++){
    float2 st; st.x = acc[co][0]; st.y = acc[co][1];
    *(float2*)(out + ((size_t)(n * 16 + co) * 128 + oy) * 128 + 2 * ox2) = st;
    sums[co] = acc[co][0] + acc[co][1];
    sqs[co] = acc[co][0] * acc[co][0] + acc[co][1] * acc[co][1];
  }
  __shared__ float sred[256 * 32];
  stats_epilogue<16>(sums, sqs, part, 0, 512, blockIdx.x, sred);
}

// ---------------- e2: 16->4 s2 with fused bn1-apply on loads + bn2-stats ----------------
__global__ __launch_bounds__(256) void e2_conv(const float* __restrict__ in, const float* __restrict__ w,
    const float* __restrict__ bias, const float* __restrict__ ssIn, float* __restrict__ out,
    double* __restrict__ part){
  int idx = blockIdx.x * 256 + threadIdx.x;
  int ox = idx & 63, oy = (idx >> 6) & 63, n = idx >> 12;
  float acc[4];
  #pragma unroll
  for (int j = 0; j < 4; j++) acc[j] = bias[j];
  int iy0 = oy * 2 - 1, ix0 = ox * 2 - 1;
  const float* ip = in + (size_t)n * 16 * 16384;
  #pragma unroll
  for (int ky = 0; ky < 3; ky++){
    int iy = iy0 + ky; if ((unsigned)iy >= 128u) continue;
    #pragma unroll
    for (int kx = 0; kx < 3; kx++){
      int ix = ix0 + kx; if ((unsigned)ix >= 128u) continue;
      const float* r = ip + iy * 128 + ix;
      #pragma unroll
      for (int ci = 0; ci < 16; ci++){
        float v = lrelu(fmaf(r[ci * 16384], ssIn[ci], ssIn[16 + ci]));
        #pragma unroll
        for (int co = 0; co < 4; co++)
          acc[co] = fmaf(v, w[(co * 16 + ci) * 9 + ky * 3 + kx], acc[co]);
      }
    }
  }
  float sums[4], sqs[4];
  #pragma unroll
  for (int co = 0; co < 4; co++){
    out[(((size_t)n * 4 + co) * 64 + oy) * 64 + ox] = acc[co];
    sums[co] = acc[co];
    sqs[co] = acc[co] * acc[co];
  }
  __shared__ float sred[256 * 8];
  stats_epilogue<4>(sums, sqs, part, 0, 256, blockIdx.x, sred);
}

// ---------------- preq: fused bn2-apply, output plane layout Zq[coq][pos][4] ----------------
__global__ __launch_bounds__(256) void preq_conv(const float* __restrict__ in, const float* __restrict__ w,
    const float* __restrict__ bias, const float* __restrict__ ssIn, float* __restrict__ Zq){
  int idx = blockIdx.x * 256 + threadIdx.x;
  int sp = idx & 65535;
  int coq = idx >> 16;
  int x = sp & 63, y = (sp >> 6) & 63, n = sp >> 12;
  float scv[4] = {ssIn[0], ssIn[1], ssIn[2], ssIn[3]};
  float shv[4] = {ssIn[4], ssIn[5], ssIn[6], ssIn[7]};
  float a0 = bias[coq * 4 + 0], a1 = bias[coq * 4 + 1], a2 = bias[coq * 4 + 2], a3 = bias[coq * 4 + 3];
  const float* ip = in + (size_t)n * 4 * 4096;
  #pragma unroll
  for (int ky = 0; ky < 3; ky++){
    int iy = y - 1 + ky; if ((unsigned)iy >= 64u) continue;
    #pragma unroll
    for (int kx = 0; kx < 3; kx++){
      int ix = x - 1 + kx; if ((unsigned)ix >= 64u) continue;
      #pragma unroll
      for (int ci = 0; ci < 4; ci++){
        float v = lrelu(fmaf(ip[ci * 4096 + iy * 64 + ix], scv[ci], shv[ci]));
        const float* wp = w + ((coq * 4) * 4 + ci) * 9 + ky * 3 + kx;
        a0 = fmaf(v, wp[0], a0);
        a1 = fmaf(v, wp[36], a1);
        a2 = fmaf(v, wp[72], a2);
        a3 = fmaf(v, wp[108], a3);
      }
    }
  }
  float4 o; o.x = a0; o.y = a1; o.z = a2; o.w = a3;
  ((float4*)Zq)[coq * 65536 + sp] = o;
}

// ---------------- VQ prep: f64 codebook + norms + split-bf16 codebook (+flagcnt zero) ----------------
__global__ void vq_prep(const float* __restrict__ cb, double* __restrict__ cb64, double* __restrict__ cbn64,
    float* __restrict__ cbn32, unsigned short* __restrict__ cbh, unsigned short* __restrict__ cbl,
    int* __restrict__ flagcnt){
  int k = blockIdx.x * 256 + threadIdx.x;
  if (k == 0) flagcnt[0] = 0;
  if (k >= 1024) return;
  double s = 0;
  for (int d = 0; d < 64; d++){
    float v = cb[k * 64 + d];
    cb64[(size_t)k * 64 + d] = (double)v;
    s = fma((double)v, (double)v, s);
    unsigned h = bf16rne(v);
    float hf = __uint_as_float(h << 16);
    unsigned l = bf16rne(v - hf);
    cbh[k * 64 + d] = (unsigned short)h;
    cbl[k * 64 + d] = (unsigned short)l;
  }
  cbn64[k] = s;
  cbn32[k] = (float)s;
}

// ---------------- VQ screen via MFMA (split-bf16 scores + tie flags) ----------------
__global__ __launch_bounds__(256) void vq_screen_mfma(const float* __restrict__ Zq,
    const unsigned short* __restrict__ cbh, const unsigned short* __restrict__ cbl,
    const float* __restrict__ cbn32, int* __restrict__ idxout,
    int* __restrict__ flagcnt, int* __restrict__ flaglist){
  __shared__ unsigned short lcb[32 * 64 * 8];
  __shared__ float lcn[128];
  int t = threadIdx.x;
  int lane = t & 63;
  int w = t >> 6;
  int col = lane & 15, hg = lane >> 4;
  int pos0 = blockIdx.x * 64 + w * 16;
  int pos = pos0 + col;
  const float4* Zq4 = (const float4*)Zq;
  short8x zh[2], zl[2];
  #pragma unroll
  for (int kc = 0; kc < 2; kc++){
    float4 f0 = Zq4[(size_t)(8 * kc + 2 * hg) * 65536 + pos];
    float4 f1 = Zq4[(size_t)(8 * kc + 2 * hg + 1) * 65536 + pos];
    float zv[8] = {f0.x, f0.y, f0.z, f0.w, f1.x, f1.y, f1.z, f1.w};
    union { unsigned u[4]; short8x v; } H, L;
    #pragma unroll
    for (int j = 0; j < 4; j++){
      unsigned h0 = bf16rne(zv[2 * j]);
      unsigned h1 = bf16rne(zv[2 * j + 1]);
      float hf0 = __uint_as_float(h0 << 16);
      float hf1 = __uint_as_float(h1 << 16);
      unsigned l0 = bf16rne(zv[2 * j] - hf0);
      unsigned l1 = bf16rne(zv[2 * j + 1] - hf1);
      H.u[j] = h0 | (h1 << 16);
      L.u[j] = l0 | (l1 << 16);
    }
    zh[kc] = H.v; zl[kc] = L.v;
  }
  float best = 3.0e38f, sec = 3.0e38f; int bidx = 0;
  for (int step = 0; step < 8; step++){
    int code0 = step * 128;
    __syncthreads();
    #pragma unroll
    for (int i = 0; i < 8; i++){
      int piece = i * 256 + t;
      int fb = piece >> 6, pl = piece & 63;
      int g = fb >> 2, kc = (fb >> 1) & 1, sp = fb & 1;
      const unsigned short* src = (sp ? cbl : cbh)
          + ((size_t)(code0 + g * 16 + (pl & 15)) << 6) + kc * 32 + ((pl >> 4) << 3);
      *(uint4*)&lcb[piece * 8] = *(const uint4*)src;
    }
    if (t < 128) lcn[t] = cbn32[code0 + t];
    __syncthreads();
    #pragma unroll 2
    for (int g = 0; g < 8; g++){
      f32x4 acc = {0.f, 0.f, 0.f, 0.f};
      const short8x* lc8 = (const short8x*)lcb;
      short8x Ah0 = lc8[(g * 4 + 0) * 64 + lane];
      short8x Al0 = lc8[(g * 4 + 1) * 64 + lane];
      short8x Ah1 = lc8[(g * 4 + 2) * 64 + lane];
      short8x Al1 = lc8[(g * 4 + 3) * 64 + lane];
      acc = __builtin_amdgcn_mfma_f32_16x16x32_bf16(Ah0, zh[0], acc, 0, 0, 0);
      acc = __builtin_amdgcn_mfma_f32_16x16x32_bf16(Ah1, zh[1], acc, 0, 0, 0);
      acc = __builtin_amdgcn_mfma_f32_16x16x32_bf16(Ah0, zl[0], acc, 0, 0, 0);
      acc = __builtin_amdgcn_mfma_f32_16x16x32_bf16(Ah1, zl[1], acc, 0, 0, 0);
      acc = __builtin_amdgcn_mfma_f32_16x16x32_bf16(Al0, zh[0], acc, 0, 0, 0);
      acc = __builtin_amdgcn_mfma_f32_16x16x32_bf16(Al1, zh[1], acc, 0, 0, 0);
      int cbase = code0 + g * 16 + 4 * hg;
      #pragma unroll
      for (int r = 0; r < 4; r++){
        float s = fmaf(acc[r], -2.0f, lcn[g * 16 + 4 * hg + r]);
        float mx = fmaxf(s, best);
        sec = fminf(sec, mx);
        if (s < best){ best = s; bidx = cbase + r; }
      }
    }
  }
  #pragma unroll
  for (int off = 16; off <= 32; off <<= 1){
    float ob = __shfl_xor(best, off);
    float os = __shfl_xor(sec, off);
    int oi = __shfl_xor(bidx, off);
    sec = fminf(fminf(sec, os), fmaxf(best, ob));
    if (ob < best){ best = ob; bidx = oi; }
  }
  if (hg == 0){
    idxout[pos] = bidx;
    if (sec - best < 1.2e-2f){
      int slot = atomicAdd(flagcnt, 1);
      flaglist[slot] = pos;
    }
  }
}

// ---------------- VQ refine: exact f64 re-rank of near-ties ----------------
__global__ __launch_bounds__(256) void vq_refine(const float* __restrict__ Zq, const double* __restrict__ cb64,
    const double* __restrict__ cbn64, const int* __restrict__ flagcnt, const int* __restrict__ flaglist,
    int* __restrict__ idxout){
  int gw = (blockIdx.x * 256 + threadIdx.x) >> 6;
  int lane = threadIdx.x & 63;
  int nf = flagcnt[0];
  for (int f = gw; f < nf; f += 512){
    int pos = flaglist[f];
    float zr[64];
    #pragma unroll
    for (int q = 0; q < 16; q++){
      float4 v = ((const float4*)Zq)[q * 65536 + pos];
      zr[4 * q] = v.x; zr[4 * q + 1] = v.y; zr[4 * q + 2] = v.z; zr[4 * q + 3] = v.w;
    }
    double best = 1e300; int bi = 1 << 30;
    for (int k = lane; k < 1024; k += 64){
      const double* c = cb64 + (size_t)k * 64;
      double a0 = 0, a1 = 0, a2 = 0, a3 = 0;
      #pragma unroll
      for (int d = 0; d < 64; d += 4){
        a0 = fma(c[d], (double)zr[d], a0);
        a1 = fma(c[d + 1], (double)zr[d + 1], a1);
        a2 = fma(c[d + 2], (double)zr[d + 2], a2);
        a3 = fma(c[d + 3], (double)zr[d + 3], a3);
      }
      double s = cbn64[k] - 2.0 * ((a0 + a1) + (a2 + a3));
      if (s < best){ best = s; bi = k; }
    }
    #pragma unroll
    for (int o = 32; o > 0; o >>= 1){
      double ob = __shfl_xor(best, o);
      int oi = __shfl_xor(bi, o);
      if (ob < best || (ob == best && oi < bi)){ best = ob; bi = oi; }
    }
    if (lane == 0) idxout[pos] = bi;
  }
}

__global__ void write_loss(const double* __restrict__ losspart, float* __restrict__ out){
  __shared__ double sb[256];
  int t = threadIdx.x;
  sb[t] = losspart[t];
  __syncthreads();
  for (int o = 128; o > 0; o >>= 1){
    if (t < o) sb[t] += sb[t + o];
    __syncthreads();
  }
  if (t == 0) out[0] = (float)(1.25 * sb[0] / (65536.0 * 64.0));
}

// ---------------- postq: conv over cb[idx] field, with fused VQ loss on co==0 blocks ----------------
__global__ __launch_bounds__(256) void postq_conv(const float* __restrict__ cb, const int* __restrict__ idxm,
    const float* __restrict__ w, const float* __restrict__ bias, float* __restrict__ out,
    const float* __restrict__ Zq, double* __restrict__ losspart){
  int gid = blockIdx.x * 256 + threadIdx.x;
  int sp = gid & 65535;
  int co = gid >> 16;
  co = __builtin_amdgcn_readfirstlane(co);
  int xx = sp & 63, yy = (sp >> 6) & 63, n = sp >> 12;
  float a0 = bias[co], a1 = 0.f, a2 = 0.f, a3 = 0.f;
  const float* wb = w + co * 576;
  #pragma unroll
  for (int ky = 0; ky < 3; ky++){
    int iy = yy - 1 + ky; if ((unsigned)iy >= 64u) continue;
    #pragma unroll
    for (int kx = 0; kx < 3; kx++){
      int ix = xx - 1 + kx; if ((unsigned)ix >= 64u) continue;
      int spt = (n << 12) + (iy << 6) + ix;
      int k = idxm[spt];
      const float4* c4 = (const float4*)(cb + (k << 6));
      int tp = ky * 3 + kx;
      #pragma unroll
      for (int q = 0; q < 16; q += 4){
        float4 ca = c4[q], cb2 = c4[q + 1], cc = c4[q + 2], cd = c4[q + 3];
        a0 = fmaf(ca.x, wb[(4*q+0)*9+tp], a0);  a1 = fmaf(ca.y, wb[(4*q+1)*9+tp], a1);
        a2 = fmaf(ca.z, wb[(4*q+2)*9+tp], a2);  a3 = fmaf(ca.w, wb[(4*q+3)*9+tp], a3);
        a0 = fmaf(cb2.x, wb[(4*q+4)*9+tp], a0); a1 = fmaf(cb2.y, wb[(4*q+5)*9+tp], a1);
        a2 = fmaf(cb2.z, wb[(4*q+6)*9+tp], a2); a3 = fmaf(cb2.w, wb[(4*q+7)*9+tp], a3);
        a0 = fmaf(cc.x, wb[(4*q+8)*9+tp], a0);  a1 = fmaf(cc.y, wb[(4*q+9)*9+tp], a1);
        a2 = fmaf(cc.z, wb[(4*q+10)*9+tp], a2); a3 = fmaf(cc.w, wb[(4*q+11)*9+tp], a3);
        a0 = fmaf(cd.x, wb[(4*q+12)*9+tp], a0); a1 = fmaf(cd.y, wb[(4*q+13)*9+tp], a1);
        a2 = fmaf(cd.z, wb[(4*q+14)*9+tp], a2); a3 = fmaf(cd.w, wb[(4*q+15)*9+tp], a3);
      }
    }
  }
  out[((size_t)(n * 4 + co) << 12) + (yy << 6) + xx] = (a0 + a1) + (a2 + a3);
  // fused VQ loss (deterministic: blockIdx < 256 exactly covers co==0, one thread per position)
  if (co == 0){
    int k = idxm[sp];
    const float4* c4 = (const float4*)(cb + (k << 6));
    double l = 0;
    #pragma unroll
    for (int q = 0; q < 16; q++){
      float4 z = ((const float4*)Zq)[q * 65536 + sp];
      float4 c = c4[q];
      float d0 = z.x - c.x, d1 = z.y - c.y, d2 = z.z - c.z, d3 = z.w - c.w;
      l += (double)d0 * d0 + (double)d1 * d1 + (double)d2 * d2 + (double)d3 * d3;
    }
    __shared__ double sb[256];
    int t = threadIdx.x;
    sb[t] = l; __syncthreads();
    for (int o = 128; o > 0; o >>= 1){
      if (t < o) sb[t] += sb[t + o];
      __syncthreads();
    }
    if (t == 0) losspart[blockIdx.x] = sb[0];
  }
}

// ---------------- transposed conv k3 s2 p1 op1, 8 co/thread, optional input-BN, fused stats ----------------
template<int CI, int CO, int IHt, int IWt, bool APPLY>
__global__ __launch_bounds__(256) void convT_cob8(const float* __restrict__ in, const float* __restrict__ w,
    const float* __restrict__ bias, const float* __restrict__ ssIn, float* __restrict__ out,
    double* __restrict__ part){
  constexpr int SB = IHt * IWt / 256;
  constexpr int COG = CO / 8;
  constexpr int P = 16 * SB;
  const int OW = IWt * 2;
  int idx = blockIdx.x * 256 + threadIdx.x;
  int ix = idx % IWt, iy = (idx / IWt) % IHt;
  int cog = (idx / (IWt * IHt)) % COG, n = idx / (IWt * IHt * COG);
  cog = __builtin_amdgcn_readfirstlane(cog);
  n   = __builtin_amdgcn_readfirstlane(n);
  float a00[8], a01[8], a10[8], a11[8];
  #pragma unroll
  for (int j = 0; j < 8; j++){ float b = bias[cog * 8 + j]; a00[j] = b; a01[j] = b; a10[j] = b; a11[j] = b; }
  bool okx = (ix + 1 < IWt), oky = (iy + 1 < IHt);
  int ixp = okx ? ix + 1 : ix, iyp = oky ? iy + 1 : iy;
  const float* ip = in + (size_t)n * CI * IHt * IWt;
  #pragma unroll 4
  for (int ci = 0; ci < CI; ci++){
    const float* p = ip + ci * IHt * IWt;
    float v00 = p[iy * IWt + ix];
    float v01 = p[iy * IWt + ixp];
    float v10 = p[iyp * IWt + ix];
    float v11 = p[iyp * IWt + ixp];
    if (APPLY){
      float sc = ssIn[ci], sh = ssIn[CI + ci];
      v00 = lrelu(fmaf(v00, sc, sh));
      v01 = lrelu(fmaf(v01, sc, sh));
      v10 = lrelu(fmaf(v10, sc, sh));
      v11 = lrelu(fmaf(v11, sc, sh));
    }
    if (!okx) v01 = 0.f;
    if (!oky) v10 = 0.f;
    if (!(okx && oky)) v11 = 0.f;
    const float* wp = w + ((size_t)ci * CO + cog * 8) * 9;
    #pragma unroll
    for (int j = 0; j < 8; j++){
      const float* q = wp + j * 9;
      a00[j] = fmaf(q[4], v00, a00[j]);
      a01[j] = fmaf(q[3], v01, a01[j]); a01[j] = fmaf(q[5], v00, a01[j]);
      a10[j] = fmaf(q[1], v10, a10[j]); a10[j] = fmaf(q[7], v00, a10[j]);
      a11[j] = fmaf(q[0], v11, a11[j]); a11[j] = fmaf(q[2], v10, a11[j]);
      a11[j] = fmaf(q[6], v01, a11[j]); a11[j] = fmaf(q[8], v00, a11[j]);
    }
  }
  float sums[8], sqs[8];
  #pragma unroll
  for (int j = 0; j < 8; j++){
    float* o = out + (((size_t)n * CO + cog * 8 + j) * (IHt * 2) + 2 * iy) * OW + 2 * ix;
    float2 r0; r0.x = a00[j]; r0.y = a01[j];
    float2 r1; r1.x = a10[j]; r1.y = a11[j];
    *(float2*)o = r0;
    *(float2*)(o + OW) = r1;
    sums[j] = (a00[j] + a01[j]) + (a10[j] + a11[j]);
    sqs[j] = (a00[j] * a00[j] + a01[j] * a01[j]) + (a10[j] * a10[j] + a11[j] * a11[j]);
  }
  __shared__ float sred[256 * 16];
  int sb = blockIdx.x % SB;
  stats_epilogue<8>(sums, sqs, part, cog * 8, P, n * SB + sb, sred);
}

// ---------------- d3: 32->3 @256x256, 4-wide, fused bn4-apply, tanh (1024 blocks) ----------------
__global__ __launch_bounds__(256) void d3_conv(const float* __restrict__ F, const float* __restrict__ w,
    const float* __restrict__ bias, const float* __restrict__ ss, float* __restrict__ out){
  int idx = blockIdx.x * 256 + threadIdx.x;     // 262144 = 16n x 256oy x 64 ox4
  int ox4 = idx & 63, oy = (idx >> 6) & 255, n = idx >> 14;
  int ox0 = ox4 * 4;
  float acc[3][4];
  #pragma unroll
  for (int co = 0; co < 3; co++){
    float b = bias[co];
    #pragma unroll
    for (int j = 0; j < 4; j++) acc[co][j] = b;
  }
  const float* base = F + (size_t)n * 32 * 65536;
  bool x0ok = (ox4 > 0), x5ok = (ox4 < 63);
  int offL = x0ok ? -1 : 0;
  int offR = x5ok ? 4 : 0;
  #pragma unroll 2
  for (int ci = 0; ci < 32; ci++){
    const float* pl = base + ci * 65536;
    float sc = ss[ci], sh = ss[32 + ci];
    #pragma unroll
    for (int ky = 0; ky < 3; ky++){
      int iy = oy - 1 + ky;
      if (iy >= 0 && iy <= 255){
        const float* row = pl + iy * 256 + ox0;
        float l  = row[offL];
        float4 m = *(const float4*)row;
        float r4 = row[offR];
        float u[6];
        u[0] = x0ok ? lrelu(fmaf(l, sc, sh)) : 0.f;
        u[1] = lrelu(fmaf(m.x, sc, sh)); u[2] = lrelu(fmaf(m.y, sc, sh));
        u[3] = lrelu(fmaf(m.z, sc, sh)); u[4] = lrelu(fmaf(m.w, sc, sh));
        u[5] = x5ok ? lrelu(fmaf(r4, sc, sh)) : 0.f;
        #pragma unroll
        for (int co = 0; co < 3; co++){
          const float* wp = w + ((co * 32 + ci) * 9) + ky * 3;
          #pragma unroll
          for (int j = 0; j < 4; j++){
            acc[co][j] = fmaf(u[j],     wp[0], acc[co][j]);
            acc[co][j] = fmaf(u[j + 1], wp[1], acc[co][j]);
            acc[co][j] = fmaf(u[j + 2], wp[2], acc[co][j]);
          }
        }
      }
    }
  }
  #pragma unroll
  for (int co = 0; co < 3; co++){
    float4 s0;
    s0.x = tanh_fast(acc[co][0]); s0.y = tanh_fast(acc[co][1]);
    s0.z = tanh_fast(acc[co][2]); s0.w = tanh_fast(acc[co][3]);
    float* o = out + ((size_t)(n * 3 + co) * 256 + oy) * 256 + ox0;
    *(float4*)o = s0;
  }
}

// ---------------- launch ----------------
extern "C" void kernel_launch(void* const* d_in, const int* in_sizes, int n_in,
                              void* d_out, int out_size, void* d_ws, size_t ws_size,
                              hipStream_t stream){
  const float* x      = (const float*)d_in[0];
  const float* cb     = (const float*)d_in[1];
  const float* e1_w   = (const float*)d_in[2];
  const float* e1_b   = (const float*)d_in[3];
  const float* bn1_g  = (const float*)d_in[4];
  const float* bn1_b  = (const float*)d_in[5];
  const float* e2_w   = (const float*)d_in[6];
  const float* e2_b   = (const float*)d_in[7];
  const float* bn2_g  = (const float*)d_in[8];
  const float* bn2_b  = (const float*)d_in[9];
  const float* preq_w = (const float*)d_in[10];
  const float* preq_b = (const float*)d_in[11];
  const float* postq_w= (const float*)d_in[12];
  const float* postq_b= (const float*)d_in[13];
  const float* d1_w   = (const float*)d_in[14];
  const float* d1_b   = (const float*)d_in[15];
  const float* bn3_g  = (const float*)d_in[16];
  const float* bn3_b  = (const float*)d_in[17];
  const float* d2_w   = (const float*)d_in[18];
  const float* d2_b   = (const float*)d_in[19];
  const float* bn4_g  = (const float*)d_in[20];
  const float* bn4_b  = (const float*)d_in[21];
  const float* d3_w   = (const float*)d_in[22];
  const float* d3_b   = (const float*)d_in[23];
  float* out = (float*)d_out;
  char* ws = (char*)d_ws;

  double* losspart = (double*)ws;                        // 2048 B
  int*    flagcnt  = (int*)(ws + 2048);                  // 64 B
  float*  ss       = (float*)(ws + 4096);                // 576 B
  double* cb64     = (double*)(ws + 8192);               // 512 KB
  double* cbn64    = (double*)(ws + 532480);             // 8 KB
  float*  cbn32    = (float*)(ws + 540672);              // 4 KB
  unsigned short* cbh = (unsigned short*)(ws + 544768);  // 128 KB
  unsigned short* cbl = (unsigned short*)(ws + 675840);  // 128 KB
  int*    flaglist = (int*)(ws + 806912);                // 256 KB
  int*    idx      = (int*)(ws + 1069056);               // 256 KB
  double* part_e1  = (double*)(ws + 1331200);            // 128 KB
  double* part_e2  = (double*)(ws + 1462272);            // 16 KB
  double* part_d1  = (double*)(ws + 1478656);            // 64 KB
  double* part_d2  = (double*)(ws + 1544192);            // 512 KB
  float*  A        = (float*)(ws + 2097152);             // 16.78 MB
  float*  B        = (float*)(ws + 18874368);            // 1 MB
  float*  Zq       = (float*)(ws + 19922944);            // 16.78 MB
  float*  F        = (float*)(ws + 36700160);            // 134.2 MB

  float *ss1 = ss + 0, *ss2 = ss + 32, *ss3 = ss + 48, *ss4 = ss + 80;
  float* D = B;   // B dead after preq

  vq_prep<<<4, 256, 0, stream>>>(cb, cb64, cbn64, cbn32, cbh, cbl, flagcnt);

  // encoder
  e1_conv<<<512, 256, 0, stream>>>(x, e1_w, e1_b, A, part_e1);
  bn_red_fin<<<16, 256, 0, stream>>>(part_e1, 512, bn1_g, bn1_b, ss1, 16, 262144.0);
  e2_conv<<<256, 256, 0, stream>>>(A, e2_w, e2_b, ss1, B, part_e2);
  bn_red_fin<<<4, 256, 0, stream>>>(part_e2, 256, bn2_g, bn2_b, ss2, 4, 65536.0);
  preq_conv<<<4096, 256, 0, stream>>>(B, preq_w, preq_b, ss2, Zq);

  // VQ
  vq_screen_mfma<<<1024, 256, 0, stream>>>(Zq, cbh, cbl, cbn32, idx, flagcnt, flaglist);
  vq_refine<<<128, 256, 0, stream>>>(Zq, cb64, cbn64, flagcnt, flaglist, idx);

  // decoder (postq also computes the VQ loss partials)
  postq_conv<<<1024, 256, 0, stream>>>(cb, idx, postq_w, postq_b, D, Zq, losspart);
  convT_cob8<4, 16, 64, 64, false><<<512, 256, 0, stream>>>(D, d1_w, d1_b, nullptr, A, part_d1);
  bn_red_fin<<<16, 256, 0, stream>>>(part_d1, 256, bn3_g, bn3_b, ss3, 16, 262144.0);
  convT_cob8<16, 32, 128, 128, true><<<4096, 256, 0, stream>>>(A, d2_w, d2_b, ss3, F, part_d2);
  bn_red_fin<<<32, 256, 0, stream>>>(part_d2, 1024, bn4_g, bn4_b, ss4, 32, 1048576.0);
  d3_conv<<<1024, 256, 0, stream>>>(F, d3_w, d3_b, ss4, out);

  write_loss<<<1, 256, 0, stream>>>(losspart, out + 3145728);
}

// Round 6
// 356.251 us; speedup vs baseline: 4.4283x; 1.1527x over previous
//
#include <hip/hip_runtime.h>
#include <math.h>

#define EPSV 1e-5
#define SLOPE 0.1f

typedef __attribute__((ext_vector_type(4))) float f32x4;
typedef __attribute__((ext_vector_type(8))) short short8x;

__device__ __forceinline__ float lrelu(float x){ return x >= 0.f ? x : SLOPE * x; }
__device__ __forceinline__ float tanh_fast(float x){
  float e = __expf(2.f * x);
  return 1.f - 2.f / (e + 1.f);
}
__device__ __forceinline__ unsigned bf16rne(float f){
  unsigned u = __float_as_uint(f);
  u += 0x7fff + ((u >> 16) & 1);
  return u >> 16;
}

// ---- block BN-stats epilogue: per-thread CL channel sums/sqs -> f64 partials ----
template<int CL>
__device__ __forceinline__ void stats_epilogue(const float* sums, const float* sqs,
    double* __restrict__ part, int chbase, int P, int p, float* sred){
  const int C2 = 2 * CL;
  int t = threadIdx.x;
  #pragma unroll
  for (int c = 0; c < CL; c++){
    sred[t * C2 + c] = sums[c];
    sred[t * C2 + CL + c] = sqs[c];
  }
  __syncthreads();
  if (t < 64){
    int c = t % C2;
    int g = t / C2;
    const int G = 64 / C2;
    const int R = 256 / G;
    double s = 0;
    for (int r = g * R; r < (g + 1) * R; r++) s += (double)sred[r * C2 + c];
    #pragma unroll
    for (int off = C2; off < 64; off <<= 1) s += __shfl_xor(s, off);
    if (t < C2){
      int ch = chbase + (c < CL ? c : c - CL);
      part[(size_t)ch * 2 * P + (c < CL ? 0 : P) + p] = s;
    }
  }
}

// ---- reduce partials + finalize scale/shift ----
__global__ __launch_bounds__(256) void bn_red_fin(const double* __restrict__ part, int P,
    const float* __restrict__ g, const float* __restrict__ b, float* __restrict__ ss, int C, double count){
  int c = blockIdx.x;
  __shared__ double r0[256], r1[256];
  int t = threadIdx.x;
  double s = 0, q = 0;
  for (int p = t; p < P; p += 256){
    s += part[(size_t)c * 2 * P + p];
    q += part[(size_t)c * 2 * P + P + p];
  }
  r0[t] = s; r1[t] = q; __syncthreads();
  for (int o = 128; o > 0; o >>= 1){
    if (t < o){ r0[t] += r0[t + o]; r1[t] += r1[t + o]; }
    __syncthreads();
  }
  if (t == 0){
    double m = r0[0] / count;
    double var = r1[0] / count - m * m;
    double scale = (double)g[c] / sqrt(var + EPSV);
    ss[c] = (float)scale;
    ss[C + c] = (float)((double)b[c] - m * scale);
  }
}

// ---------------- e1: 3->16 s2, 256->128, 2 x-outputs/thread, fused bn1-stats ----------------
__global__ __launch_bounds__(256) void e1_conv(const float* __restrict__ x, const float* __restrict__ w,
    const float* __restrict__ bias, float* __restrict__ out, double* __restrict__ part){
  int idx = blockIdx.x * 256 + threadIdx.x;
  int ox2 = idx & 63, oy = (idx >> 6) & 127, n = idx >> 13;
  float acc[16][2];
  #pragma unroll
  for (int co = 0; co < 16; co++){ float b = bias[co]; acc[co][0] = b; acc[co][1] = b; }
  int ix0 = 4 * ox2 - 1;
  int lclamp = (ox2 > 0) ? ix0 : 0;
  const float* xp = x + (size_t)n * 3 * 65536;
  #pragma unroll
  for (int ci = 0; ci < 3; ci++){
    const float* pl = xp + ci * 65536;
    #pragma unroll
    for (int ky = 0; ky < 3; ky++){
      int iy = 2 * oy - 1 + ky;
      if (iy >= 0){
        const float* row = pl + iy * 256;
        float l = row[lclamp];
        float4 m = *(const float4*)(row + ix0 + 1);
        float v0 = (ox2 > 0) ? l : 0.f;
        #pragma unroll
        for (int co = 0; co < 16; co++){
          const float* wp = w + ((co * 3 + ci) * 3 + ky) * 3;
          acc[co][0] = fmaf(v0,  wp[0], acc[co][0]);
          acc[co][0] = fmaf(m.x, wp[1], acc[co][0]);
          acc[co][0] = fmaf(m.y, wp[2], acc[co][0]);
          acc[co][1] = fmaf(m.y, wp[0], acc[co][1]);
          acc[co][1] = fmaf(m.z, wp[1], acc[co][1]);
          acc[co][1] = fmaf(m.w, wp[2], acc[co][1]);
        }
      }
    }
  }
  float sums[16], sqs[16];
  #pragma unroll
  for (int co = 0; co < 16; co++){
    float2 st; st.x = acc[co][0]; st.y = acc[co][1];
    *(float2*)(out + ((size_t)(n * 16 + co) * 128 + oy) * 128 + 2 * ox2) = st;
    sums[co] = acc[co][0] + acc[co][1];
    sqs[co] = acc[co][0] * acc[co][0] + acc[co][1] * acc[co][1];
  }
  __shared__ float sred[256 * 32];
  stats_epilogue<16>(sums, sqs, part, 0, 512, blockIdx.x, sred);
}

// ---------------- e2: 16->4 s2 with fused bn1-apply on loads + bn2-stats ----------------
__global__ __launch_bounds__(256) void e2_conv(const float* __restrict__ in, const float* __restrict__ w,
    const float* __restrict__ bias, const float* __restrict__ ssIn, float* __restrict__ out,
    double* __restrict__ part){
  int idx = blockIdx.x * 256 + threadIdx.x;
  int ox = idx & 63, oy = (idx >> 6) & 63, n = idx >> 12;
  float acc[4];
  #pragma unroll
  for (int j = 0; j < 4; j++) acc[j] = bias[j];
  int iy0 = oy * 2 - 1, ix0 = ox * 2 - 1;
  const float* ip = in + (size_t)n * 16 * 16384;
  #pragma unroll
  for (int ky = 0; ky < 3; ky++){
    int iy = iy0 + ky; if ((unsigned)iy >= 128u) continue;
    #pragma unroll
    for (int kx = 0; kx < 3; kx++){
      int ix = ix0 + kx; if ((unsigned)ix >= 128u) continue;
      const float* r = ip + iy * 128 + ix;
      #pragma unroll
      for (int ci = 0; ci < 16; ci++){
        float v = lrelu(fmaf(r[ci * 16384], ssIn[ci], ssIn[16 + ci]));
        #pragma unroll
        for (int co = 0; co < 4; co++)
          acc[co] = fmaf(v, w[(co * 16 + ci) * 9 + ky * 3 + kx], acc[co]);
      }
    }
  }
  float sums[4], sqs[4];
  #pragma unroll
  for (int co = 0; co < 4; co++){
    out[(((size_t)n * 4 + co) * 64 + oy) * 64 + ox] = acc[co];
    sums[co] = acc[co];
    sqs[co] = acc[co] * acc[co];
  }
  __shared__ float sred[256 * 8];
  stats_epilogue<4>(sums, sqs, part, 0, 256, blockIdx.x, sred);
}

// ---------------- preq: fused bn2-apply, output plane layout Zq[coq][pos][4] ----------------
__global__ __launch_bounds__(256) void preq_conv(const float* __restrict__ in, const float* __restrict__ w,
    const float* __restrict__ bias, const float* __restrict__ ssIn, float* __restrict__ Zq){
  int idx = blockIdx.x * 256 + threadIdx.x;
  int sp = idx & 65535;
  int coq = idx >> 16;
  int x = sp & 63, y = (sp >> 6) & 63, n = sp >> 12;
  float scv[4] = {ssIn[0], ssIn[1], ssIn[2], ssIn[3]};
  float shv[4] = {ssIn[4], ssIn[5], ssIn[6], ssIn[7]};
  float a0 = bias[coq * 4 + 0], a1 = bias[coq * 4 + 1], a2 = bias[coq * 4 + 2], a3 = bias[coq * 4 + 3];
  const float* ip = in + (size_t)n * 4 * 4096;
  #pragma unroll
  for (int ky = 0; ky < 3; ky++){
    int iy = y - 1 + ky; if ((unsigned)iy >= 64u) continue;
    #pragma unroll
    for (int kx = 0; kx < 3; kx++){
      int ix = x - 1 + kx; if ((unsigned)ix >= 64u) continue;
      #pragma unroll
      for (int ci = 0; ci < 4; ci++){
        float v = lrelu(fmaf(ip[ci * 4096 + iy * 64 + ix], scv[ci], shv[ci]));
        const float* wp = w + ((coq * 4) * 4 + ci) * 9 + ky * 3 + kx;
        a0 = fmaf(v, wp[0], a0);
        a1 = fmaf(v, wp[36], a1);
        a2 = fmaf(v, wp[72], a2);
        a3 = fmaf(v, wp[108], a3);
      }
    }
  }
  float4 o; o.x = a0; o.y = a1; o.z = a2; o.w = a3;
  ((float4*)Zq)[coq * 65536 + sp] = o;
}

// ---------------- VQ prep: f64 codebook + norms + split-bf16 codebook (+flagcnt zero) ----------------
__global__ void vq_prep(const float* __restrict__ cb, double* __restrict__ cb64, double* __restrict__ cbn64,
    float* __restrict__ cbn32, unsigned short* __restrict__ cbh, unsigned short* __restrict__ cbl,
    int* __restrict__ flagcnt){
  int k = blockIdx.x * 256 + threadIdx.x;
  if (k == 0) flagcnt[0] = 0;
  if (k >= 1024) return;
  double s = 0;
  for (int d = 0; d < 64; d++){
    float v = cb[k * 64 + d];
    cb64[(size_t)k * 64 + d] = (double)v;
    s = fma((double)v, (double)v, s);
    unsigned h = bf16rne(v);
    float hf = __uint_as_float(h << 16);
    unsigned l = bf16rne(v - hf);
    cbh[k * 64 + d] = (unsigned short)h;
    cbl[k * 64 + d] = (unsigned short)l;
  }
  cbn64[k] = s;
  cbn32[k] = (float)s;
}

// ---------------- VQ screen via MFMA (split-bf16 scores + tie flags) ----------------
__global__ __launch_bounds__(256) void vq_screen_mfma(const float* __restrict__ Zq,
    const unsigned short* __restrict__ cbh, const unsigned short* __restrict__ cbl,
    const float* __restrict__ cbn32, int* __restrict__ idxout,
    int* __restrict__ flagcnt, int* __restrict__ flaglist){
  __shared__ unsigned short lcb[32 * 64 * 8];
  __shared__ float lcn[128];
  int t = threadIdx.x;
  int lane = t & 63;
  int w = t >> 6;
  int col = lane & 15, hg = lane >> 4;
  int pos0 = blockIdx.x * 64 + w * 16;
  int pos = pos0 + col;
  const float4* Zq4 = (const float4*)Zq;
  short8x zh[2], zl[2];
  #pragma unroll
  for (int kc = 0; kc < 2; kc++){
    float4 f0 = Zq4[(size_t)(8 * kc + 2 * hg) * 65536 + pos];
    float4 f1 = Zq4[(size_t)(8 * kc + 2 * hg + 1) * 65536 + pos];
    float zv[8] = {f0.x, f0.y, f0.z, f0.w, f1.x, f1.y, f1.z, f1.w};
    union { unsigned u[4]; short8x v; } H, L;
    #pragma unroll
    for (int j = 0; j < 4; j++){
      unsigned h0 = bf16rne(zv[2 * j]);
      unsigned h1 = bf16rne(zv[2 * j + 1]);
      float hf0 = __uint_as_float(h0 << 16);
      float hf1 = __uint_as_float(h1 << 16);
      unsigned l0 = bf16rne(zv[2 * j] - hf0);
      unsigned l1 = bf16rne(zv[2 * j + 1] - hf1);
      H.u[j] = h0 | (h1 << 16);
      L.u[j] = l0 | (l1 << 16);
    }
    zh[kc] = H.v; zl[kc] = L.v;
  }
  float best = 3.0e38f, sec = 3.0e38f; int bidx = 0;
  for (int step = 0; step < 8; step++){
    int code0 = step * 128;
    __syncthreads();
    #pragma unroll
    for (int i = 0; i < 8; i++){
      int piece = i * 256 + t;
      int fb = piece >> 6, pl = piece & 63;
      int g = fb >> 2, kc = (fb >> 1) & 1, sp = fb & 1;
      const unsigned short* src = (sp ? cbl : cbh)
          + ((size_t)(code0 + g * 16 + (pl & 15)) << 6) + kc * 32 + ((pl >> 4) << 3);
      *(uint4*)&lcb[piece * 8] = *(const uint4*)src;
    }
    if (t < 128) lcn[t] = cbn32[code0 + t];
    __syncthreads();
    #pragma unroll 2
    for (int g = 0; g < 8; g++){
      f32x4 acc = {0.f, 0.f, 0.f, 0.f};
      const short8x* lc8 = (const short8x*)lcb;
      short8x Ah0 = lc8[(g * 4 + 0) * 64 + lane];
      short8x Al0 = lc8[(g * 4 + 1) * 64 + lane];
      short8x Ah1 = lc8[(g * 4 + 2) * 64 + lane];
      short8x Al1 = lc8[(g * 4 + 3) * 64 + lane];
      acc = __builtin_amdgcn_mfma_f32_16x16x32_bf16(Ah0, zh[0], acc, 0, 0, 0);
      acc = __builtin_amdgcn_mfma_f32_16x16x32_bf16(Ah1, zh[1], acc, 0, 0, 0);
      acc = __builtin_amdgcn_mfma_f32_16x16x32_bf16(Ah0, zl[0], acc, 0, 0, 0);
      acc = __builtin_amdgcn_mfma_f32_16x16x32_bf16(Ah1, zl[1], acc, 0, 0, 0);
      acc = __builtin_amdgcn_mfma_f32_16x16x32_bf16(Al0, zh[0], acc, 0, 0, 0);
      acc = __builtin_amdgcn_mfma_f32_16x16x32_bf16(Al1, zh[1], acc, 0, 0, 0);
      int cbase = code0 + g * 16 + 4 * hg;
      #pragma unroll
      for (int r = 0; r < 4; r++){
        float s = fmaf(acc[r], -2.0f, lcn[g * 16 + 4 * hg + r]);
        float mx = fmaxf(s, best);
        sec = fminf(sec, mx);
        if (s < best){ best = s; bidx = cbase + r; }
      }
    }
  }
  #pragma unroll
  for (int off = 16; off <= 32; off <<= 1){
    float ob = __shfl_xor(best, off);
    float os = __shfl_xor(sec, off);
    int oi = __shfl_xor(bidx, off);
    sec = fminf(fminf(sec, os), fmaxf(best, ob));
    if (ob < best){ best = ob; bidx = oi; }
  }
  if (hg == 0){
    idxout[pos] = bidx;
    if (sec - best < 1.2e-2f){
      int slot = atomicAdd(flagcnt, 1);
      flaglist[slot] = pos;
    }
  }
}

// ---------------- VQ refine: exact f64 re-rank of near-ties ----------------
__global__ __launch_bounds__(256) void vq_refine(const float* __restrict__ Zq, const double* __restrict__ cb64,
    const double* __restrict__ cbn64, const int* __restrict__ flagcnt, const int* __restrict__ flaglist,
    int* __restrict__ idxout){
  int gw = (blockIdx.x * 256 + threadIdx.x) >> 6;
  int lane = threadIdx.x & 63;
  int nf = flagcnt[0];
  for (int f = gw; f < nf; f += 512){
    int pos = flaglist[f];
    float zr[64];
    #pragma unroll
    for (int q = 0; q < 16; q++){
      float4 v = ((const float4*)Zq)[q * 65536 + pos];
      zr[4 * q] = v.x; zr[4 * q + 1] = v.y; zr[4 * q + 2] = v.z; zr[4 * q + 3] = v.w;
    }
    double best = 1e300; int bi = 1 << 30;
    for (int k = lane; k < 1024; k += 64){
      const double* c = cb64 + (size_t)k * 64;
      double a0 = 0, a1 = 0, a2 = 0, a3 = 0;
      #pragma unroll
      for (int d = 0; d < 64; d += 4){
        a0 = fma(c[d], (double)zr[d], a0);
        a1 = fma(c[d + 1], (double)zr[d + 1], a1);
        a2 = fma(c[d + 2], (double)zr[d + 2], a2);
        a3 = fma(c[d + 3], (double)zr[d + 3], a3);
      }
      double s = cbn64[k] - 2.0 * ((a0 + a1) + (a2 + a3));
      if (s < best){ best = s; bi = k; }
    }
    #pragma unroll
    for (int o = 32; o > 0; o >>= 1){
      double ob = __shfl_xor(best, o);
      int oi = __shfl_xor(bi, o);
      if (ob < best || (ob == best && oi < bi)){ best = ob; bi = oi; }
    }
    if (lane == 0) idxout[pos] = bi;
  }
}

__global__ void write_loss(const double* __restrict__ losspart, float* __restrict__ out){
  __shared__ double sb[256];
  int t = threadIdx.x;
  sb[t] = losspart[t];
  __syncthreads();
  for (int o = 128; o > 0; o >>= 1){
    if (t < o) sb[t] += sb[t + o];
    __syncthreads();
  }
  if (t == 0) out[0] = (float)(1.25 * sb[0] / (65536.0 * 64.0));
}

// ---------------- postq P-table: P[k][tap][co] = sum_ci cb[k][ci]*w[co][ci][tap] ----------------
__global__ __launch_bounds__(256) void postq_prep(const float* __restrict__ cb, const float* __restrict__ w,
    float* __restrict__ P){
  int gid = blockIdx.x * 256 + threadIdx.x;   // 9216 = 1024k x 9tap
  if (gid >= 9216) return;
  int k = gid / 9, tap = gid - k * 9;
  float a0 = 0.f, a1 = 0.f, a2 = 0.f, a3 = 0.f;
  const float* cp = cb + (k << 6);
  #pragma unroll 16
  for (int ci = 0; ci < 64; ci++){
    float c = cp[ci];
    a0 = fmaf(c, w[(0 * 64 + ci) * 9 + tap], a0);
    a1 = fmaf(c, w[(1 * 64 + ci) * 9 + tap], a1);
    a2 = fmaf(c, w[(2 * 64 + ci) * 9 + tap], a2);
    a3 = fmaf(c, w[(3 * 64 + ci) * 9 + tap], a3);
  }
  float4 o; o.x = a0; o.y = a1; o.z = a2; o.w = a3;
  ((float4*)P)[gid] = o;
}

// ---------------- postq gather: out[pos][co] = bias + sum_tap P[idx[nbr]][tap][co]; fused loss ----------------
__global__ __launch_bounds__(256) void postq_gather(const float* __restrict__ P, const int* __restrict__ idxm,
    const float* __restrict__ bias, float* __restrict__ out,
    const float* __restrict__ Zq, const float* __restrict__ cb, double* __restrict__ losspart){
  int gid = blockIdx.x * 256 + threadIdx.x;   // 262144 = 4co x 65536pos
  int sp = gid & 65535;
  int co = gid >> 16;
  co = __builtin_amdgcn_readfirstlane(co);
  int xx = sp & 63, yy = (sp >> 6) & 63, n = sp >> 12;
  float acc = bias[co];
  #pragma unroll
  for (int ky = 0; ky < 3; ky++){
    int iy = yy - 1 + ky; if ((unsigned)iy >= 64u) continue;
    #pragma unroll
    for (int kx = 0; kx < 3; kx++){
      int ix = xx - 1 + kx; if ((unsigned)ix >= 64u) continue;
      int spt = (n << 12) + (iy << 6) + ix;
      int k = idxm[spt];
      acc += P[(k * 9 + (ky * 3 + kx)) * 4 + co];
    }
  }
  out[((size_t)(n * 4 + co) << 12) + (yy << 6) + xx] = acc;
  // fused VQ loss: blocks 0..255 exactly cover co==0, one thread per position
  if (co == 0){
    int k = idxm[sp];
    const float4* c4 = (const float4*)(cb + (k << 6));
    double l = 0;
    #pragma unroll
    for (int q = 0; q < 16; q++){
      float4 z = ((const float4*)Zq)[q * 65536 + sp];
      float4 c = c4[q];
      float d0 = z.x - c.x, d1 = z.y - c.y, d2 = z.z - c.z, d3 = z.w - c.w;
      l += (double)d0 * d0 + (double)d1 * d1 + (double)d2 * d2 + (double)d3 * d3;
    }
    __shared__ double sb[256];
    int t = threadIdx.x;
    sb[t] = l; __syncthreads();
    for (int o = 128; o > 0; o >>= 1){
      if (t < o) sb[t] += sb[t + o];
      __syncthreads();
    }
    if (t == 0) losspart[blockIdx.x] = sb[0];
  }
}

// ---------------- transposed conv k3 s2 p1 op1, 8 co/thread, optional input-BN, fused stats ----------------
template<int CI, int CO, int IHt, int IWt, bool APPLY>
__global__ __launch_bounds__(256) void convT_cob8(const float* __restrict__ in, const float* __restrict__ w,
    const float* __restrict__ bias, const float* __restrict__ ssIn, float* __restrict__ out,
    double* __restrict__ part){
  constexpr int SB = IHt * IWt / 256;
  constexpr int COG = CO / 8;
  constexpr int P = 16 * SB;
  const int OW = IWt * 2;
  int idx = blockIdx.x * 256 + threadIdx.x;
  int ix = idx % IWt, iy = (idx / IWt) % IHt;
  int cog = (idx / (IWt * IHt)) % COG, n = idx / (IWt * IHt * COG);
  cog = __builtin_amdgcn_readfirstlane(cog);
  n   = __builtin_amdgcn_readfirstlane(n);
  float a00[8], a01[8], a10[8], a11[8];
  #pragma unroll
  for (int j = 0; j < 8; j++){ float b = bias[cog * 8 + j]; a00[j] = b; a01[j] = b; a10[j] = b; a11[j] = b; }
  bool okx = (ix + 1 < IWt), oky = (iy + 1 < IHt);
  int ixp = okx ? ix + 1 : ix, iyp = oky ? iy + 1 : iy;
  const float* ip = in + (size_t)n * CI * IHt * IWt;
  #pragma unroll 4
  for (int ci = 0; ci < CI; ci++){
    const float* p = ip + ci * IHt * IWt;
    float v00 = p[iy * IWt + ix];
    float v01 = p[iy * IWt + ixp];
    float v10 = p[iyp * IWt + ix];
    float v11 = p[iyp * IWt + ixp];
    if (APPLY){
      float sc = ssIn[ci], sh = ssIn[CI + ci];
      v00 = lrelu(fmaf(v00, sc, sh));
      v01 = lrelu(fmaf(v01, sc, sh));
      v10 = lrelu(fmaf(v10, sc, sh));
      v11 = lrelu(fmaf(v11, sc, sh));
    }
    if (!okx) v01 = 0.f;
    if (!oky) v10 = 0.f;
    if (!(okx && oky)) v11 = 0.f;
    const float* wp = w + ((size_t)ci * CO + cog * 8) * 9;
    #pragma unroll
    for (int j = 0; j < 8; j++){
      const float* q = wp + j * 9;
      a00[j] = fmaf(q[4], v00, a00[j]);
      a01[j] = fmaf(q[3], v01, a01[j]); a01[j] = fmaf(q[5], v00, a01[j]);
      a10[j] = fmaf(q[1], v10, a10[j]); a10[j] = fmaf(q[7], v00, a10[j]);
      a11[j] = fmaf(q[0], v11, a11[j]); a11[j] = fmaf(q[2], v10, a11[j]);
      a11[j] = fmaf(q[6], v01, a11[j]); a11[j] = fmaf(q[8], v00, a11[j]);
    }
  }
  float sums[8], sqs[8];
  #pragma unroll
  for (int j = 0; j < 8; j++){
    float* o = out + (((size_t)n * CO + cog * 8 + j) * (IHt * 2) + 2 * iy) * OW + 2 * ix;
    float2 r0; r0.x = a00[j]; r0.y = a01[j];
    float2 r1; r1.x = a10[j]; r1.y = a11[j];
    *(float2*)o = r0;
    *(float2*)(o + OW) = r1;
    sums[j] = (a00[j] + a01[j]) + (a10[j] + a11[j]);
    sqs[j] = (a00[j] * a00[j] + a01[j] * a01[j]) + (a10[j] * a10[j] + a11[j] * a11[j]);
  }
  __shared__ float sred[256 * 16];
  int sb = blockIdx.x % SB;
  stats_epilogue<8>(sums, sqs, part, cog * 8, P, n * SB + sb, sred);
}

// ---------------- d3: 32->3 @256x256, LDS-tiled, fused bn4-apply at stage, tanh ----------------
// block = (n, 4-row stripe x full 256 width); 64 xg x 4 r threads; ci chunks of 8
__global__ __launch_bounds__(256) void d3_tile(const float* __restrict__ F, const float* __restrict__ w,
    const float* __restrict__ bias, const float* __restrict__ ss, float* __restrict__ out){
  __shared__ float st[8 * 6 * 256];             // 48 KB: [cl][rr][x]
  int t = threadIdx.x;
  int xg = t & 63, r = t >> 6;
  int n = blockIdx.x >> 6, oyb = blockIdx.x & 63;
  int oy = oyb * 4 + r;
  float acc[3][4];
  #pragma unroll
  for (int co = 0; co < 3; co++){
    float b = bias[co];
    #pragma unroll
    for (int j = 0; j < 4; j++) acc[co][j] = b;
  }
  const float* base = F + (size_t)n * 32 * 65536;
  for (int cc = 0; cc < 4; cc++){
    int cib = cc * 8;
    // stage 8 ci x 6 rows x 256 (bn+lrelu applied once here)
    #pragma unroll
    for (int j = 0; j < 12; j++){
      int p = j * 256 + t;                       // 3072 float4 pieces
      int cl = p / 384, rem = p - cl * 384;
      int rr = rem >> 6, xq = rem & 63;
      int g = oyb * 4 - 1 + rr;
      float4 v;
      if ((unsigned)g < 256u){
        v = *(const float4*)(base + ((size_t)(cib + cl) * 256 + g) * 256 + 4 * xq);
        float sc = ss[cib + cl], sh = ss[32 + cib + cl];
        v.x = lrelu(fmaf(v.x, sc, sh));
        v.y = lrelu(fmaf(v.y, sc, sh));
        v.z = lrelu(fmaf(v.z, sc, sh));
        v.w = lrelu(fmaf(v.w, sc, sh));
      } else {
        v.x = 0.f; v.y = 0.f; v.z = 0.f; v.w = 0.f;
      }
      *(float4*)&st[((cl * 6 + rr) << 8) | (4 * xq)] = v;
    }
    __syncthreads();
    #pragma unroll
    for (int cl = 0; cl < 8; cl++){
      #pragma unroll
      for (int ky = 0; ky < 3; ky++){
        int rr = r + ky;
        float4 A = *(const float4*)&st[((cl * 6 + rr) << 8) | (4 * xg)];
        float Lv = __shfl_up(A.w, 1);            // lane xg-1's x=4xg-1
        float Rv = __shfl_down(A.x, 1);          // lane xg+1's x=4xg+4
        float u0 = (xg == 0) ? 0.f : Lv;
        float u5 = (xg == 63) ? 0.f : Rv;
        float u[6] = {u0, A.x, A.y, A.z, A.w, u5};
        #pragma unroll
        for (int co = 0; co < 3; co++){
          const float* wp = w + ((co * 32 + cib + cl) * 9) + ky * 3;
          #pragma unroll
          for (int j = 0; j < 4; j++){
            acc[co][j] = fmaf(u[j],     wp[0], acc[co][j]);
            acc[co][j] = fmaf(u[j + 1], wp[1], acc[co][j]);
            acc[co][j] = fmaf(u[j + 2], wp[2], acc[co][j]);
          }
        }
      }
    }
    __syncthreads();
  }
  #pragma unroll
  for (int co = 0; co < 3; co++){
    float4 s0;
    s0.x = tanh_fast(acc[co][0]); s0.y = tanh_fast(acc[co][1]);
    s0.z = tanh_fast(acc[co][2]); s0.w = tanh_fast(acc[co][3]);
    float* o = out + ((size_t)(n * 3 + co) * 256 + oy) * 256 + 4 * xg;
    *(float4*)o = s0;
  }
}

// ---------------- launch ----------------
extern "C" void kernel_launch(void* const* d_in, const int* in_sizes, int n_in,
                              void* d_out, int out_size, void* d_ws, size_t ws_size,
                              hipStream_t stream){
  const float* x      = (const float*)d_in[0];
  const float* cb     = (const float*)d_in[1];
  const float* e1_w   = (const float*)d_in[2];
  const float* e1_b   = (const float*)d_in[3];
  const float* bn1_g  = (const float*)d_in[4];
  const float* bn1_b  = (const float*)d_in[5];
  const float* e2_w   = (const float*)d_in[6];
  const float* e2_b   = (const float*)d_in[7];
  const float* bn2_g  = (const float*)d_in[8];
  const float* bn2_b  = (const float*)d_in[9];
  const float* preq_w = (const float*)d_in[10];
  const float* preq_b = (const float*)d_in[11];
  const float* postq_w= (const float*)d_in[12];
  const float* postq_b= (const float*)d_in[13];
  const float* d1_w   = (const float*)d_in[14];
  const float* d1_b   = (const float*)d_in[15];
  const float* bn3_g  = (const float*)d_in[16];
  const float* bn3_b  = (const float*)d_in[17];
  const float* d2_w   = (const float*)d_in[18];
  const float* d2_b   = (const float*)d_in[19];
  const float* bn4_g  = (const float*)d_in[20];
  const float* bn4_b  = (const float*)d_in[21];
  const float* d3_w   = (const float*)d_in[22];
  const float* d3_b   = (const float*)d_in[23];
  float* out = (float*)d_out;
  char* ws = (char*)d_ws;

  double* losspart = (double*)ws;                        // 2048 B
  int*    flagcnt  = (int*)(ws + 2048);                  // 64 B
  float*  ss       = (float*)(ws + 4096);                // 576 B
  double* cb64     = (double*)(ws + 8192);               // 512 KB
  double* cbn64    = (double*)(ws + 532480);             // 8 KB
  float*  cbn32    = (float*)(ws + 540672);              // 4 KB
  unsigned short* cbh = (unsigned short*)(ws + 544768);  // 128 KB
  unsigned short* cbl = (unsigned short*)(ws + 675840);  // 128 KB
  int*    flaglist = (int*)(ws + 806912);                // 256 KB
  int*    idx      = (int*)(ws + 1069056);               // 256 KB
  double* part_e1  = (double*)(ws + 1331200);            // 128 KB
  double* part_e2  = (double*)(ws + 1462272);            // 16 KB
  float*  Ptab     = (float*)(ws + 1478656);             // 147 KB (aliases part_d1/d2 head; dead before d1 stats)
  double* part_d1  = (double*)(ws + 1478656);            // 64 KB (written by d1, after postq_gather)
  double* part_d2  = (double*)(ws + 1544192);            // 512 KB (written by d2, after postq_gather)
  float*  A        = (float*)(ws + 2097152);             // 16.78 MB
  float*  B        = (float*)(ws + 18874368);            // 1 MB
  float*  Zq       = (float*)(ws + 19922944);            // 16.78 MB
  float*  F        = (float*)(ws + 36700160);            // 134.2 MB

  float *ss1 = ss + 0, *ss2 = ss + 32, *ss3 = ss + 48, *ss4 = ss + 80;
  float* D = B;   // B dead after preq

  vq_prep<<<4, 256, 0, stream>>>(cb, cb64, cbn64, cbn32, cbh, cbl, flagcnt);
  postq_prep<<<36, 256, 0, stream>>>(cb, postq_w, Ptab);

  // encoder
  e1_conv<<<512, 256, 0, stream>>>(x, e1_w, e1_b, A, part_e1);
  bn_red_fin<<<16, 256, 0, stream>>>(part_e1, 512, bn1_g, bn1_b, ss1, 16, 262144.0);
  e2_conv<<<256, 256, 0, stream>>>(A, e2_w, e2_b, ss1, B, part_e2);
  bn_red_fin<<<4, 256, 0, stream>>>(part_e2, 256, bn2_g, bn2_b, ss2, 4, 65536.0);
  preq_conv<<<4096, 256, 0, stream>>>(B, preq_w, preq_b, ss2, Zq);

  // VQ
  vq_screen_mfma<<<1024, 256, 0, stream>>>(Zq, cbh, cbl, cbn32, idx, flagcnt, flaglist);
  vq_refine<<<128, 256, 0, stream>>>(Zq, cb64, cbn64, flagcnt, flaglist, idx);

  // decoder (postq_gather also computes VQ loss partials)
  postq_gather<<<1024, 256, 0, stream>>>(Ptab, idx, postq_b, D, Zq, cb, losspart);
  convT_cob8<4, 16, 64, 64, false><<<512, 256, 0, stream>>>(D, d1_w, d1_b, nullptr, A, part_d1);
  bn_red_fin<<<16, 256, 0, stream>>>(part_d1, 256, bn3_g, bn3_b, ss3, 16, 262144.0);
  convT_cob8<16, 32, 128, 128, true><<<4096, 256, 0, stream>>>(A, d2_w, d2_b, ss3, F, part_d2);
  bn_red_fin<<<32, 256, 0, stream>>>(part_d2, 1024, bn4_g, bn4_b, ss4, 32, 1048576.0);
  d3_tile<<<1024, 256, 0, stream>>>(F, d3_w, d3_b, ss4, out);

  write_loss<<<1, 256, 0, stream>>>(losspart, out + 3145728);
}

// Round 7
// 307.992 us; speedup vs baseline: 5.1221x; 1.1567x over previous
//
#include <hip/hip_runtime.h>
#include <math.h>

#define EPSV 1e-5
#define SLOPE 0.1f

typedef __attribute__((ext_vector_type(4))) float f32x4;
typedef __attribute__((ext_vector_type(8))) short short8x;

__device__ __forceinline__ float lrelu(float x){ return x >= 0.f ? x : SLOPE * x; }
__device__ __forceinline__ float tanh_fast(float x){
  float e = __expf(2.f * x);
  return 1.f - 2.f / (e + 1.f);
}
__device__ __forceinline__ unsigned bf16rne(float f){
  unsigned u = __float_as_uint(f);
  u += 0x7fff + ((u >> 16) & 1);
  return u >> 16;
}

// ---- block BN-stats epilogue: per-thread CL channel sums/sqs -> f64 partials ----
template<int CL>
__device__ __forceinline__ void stats_epilogue(const float* sums, const float* sqs,
    double* __restrict__ part, int chbase, int P, int p, float* sred){
  const int C2 = 2 * CL;
  int t = threadIdx.x;
  #pragma unroll
  for (int c = 0; c < CL; c++){
    sred[t * C2 + c] = sums[c];
    sred[t * C2 + CL + c] = sqs[c];
  }
  __syncthreads();
  if (t < 64){
    int c = t % C2;
    int g = t / C2;
    const int G = 64 / C2;
    const int R = 256 / G;
    double s = 0;
    for (int r = g * R; r < (g + 1) * R; r++) s += (double)sred[r * C2 + c];
    #pragma unroll
    for (int off = C2; off < 64; off <<= 1) s += __shfl_xor(s, off);
    if (t < C2){
      int ch = chbase + (c < CL ? c : c - CL);
      part[(size_t)ch * 2 * P + (c < CL ? 0 : P) + p] = s;
    }
  }
}

// ---- reduce partials + finalize scale/shift ----
__global__ __launch_bounds__(256) void bn_red_fin(const double* __restrict__ part, int P,
    const float* __restrict__ g, const float* __restrict__ b, float* __restrict__ ss, int C, double count){
  int c = blockIdx.x;
  __shared__ double r0[256], r1[256];
  int t = threadIdx.x;
  double s = 0, q = 0;
  for (int p = t; p < P; p += 256){
    s += part[(size_t)c * 2 * P + p];
    q += part[(size_t)c * 2 * P + P + p];
  }
  r0[t] = s; r1[t] = q; __syncthreads();
  for (int o = 128; o > 0; o >>= 1){
    if (t < o){ r0[t] += r0[t + o]; r1[t] += r1[t + o]; }
    __syncthreads();
  }
  if (t == 0){
    double m = r0[0] / count;
    double var = r1[0] / count - m * m;
    double scale = (double)g[c] / sqrt(var + EPSV);
    ss[c] = (float)scale;
    ss[C + c] = (float)((double)b[c] - m * scale);
  }
}

// ---------------- e1: 3->16 s2, 256->128, 2 x-outputs/thread, fused bn1-stats ----------------
__global__ __launch_bounds__(256) void e1_conv(const float* __restrict__ x, const float* __restrict__ w,
    const float* __restrict__ bias, float* __restrict__ out, double* __restrict__ part){
  int idx = blockIdx.x * 256 + threadIdx.x;
  int ox2 = idx & 63, oy = (idx >> 6) & 127, n = idx >> 13;
  float acc[16][2];
  #pragma unroll
  for (int co = 0; co < 16; co++){ float b = bias[co]; acc[co][0] = b; acc[co][1] = b; }
  int ix0 = 4 * ox2 - 1;
  int lclamp = (ox2 > 0) ? ix0 : 0;
  const float* xp = x + (size_t)n * 3 * 65536;
  #pragma unroll
  for (int ci = 0; ci < 3; ci++){
    const float* pl = xp + ci * 65536;
    #pragma unroll
    for (int ky = 0; ky < 3; ky++){
      int iy = 2 * oy - 1 + ky;
      if (iy >= 0){
        const float* row = pl + iy * 256;
        float l = row[lclamp];
        float4 m = *(const float4*)(row + ix0 + 1);
        float v0 = (ox2 > 0) ? l : 0.f;
        #pragma unroll
        for (int co = 0; co < 16; co++){
          const float* wp = w + ((co * 3 + ci) * 3 + ky) * 3;
          acc[co][0] = fmaf(v0,  wp[0], acc[co][0]);
          acc[co][0] = fmaf(m.x, wp[1], acc[co][0]);
          acc[co][0] = fmaf(m.y, wp[2], acc[co][0]);
          acc[co][1] = fmaf(m.y, wp[0], acc[co][1]);
          acc[co][1] = fmaf(m.z, wp[1], acc[co][1]);
          acc[co][1] = fmaf(m.w, wp[2], acc[co][1]);
        }
      }
    }
  }
  float sums[16], sqs[16];
  #pragma unroll
  for (int co = 0; co < 16; co++){
    float2 st; st.x = acc[co][0]; st.y = acc[co][1];
    *(float2*)(out + ((size_t)(n * 16 + co) * 128 + oy) * 128 + 2 * ox2) = st;
    sums[co] = acc[co][0] + acc[co][1];
    sqs[co] = acc[co][0] * acc[co][0] + acc[co][1] * acc[co][1];
  }
  __shared__ float sred[256 * 32];
  stats_epilogue<16>(sums, sqs, part, 0, 512, blockIdx.x, sred);
}

// ---------------- e2: 16->4 s2 with fused bn1-apply on loads + bn2-stats ----------------
__global__ __launch_bounds__(256) void e2_conv(const float* __restrict__ in, const float* __restrict__ w,
    const float* __restrict__ bias, const float* __restrict__ ssIn, float* __restrict__ out,
    double* __restrict__ part){
  int idx = blockIdx.x * 256 + threadIdx.x;
  int ox = idx & 63, oy = (idx >> 6) & 63, n = idx >> 12;
  float acc[4];
  #pragma unroll
  for (int j = 0; j < 4; j++) acc[j] = bias[j];
  int iy0 = oy * 2 - 1, ix0 = ox * 2 - 1;
  const float* ip = in + (size_t)n * 16 * 16384;
  #pragma unroll
  for (int ky = 0; ky < 3; ky++){
    int iy = iy0 + ky; if ((unsigned)iy >= 128u) continue;
    #pragma unroll
    for (int kx = 0; kx < 3; kx++){
      int ix = ix0 + kx; if ((unsigned)ix >= 128u) continue;
      const float* r = ip + iy * 128 + ix;
      #pragma unroll
      for (int ci = 0; ci < 16; ci++){
        float v = lrelu(fmaf(r[ci * 16384], ssIn[ci], ssIn[16 + ci]));
        #pragma unroll
        for (int co = 0; co < 4; co++)
          acc[co] = fmaf(v, w[(co * 16 + ci) * 9 + ky * 3 + kx], acc[co]);
      }
    }
  }
  float sums[4], sqs[4];
  #pragma unroll
  for (int co = 0; co < 4; co++){
    out[(((size_t)n * 4 + co) * 64 + oy) * 64 + ox] = acc[co];
    sums[co] = acc[co];
    sqs[co] = acc[co] * acc[co];
  }
  __shared__ float sred[256 * 8];
  stats_epilogue<4>(sums, sqs, part, 0, 256, blockIdx.x, sred);
}

// ---------------- preq: fused bn2-apply, output plane layout Zq[coq][pos][4] ----------------
__global__ __launch_bounds__(256) void preq_conv(const float* __restrict__ in, const float* __restrict__ w,
    const float* __restrict__ bias, const float* __restrict__ ssIn, float* __restrict__ Zq){
  int idx = blockIdx.x * 256 + threadIdx.x;
  int sp = idx & 65535;
  int coq = idx >> 16;
  int x = sp & 63, y = (sp >> 6) & 63, n = sp >> 12;
  float scv[4] = {ssIn[0], ssIn[1], ssIn[2], ssIn[3]};
  float shv[4] = {ssIn[4], ssIn[5], ssIn[6], ssIn[7]};
  float a0 = bias[coq * 4 + 0], a1 = bias[coq * 4 + 1], a2 = bias[coq * 4 + 2], a3 = bias[coq * 4 + 3];
  const float* ip = in + (size_t)n * 4 * 4096;
  #pragma unroll
  for (int ky = 0; ky < 3; ky++){
    int iy = y - 1 + ky; if ((unsigned)iy >= 64u) continue;
    #pragma unroll
    for (int kx = 0; kx < 3; kx++){
      int ix = x - 1 + kx; if ((unsigned)ix >= 64u) continue;
      #pragma unroll
      for (int ci = 0; ci < 4; ci++){
        float v = lrelu(fmaf(ip[ci * 4096 + iy * 64 + ix], scv[ci], shv[ci]));
        const float* wp = w + ((coq * 4) * 4 + ci) * 9 + ky * 3 + kx;
        a0 = fmaf(v, wp[0], a0);
        a1 = fmaf(v, wp[36], a1);
        a2 = fmaf(v, wp[72], a2);
        a3 = fmaf(v, wp[108], a3);
      }
    }
  }
  float4 o; o.x = a0; o.y = a1; o.z = a2; o.w = a3;
  ((float4*)Zq)[coq * 65536 + sp] = o;
}

// ---------------- prep_all: blocks 0-3 VQ codebook prep, blocks 4-39 postq P-table ----------------
__global__ __launch_bounds__(256) void prep_all(const float* __restrict__ cb, double* __restrict__ cb64,
    double* __restrict__ cbn64, float* __restrict__ cbn32, unsigned short* __restrict__ cbh,
    unsigned short* __restrict__ cbl, int* __restrict__ flagcnt,
    const float* __restrict__ pw, float* __restrict__ P){
  int t = threadIdx.x;
  if (blockIdx.x < 4){
    int k = blockIdx.x * 256 + t;
    if (k == 0) flagcnt[0] = 0;
    double s = 0;
    for (int d = 0; d < 64; d++){
      float v = cb[k * 64 + d];
      cb64[(size_t)k * 64 + d] = (double)v;
      s = fma((double)v, (double)v, s);
      unsigned h = bf16rne(v);
      float hf = __uint_as_float(h << 16);
      unsigned l = bf16rne(v - hf);
      cbh[k * 64 + d] = (unsigned short)h;
      cbl[k * 64 + d] = (unsigned short)l;
    }
    cbn64[k] = s;
    cbn32[k] = (float)s;
  } else {
    int gid = (blockIdx.x - 4) * 256 + t;       // 9216 = 1024k x 9tap
    if (gid >= 9216) return;
    int k = gid / 9, tap = gid - k * 9;
    float a0 = 0.f, a1 = 0.f, a2 = 0.f, a3 = 0.f;
    const float* cp = cb + (k << 6);
    #pragma unroll 16
    for (int ci = 0; ci < 64; ci++){
      float c = cp[ci];
      a0 = fmaf(c, pw[(0 * 64 + ci) * 9 + tap], a0);
      a1 = fmaf(c, pw[(1 * 64 + ci) * 9 + tap], a1);
      a2 = fmaf(c, pw[(2 * 64 + ci) * 9 + tap], a2);
      a3 = fmaf(c, pw[(3 * 64 + ci) * 9 + tap], a3);
    }
    float4 o; o.x = a0; o.y = a1; o.z = a2; o.w = a3;
    ((float4*)P)[gid] = o;
  }
}

// ---------------- VQ screen via MFMA: wave = 32 positions (2 B-tiles) x all 1024 codes ----------------
__global__ __launch_bounds__(256) void vq_screen_mfma(const float* __restrict__ Zq,
    const unsigned short* __restrict__ cbh, const unsigned short* __restrict__ cbl,
    const float* __restrict__ cbn32, int* __restrict__ idxout,
    int* __restrict__ flagcnt, int* __restrict__ flaglist){
  __shared__ unsigned short lcb[32 * 64 * 8];   // 32 KB staged A-fragments
  __shared__ float lcn[128];
  int t = threadIdx.x;
  int lane = t & 63;
  int w = t >> 6;
  int col = lane & 15, hg = lane >> 4;
  int pos0 = blockIdx.x * 128 + w * 32;
  int posA = pos0 + col, posB = pos0 + 16 + col;
  const float4* Zq4 = (const float4*)Zq;
  short8x zhA[2], zlA[2], zhB[2], zlB[2];
  #pragma unroll
  for (int kc = 0; kc < 2; kc++){
    #pragma unroll
    for (int s = 0; s < 2; s++){
      int pos = s ? posB : posA;
      float4 f0 = Zq4[(size_t)(8 * kc + 2 * hg) * 65536 + pos];
      float4 f1 = Zq4[(size_t)(8 * kc + 2 * hg + 1) * 65536 + pos];
      float zv[8] = {f0.x, f0.y, f0.z, f0.w, f1.x, f1.y, f1.z, f1.w};
      union { unsigned u[4]; short8x v; } H, L;
      #pragma unroll
      for (int j = 0; j < 4; j++){
        unsigned h0 = bf16rne(zv[2 * j]);
        unsigned h1 = bf16rne(zv[2 * j + 1]);
        float hf0 = __uint_as_float(h0 << 16);
        float hf1 = __uint_as_float(h1 << 16);
        unsigned l0 = bf16rne(zv[2 * j] - hf0);
        unsigned l1 = bf16rne(zv[2 * j + 1] - hf1);
        H.u[j] = h0 | (h1 << 16);
        L.u[j] = l0 | (l1 << 16);
      }
      if (s){ zhB[kc] = H.v; zlB[kc] = L.v; } else { zhA[kc] = H.v; zlA[kc] = L.v; }
    }
  }
  float bestA = 3.0e38f, secA = 3.0e38f, bestB = 3.0e38f, secB = 3.0e38f;
  int biA = 0, biB = 0;
  for (int step = 0; step < 8; step++){
    int code0 = step * 128;
    __syncthreads();
    #pragma unroll
    for (int i = 0; i < 8; i++){
      int piece = i * 256 + t;
      int fb = piece >> 6, pl = piece & 63;
      int g = fb >> 2, kc = (fb >> 1) & 1, sp = fb & 1;
      const unsigned short* src = (sp ? cbl : cbh)
          + ((size_t)(code0 + g * 16 + (pl & 15)) << 6) + kc * 32 + ((pl >> 4) << 3);
      *(uint4*)&lcb[piece * 8] = *(const uint4*)src;
    }
    if (t < 128) lcn[t] = cbn32[code0 + t];
    __syncthreads();
    #pragma unroll 2
    for (int g = 0; g < 8; g++){
      const short8x* lc8 = (const short8x*)lcb;
      short8x Ah0 = lc8[(g * 4 + 0) * 64 + lane];
      short8x Al0 = lc8[(g * 4 + 1) * 64 + lane];
      short8x Ah1 = lc8[(g * 4 + 2) * 64 + lane];
      short8x Al1 = lc8[(g * 4 + 3) * 64 + lane];
      f32x4 accA = {0.f, 0.f, 0.f, 0.f};
      f32x4 accB = {0.f, 0.f, 0.f, 0.f};
      accA = __builtin_amdgcn_mfma_f32_16x16x32_bf16(Ah0, zhA[0], accA, 0, 0, 0);
      accA = __builtin_amdgcn_mfma_f32_16x16x32_bf16(Ah1, zhA[1], accA, 0, 0, 0);
      accA = __builtin_amdgcn_mfma_f32_16x16x32_bf16(Ah0, zlA[0], accA, 0, 0, 0);
      accA = __builtin_amdgcn_mfma_f32_16x16x32_bf16(Ah1, zlA[1], accA, 0, 0, 0);
      accA = __builtin_amdgcn_mfma_f32_16x16x32_bf16(Al0, zhA[0], accA, 0, 0, 0);
      accA = __builtin_amdgcn_mfma_f32_16x16x32_bf16(Al1, zhA[1], accA, 0, 0, 0);
      accB = __builtin_amdgcn_mfma_f32_16x16x32_bf16(Ah0, zhB[0], accB, 0, 0, 0);
      accB = __builtin_amdgcn_mfma_f32_16x16x32_bf16(Ah1, zhB[1], accB, 0, 0, 0);
      accB = __builtin_amdgcn_mfma_f32_16x16x32_bf16(Ah0, zlB[0], accB, 0, 0, 0);
      accB = __builtin_amdgcn_mfma_f32_16x16x32_bf16(Ah1, zlB[1], accB, 0, 0, 0);
      accB = __builtin_amdgcn_mfma_f32_16x16x32_bf16(Al0, zhB[0], accB, 0, 0, 0);
      accB = __builtin_amdgcn_mfma_f32_16x16x32_bf16(Al1, zhB[1], accB, 0, 0, 0);
      int cbase = code0 + g * 16 + 4 * hg;
      #pragma unroll
      for (int r = 0; r < 4; r++){
        float cn = lcn[g * 16 + 4 * hg + r];
        float sA = fmaf(accA[r], -2.0f, cn);
        float mA = fmaxf(sA, bestA);
        secA = fminf(secA, mA);
        if (sA < bestA){ bestA = sA; biA = cbase + r; }
        float sB = fmaf(accB[r], -2.0f, cn);
        float mB = fmaxf(sB, bestB);
        secB = fminf(secB, mB);
        if (sB < bestB){ bestB = sB; biB = cbase + r; }
      }
    }
  }
  #pragma unroll
  for (int off = 16; off <= 32; off <<= 1){
    float ob = __shfl_xor(bestA, off);
    float os = __shfl_xor(secA, off);
    int oi = __shfl_xor(biA, off);
    secA = fminf(fminf(secA, os), fmaxf(bestA, ob));
    if (ob < bestA){ bestA = ob; biA = oi; }
    ob = __shfl_xor(bestB, off);
    os = __shfl_xor(secB, off);
    oi = __shfl_xor(biB, off);
    secB = fminf(fminf(secB, os), fmaxf(bestB, ob));
    if (ob < bestB){ bestB = ob; biB = oi; }
  }
  if (hg == 0){
    idxout[posA] = biA;
    if (secA - bestA < 1.2e-2f){
      int slot = atomicAdd(flagcnt, 1);
      flaglist[slot] = posA;
    }
    idxout[posB] = biB;
    if (secB - bestB < 1.2e-2f){
      int slot = atomicAdd(flagcnt, 1);
      flaglist[slot] = posB;
    }
  }
}

// ---------------- VQ refine: exact f64 re-rank of near-ties ----------------
__global__ __launch_bounds__(256) void vq_refine(const float* __restrict__ Zq, const double* __restrict__ cb64,
    const double* __restrict__ cbn64, const int* __restrict__ flagcnt, const int* __restrict__ flaglist,
    int* __restrict__ idxout){
  int gw = (blockIdx.x * 256 + threadIdx.x) >> 6;
  int lane = threadIdx.x & 63;
  int nf = flagcnt[0];
  for (int f = gw; f < nf; f += 512){
    int pos = flaglist[f];
    float zr[64];
    #pragma unroll
    for (int q = 0; q < 16; q++){
      float4 v = ((const float4*)Zq)[q * 65536 + pos];
      zr[4 * q] = v.x; zr[4 * q + 1] = v.y; zr[4 * q + 2] = v.z; zr[4 * q + 3] = v.w;
    }
    double best = 1e300; int bi = 1 << 30;
    for (int k = lane; k < 1024; k += 64){
      const double* c = cb64 + (size_t)k * 64;
      double a0 = 0, a1 = 0, a2 = 0, a3 = 0;
      #pragma unroll
      for (int d = 0; d < 64; d += 4){
        a0 = fma(c[d], (double)zr[d], a0);
        a1 = fma(c[d + 1], (double)zr[d + 1], a1);
        a2 = fma(c[d + 2], (double)zr[d + 2], a2);
        a3 = fma(c[d + 3], (double)zr[d + 3], a3);
      }
      double s = cbn64[k] - 2.0 * ((a0 + a1) + (a2 + a3));
      if (s < best){ best = s; bi = k; }
    }
    #pragma unroll
    for (int o = 32; o > 0; o >>= 1){
      double ob = __shfl_xor(best, o);
      int oi = __shfl_xor(bi, o);
      if (ob < best || (ob == best && oi < bi)){ best = ob; bi = oi; }
    }
    if (lane == 0) idxout[pos] = bi;
  }
}

// ---------------- postq gather: out[pos][co] = bias + sum_tap P[idx[nbr]][tap][co]; fused loss ----------------
__global__ __launch_bounds__(256) void postq_gather(const float* __restrict__ P, const int* __restrict__ idxm,
    const float* __restrict__ bias, float* __restrict__ out,
    const float* __restrict__ Zq, const float* __restrict__ cb, double* __restrict__ losspart){
  int gid = blockIdx.x * 256 + threadIdx.x;   // 262144 = 4co x 65536pos
  int sp = gid & 65535;
  int co = gid >> 16;
  co = __builtin_amdgcn_readfirstlane(co);
  int xx = sp & 63, yy = (sp >> 6) & 63, n = sp >> 12;
  float acc = bias[co];
  #pragma unroll
  for (int ky = 0; ky < 3; ky++){
    int iy = yy - 1 + ky; if ((unsigned)iy >= 64u) continue;
    #pragma unroll
    for (int kx = 0; kx < 3; kx++){
      int ix = xx - 1 + kx; if ((unsigned)ix >= 64u) continue;
      int spt = (n << 12) + (iy << 6) + ix;
      int k = idxm[spt];
      acc += P[(k * 9 + (ky * 3 + kx)) * 4 + co];
    }
  }
  out[((size_t)(n * 4 + co) << 12) + (yy << 6) + xx] = acc;
  // fused VQ loss: blocks 0..255 exactly cover co==0, one thread per position
  if (co == 0){
    int k = idxm[sp];
    const float4* c4 = (const float4*)(cb + (k << 6));
    double l = 0;
    #pragma unroll
    for (int q = 0; q < 16; q++){
      float4 z = ((const float4*)Zq)[q * 65536 + sp];
      float4 c = c4[q];
      float d0 = z.x - c.x, d1 = z.y - c.y, d2 = z.z - c.z, d3 = z.w - c.w;
      l += (double)d0 * d0 + (double)d1 * d1 + (double)d2 * d2 + (double)d3 * d3;
    }
    __shared__ double sb[256];
    int t = threadIdx.x;
    sb[t] = l; __syncthreads();
    for (int o = 128; o > 0; o >>= 1){
      if (t < o) sb[t] += sb[t + o];
      __syncthreads();
    }
    if (t == 0) losspart[blockIdx.x] = sb[0];
  }
}

// ---------------- transposed conv k3 s2 p1 op1, 8 co/thread, optional input-BN, fused stats ----------------
template<int CI, int CO, int IHt, int IWt, bool APPLY>
__global__ __launch_bounds__(256) void convT_cob8(const float* __restrict__ in, const float* __restrict__ w,
    const float* __restrict__ bias, const float* __restrict__ ssIn, float* __restrict__ out,
    double* __restrict__ part){
  constexpr int SB = IHt * IWt / 256;
  constexpr int COG = CO / 8;
  constexpr int P = 16 * SB;
  const int OW = IWt * 2;
  int idx = blockIdx.x * 256 + threadIdx.x;
  int ix = idx % IWt, iy = (idx / IWt) % IHt;
  int cog = (idx / (IWt * IHt)) % COG, n = idx / (IWt * IHt * COG);
  cog = __builtin_amdgcn_readfirstlane(cog);
  n   = __builtin_amdgcn_readfirstlane(n);
  float a00[8], a01[8], a10[8], a11[8];
  #pragma unroll
  for (int j = 0; j < 8; j++){ float b = bias[cog * 8 + j]; a00[j] = b; a01[j] = b; a10[j] = b; a11[j] = b; }
  bool okx = (ix + 1 < IWt), oky = (iy + 1 < IHt);
  int ixp = okx ? ix + 1 : ix, iyp = oky ? iy + 1 : iy;
  const float* ip = in + (size_t)n * CI * IHt * IWt;
  #pragma unroll 4
  for (int ci = 0; ci < CI; ci++){
    const float* p = ip + ci * IHt * IWt;
    float v00 = p[iy * IWt + ix];
    float v01 = p[iy * IWt + ixp];
    float v10 = p[iyp * IWt + ix];
    float v11 = p[iyp * IWt + ixp];
    if (APPLY){
      float sc = ssIn[ci], sh = ssIn[CI + ci];
      v00 = lrelu(fmaf(v00, sc, sh));
      v01 = lrelu(fmaf(v01, sc, sh));
      v10 = lrelu(fmaf(v10, sc, sh));
      v11 = lrelu(fmaf(v11, sc, sh));
    }
    if (!okx) v01 = 0.f;
    if (!oky) v10 = 0.f;
    if (!(okx && oky)) v11 = 0.f;
    const float* wp = w + ((size_t)ci * CO + cog * 8) * 9;
    #pragma unroll
    for (int j = 0; j < 8; j++){
      const float* q = wp + j * 9;
      a00[j] = fmaf(q[4], v00, a00[j]);
      a01[j] = fmaf(q[3], v01, a01[j]); a01[j] = fmaf(q[5], v00, a01[j]);
      a10[j] = fmaf(q[1], v10, a10[j]); a10[j] = fmaf(q[7], v00, a10[j]);
      a11[j] = fmaf(q[0], v11, a11[j]); a11[j] = fmaf(q[2], v10, a11[j]);
      a11[j] = fmaf(q[6], v01, a11[j]); a11[j] = fmaf(q[8], v00, a11[j]);
    }
  }
  float sums[8], sqs[8];
  #pragma unroll
  for (int j = 0; j < 8; j++){
    float* o = out + (((size_t)n * CO + cog * 8 + j) * (IHt * 2) + 2 * iy) * OW + 2 * ix;
    float2 r0; r0.x = a00[j]; r0.y = a01[j];
    float2 r1; r1.x = a10[j]; r1.y = a11[j];
    *(float2*)o = r0;
    *(float2*)(o + OW) = r1;
    sums[j] = (a00[j] + a01[j]) + (a10[j] + a11[j]);
    sqs[j] = (a00[j] * a00[j] + a01[j] * a01[j]) + (a10[j] * a10[j] + a11[j] * a11[j]);
  }
  __shared__ float sred[256 * 16];
  int sb = blockIdx.x % SB;
  stats_epilogue<8>(sums, sqs, part, cog * 8, P, n * SB + sb, sred);
}

// ---------------- d3: 32->3 @256x256, LDS-tiled (24 KB), fused bn4 + loss write ----------------
// block = (n, 4-row stripe x full 256 width); ci chunks of 4
__global__ __launch_bounds__(256) void d3_tile(const float* __restrict__ F, const float* __restrict__ w,
    const float* __restrict__ bias, const float* __restrict__ ss, float* __restrict__ out,
    const double* __restrict__ losspart){
  __shared__ float st[4 * 6 * 256];             // 24 KB: [cl][rr][x]
  int t = threadIdx.x;
  int xg = t & 63, r = t >> 6;
  int n = blockIdx.x >> 6, oyb = blockIdx.x & 63;
  int oy = oyb * 4 + r;
  // fused loss finalize (block 0, wave 0; losspart written 3 kernels earlier)
  if (blockIdx.x == 0 && t < 64){
    double s = losspart[t] + losspart[t + 64] + losspart[t + 128] + losspart[t + 192];
    #pragma unroll
    for (int o = 32; o > 0; o >>= 1) s += __shfl_xor(s, o);
    if (t == 0) out[3145728] = (float)(1.25 * s / (65536.0 * 64.0));
  }
  float acc[3][4];
  #pragma unroll
  for (int co = 0; co < 3; co++){
    float b = bias[co];
    #pragma unroll
    for (int j = 0; j < 4; j++) acc[co][j] = b;
  }
  const float* base = F + (size_t)n * 32 * 65536;
  for (int cc = 0; cc < 8; cc++){
    int cib = cc * 4;
    // stage 4 ci x 6 rows x 256 (bn+lrelu applied once here)
    #pragma unroll
    for (int j = 0; j < 6; j++){
      int p = j * 256 + t;                       // 1536 float4 pieces
      int cl = p / 384, rem = p - cl * 384;
      int rr = rem >> 6, xq = rem & 63;
      int g = oyb * 4 - 1 + rr;
      float4 v;
      if ((unsigned)g < 256u){
        v = *(const float4*)(base + ((size_t)(cib + cl) * 256 + g) * 256 + 4 * xq);
        float sc = ss[cib + cl], sh = ss[32 + cib + cl];
        v.x = lrelu(fmaf(v.x, sc, sh));
        v.y = lrelu(fmaf(v.y, sc, sh));
        v.z = lrelu(fmaf(v.z, sc, sh));
        v.w = lrelu(fmaf(v.w, sc, sh));
      } else {
        v.x = 0.f; v.y = 0.f; v.z = 0.f; v.w = 0.f;
      }
      *(float4*)&st[((cl * 6 + rr) << 8) | (4 * xq)] = v;
    }
    __syncthreads();
    #pragma unroll
    for (int cl = 0; cl < 4; cl++){
      #pragma unroll
      for (int ky = 0; ky < 3; ky++){
        int rr = r + ky;
        float4 A = *(const float4*)&st[((cl * 6 + rr) << 8) | (4 * xg)];
        float Lv = __shfl_up(A.w, 1);
        float Rv = __shfl_down(A.x, 1);
        float u0 = (xg == 0) ? 0.f : Lv;
        float u5 = (xg == 63) ? 0.f : Rv;
        float u[6] = {u0, A.x, A.y, A.z, A.w, u5};
        #pragma unroll
        for (int co = 0; co < 3; co++){
          const float* wp = w + ((co * 32 + cib + cl) * 9) + ky * 3;
          #pragma unroll
          for (int j = 0; j < 4; j++){
            acc[co][j] = fmaf(u[j],     wp[0], acc[co][j]);
            acc[co][j] = fmaf(u[j + 1], wp[1], acc[co][j]);
            acc[co][j] = fmaf(u[j + 2], wp[2], acc[co][j]);
          }
        }
      }
    }
    __syncthreads();
  }
  #pragma unroll
  for (int co = 0; co < 3; co++){
    float4 s0;
    s0.x = tanh_fast(acc[co][0]); s0.y = tanh_fast(acc[co][1]);
    s0.z = tanh_fast(acc[co][2]); s0.w = tanh_fast(acc[co][3]);
    float* o = out + ((size_t)(n * 3 + co) * 256 + oy) * 256 + 4 * xg;
    *(float4*)o = s0;
  }
}

// ---------------- launch ----------------
extern "C" void kernel_launch(void* const* d_in, const int* in_sizes, int n_in,
                              void* d_out, int out_size, void* d_ws, size_t ws_size,
                              hipStream_t stream){
  const float* x      = (const float*)d_in[0];
  const float* cb     = (const float*)d_in[1];
  const float* e1_w   = (const float*)d_in[2];
  const float* e1_b   = (const float*)d_in[3];
  const float* bn1_g  = (const float*)d_in[4];
  const float* bn1_b  = (const float*)d_in[5];
  const float* e2_w   = (const float*)d_in[6];
  const float* e2_b   = (const float*)d_in[7];
  const float* bn2_g  = (const float*)d_in[8];
  const float* bn2_b  = (const float*)d_in[9];
  const float* preq_w = (const float*)d_in[10];
  const float* preq_b = (const float*)d_in[11];
  const float* postq_w= (const float*)d_in[12];
  const float* postq_b= (const float*)d_in[13];
  const float* d1_w   = (const float*)d_in[14];
  const float* d1_b   = (const float*)d_in[15];
  const float* bn3_g  = (const float*)d_in[16];
  const float* bn3_b  = (const float*)d_in[17];
  const float* d2_w   = (const float*)d_in[18];
  const float* d2_b   = (const float*)d_in[19];
  const float* bn4_g  = (const float*)d_in[20];
  const float* bn4_b  = (const float*)d_in[21];
  const float* d3_w   = (const float*)d_in[22];
  const float* d3_b   = (const float*)d_in[23];
  float* out = (float*)d_out;
  char* ws = (char*)d_ws;

  double* losspart = (double*)ws;                        // 2048 B
  int*    flagcnt  = (int*)(ws + 2048);                  // 64 B
  float*  ss       = (float*)(ws + 4096);                // 576 B
  double* cb64     = (double*)(ws + 8192);               // 512 KB
  double* cbn64    = (double*)(ws + 532480);             // 8 KB
  float*  cbn32    = (float*)(ws + 540672);              // 4 KB
  unsigned short* cbh = (unsigned short*)(ws + 544768);  // 128 KB
  unsigned short* cbl = (unsigned short*)(ws + 675840);  // 128 KB
  int*    flaglist = (int*)(ws + 806912);                // 256 KB
  int*    idx      = (int*)(ws + 1069056);               // 256 KB
  double* part_e1  = (double*)(ws + 1331200);            // 128 KB
  double* part_e2  = (double*)(ws + 1462272);            // 16 KB
  float*  Ptab     = (float*)(ws + 1478656);             // 147 KB (aliases part_d1/d2 head; dead before d1 stats)
  double* part_d1  = (double*)(ws + 1478656);            // 64 KB (written by d1, after postq_gather)
  double* part_d2  = (double*)(ws + 1544192);            // 512 KB (written by d2, after postq_gather)
  float*  A        = (float*)(ws + 2097152);             // 16.78 MB
  float*  B        = (float*)(ws + 18874368);            // 1 MB
  float*  Zq       = (float*)(ws + 19922944);            // 16.78 MB
  float*  F        = (float*)(ws + 36700160);            // 134.2 MB

  float *ss1 = ss + 0, *ss2 = ss + 32, *ss3 = ss + 48, *ss4 = ss + 80;
  float* D = B;   // B dead after preq

  prep_all<<<40, 256, 0, stream>>>(cb, cb64, cbn64, cbn32, cbh, cbl, flagcnt, postq_w, Ptab);

  // encoder
  e1_conv<<<512, 256, 0, stream>>>(x, e1_w, e1_b, A, part_e1);
  bn_red_fin<<<16, 256, 0, stream>>>(part_e1, 512, bn1_g, bn1_b, ss1, 16, 262144.0);
  e2_conv<<<256, 256, 0, stream>>>(A, e2_w, e2_b, ss1, B, part_e2);
  bn_red_fin<<<4, 256, 0, stream>>>(part_e2, 256, bn2_g, bn2_b, ss2, 4, 65536.0);
  preq_conv<<<4096, 256, 0, stream>>>(B, preq_w, preq_b, ss2, Zq);

  // VQ
  vq_screen_mfma<<<512, 256, 0, stream>>>(Zq, cbh, cbl, cbn32, idx, flagcnt, flaglist);
  vq_refine<<<128, 256, 0, stream>>>(Zq, cb64, cbn64, flagcnt, flaglist, idx);

  // decoder (postq_gather also computes VQ loss partials)
  postq_gather<<<1024, 256, 0, stream>>>(Ptab, idx, postq_b, D, Zq, cb, losspart);
  convT_cob8<4, 16, 64, 64, false><<<512, 256, 0, stream>>>(D, d1_w, d1_b, nullptr, A, part_d1);
  bn_red_fin<<<16, 256, 0, stream>>>(part_d1, 256, bn3_g, bn3_b, ss3, 16, 262144.0);
  convT_cob8<16, 32, 128, 128, true><<<4096, 256, 0, stream>>>(A, d2_w, d2_b, ss3, F, part_d2);
  bn_red_fin<<<32, 256, 0, stream>>>(part_d2, 1024, bn4_g, bn4_b, ss4, 32, 1048576.0);
  d3_tile<<<1024, 256, 0, stream>>>(F, d3_w, d3_b, ss4, out, losspart);
}

// Round 8
// 301.702 us; speedup vs baseline: 5.2289x; 1.0208x over previous
//
#include <hip/hip_runtime.h>
#include <math.h>

#define EPSV 1e-5
#define SLOPE 0.1f

typedef __attribute__((ext_vector_type(4))) float f32x4;
typedef __attribute__((ext_vector_type(8))) short short8x;

__device__ __forceinline__ float lrelu(float x){ return x >= 0.f ? x : SLOPE * x; }
__device__ __forceinline__ float tanh_fast(float x){
  float e = __expf(2.f * x);
  return 1.f - 2.f / (e + 1.f);
}
__device__ __forceinline__ unsigned bf16rne(float f){
  unsigned u = __float_as_uint(f);
  u += 0x7fff + ((u >> 16) & 1);
  return u >> 16;
}

// ---- block BN-stats epilogue: per-thread CL channel sums/sqs -> f64 partials ----
template<int CL>
__device__ __forceinline__ void stats_epilogue(const float* sums, const float* sqs,
    double* __restrict__ part, int chbase, int P, int p, float* sred){
  const int C2 = 2 * CL;
  int t = threadIdx.x;
  #pragma unroll
  for (int c = 0; c < CL; c++){
    sred[t * C2 + c] = sums[c];
    sred[t * C2 + CL + c] = sqs[c];
  }
  __syncthreads();
  if (t < 64){
    int c = t % C2;
    int g = t / C2;
    const int G = 64 / C2;
    const int R = 256 / G;
    double s = 0;
    for (int r = g * R; r < (g + 1) * R; r++) s += (double)sred[r * C2 + c];
    #pragma unroll
    for (int off = C2; off < 64; off <<= 1) s += __shfl_xor(s, off);
    if (t < C2){
      int ch = chbase + (c < CL ? c : c - CL);
      part[(size_t)ch * 2 * P + (c < CL ? 0 : P) + p] = s;
    }
  }
}

// ---- reduce partials + finalize scale/shift ----
__global__ __launch_bounds__(256) void bn_red_fin(const double* __restrict__ part, int P,
    const float* __restrict__ g, const float* __restrict__ b, float* __restrict__ ss, int C, double count){
  int c = blockIdx.x;
  __shared__ double r0[256], r1[256];
  int t = threadIdx.x;
  double s = 0, q = 0;
  for (int p = t; p < P; p += 256){
    s += part[(size_t)c * 2 * P + p];
    q += part[(size_t)c * 2 * P + P + p];
  }
  r0[t] = s; r1[t] = q; __syncthreads();
  for (int o = 128; o > 0; o >>= 1){
    if (t < o){ r0[t] += r0[t + o]; r1[t] += r1[t + o]; }
    __syncthreads();
  }
  if (t == 0){
    double m = r0[0] / count;
    double var = r1[0] / count - m * m;
    double scale = (double)g[c] / sqrt(var + EPSV);
    ss[c] = (float)scale;
    ss[C + c] = (float)((double)b[c] - m * scale);
  }
}

// ---------------- e1: 3->16 s2, 256->128, 2 x-outputs/thread, fused bn1-stats ----------------
__global__ __launch_bounds__(256) void e1_conv(const float* __restrict__ x, const float* __restrict__ w,
    const float* __restrict__ bias, float* __restrict__ out, double* __restrict__ part){
  int idx = blockIdx.x * 256 + threadIdx.x;
  int ox2 = idx & 63, oy = (idx >> 6) & 127, n = idx >> 13;
  float acc[16][2];
  #pragma unroll
  for (int co = 0; co < 16; co++){ float b = bias[co]; acc[co][0] = b; acc[co][1] = b; }
  int ix0 = 4 * ox2 - 1;
  int lclamp = (ox2 > 0) ? ix0 : 0;
  const float* xp = x + (size_t)n * 3 * 65536;
  #pragma unroll
  for (int ci = 0; ci < 3; ci++){
    const float* pl = xp + ci * 65536;
    #pragma unroll
    for (int ky = 0; ky < 3; ky++){
      int iy = 2 * oy - 1 + ky;
      if (iy >= 0){
        const float* row = pl + iy * 256;
        float l = row[lclamp];
        float4 m = *(const float4*)(row + ix0 + 1);
        float v0 = (ox2 > 0) ? l : 0.f;
        #pragma unroll
        for (int co = 0; co < 16; co++){
          const float* wp = w + ((co * 3 + ci) * 3 + ky) * 3;
          acc[co][0] = fmaf(v0,  wp[0], acc[co][0]);
          acc[co][0] = fmaf(m.x, wp[1], acc[co][0]);
          acc[co][0] = fmaf(m.y, wp[2], acc[co][0]);
          acc[co][1] = fmaf(m.y, wp[0], acc[co][1]);
          acc[co][1] = fmaf(m.z, wp[1], acc[co][1]);
          acc[co][1] = fmaf(m.w, wp[2], acc[co][1]);
        }
      }
    }
  }
  float sums[16], sqs[16];
  #pragma unroll
  for (int co = 0; co < 16; co++){
    float2 st; st.x = acc[co][0]; st.y = acc[co][1];
    *(float2*)(out + ((size_t)(n * 16 + co) * 128 + oy) * 128 + 2 * ox2) = st;
    sums[co] = acc[co][0] + acc[co][1];
    sqs[co] = acc[co][0] * acc[co][0] + acc[co][1] * acc[co][1];
  }
  __shared__ float sred[256 * 32];
  stats_epilogue<16>(sums, sqs, part, 0, 512, blockIdx.x, sred);
}

// ---------------- e2: 16->4 s2 with fused bn1-apply on loads + bn2-stats ----------------
__global__ __launch_bounds__(256) void e2_conv(const float* __restrict__ in, const float* __restrict__ w,
    const float* __restrict__ bias, const float* __restrict__ ssIn, float* __restrict__ out,
    double* __restrict__ part){
  int idx = blockIdx.x * 256 + threadIdx.x;
  int ox = idx & 63, oy = (idx >> 6) & 63, n = idx >> 12;
  float acc[4];
  #pragma unroll
  for (int j = 0; j < 4; j++) acc[j] = bias[j];
  int iy0 = oy * 2 - 1, ix0 = ox * 2 - 1;
  const float* ip = in + (size_t)n * 16 * 16384;
  #pragma unroll
  for (int ky = 0; ky < 3; ky++){
    int iy = iy0 + ky; if ((unsigned)iy >= 128u) continue;
    #pragma unroll
    for (int kx = 0; kx < 3; kx++){
      int ix = ix0 + kx; if ((unsigned)ix >= 128u) continue;
      const float* r = ip + iy * 128 + ix;
      #pragma unroll
      for (int ci = 0; ci < 16; ci++){
        float v = lrelu(fmaf(r[ci * 16384], ssIn[ci], ssIn[16 + ci]));
        #pragma unroll
        for (int co = 0; co < 4; co++)
          acc[co] = fmaf(v, w[(co * 16 + ci) * 9 + ky * 3 + kx], acc[co]);
      }
    }
  }
  float sums[4], sqs[4];
  #pragma unroll
  for (int co = 0; co < 4; co++){
    out[(((size_t)n * 4 + co) * 64 + oy) * 64 + ox] = acc[co];
    sums[co] = acc[co];
    sqs[co] = acc[co] * acc[co];
  }
  __shared__ float sred[256 * 8];
  stats_epilogue<4>(sums, sqs, part, 0, 256, blockIdx.x, sred);
}

// ---------------- preq: fused bn2-apply, output plane layout Zq[coq][pos][4] ----------------
__global__ __launch_bounds__(256) void preq_conv(const float* __restrict__ in, const float* __restrict__ w,
    const float* __restrict__ bias, const float* __restrict__ ssIn, float* __restrict__ Zq){
  int idx = blockIdx.x * 256 + threadIdx.x;
  int sp = idx & 65535;
  int coq = idx >> 16;
  int x = sp & 63, y = (sp >> 6) & 63, n = sp >> 12;
  float scv[4] = {ssIn[0], ssIn[1], ssIn[2], ssIn[3]};
  float shv[4] = {ssIn[4], ssIn[5], ssIn[6], ssIn[7]};
  float a0 = bias[coq * 4 + 0], a1 = bias[coq * 4 + 1], a2 = bias[coq * 4 + 2], a3 = bias[coq * 4 + 3];
  const float* ip = in + (size_t)n * 4 * 4096;
  #pragma unroll
  for (int ky = 0; ky < 3; ky++){
    int iy = y - 1 + ky; if ((unsigned)iy >= 64u) continue;
    #pragma unroll
    for (int kx = 0; kx < 3; kx++){
      int ix = x - 1 + kx; if ((unsigned)ix >= 64u) continue;
      #pragma unroll
      for (int ci = 0; ci < 4; ci++){
        float v = lrelu(fmaf(ip[ci * 4096 + iy * 64 + ix], scv[ci], shv[ci]));
        const float* wp = w + ((coq * 4) * 4 + ci) * 9 + ky * 3 + kx;
        a0 = fmaf(v, wp[0], a0);
        a1 = fmaf(v, wp[36], a1);
        a2 = fmaf(v, wp[72], a2);
        a3 = fmaf(v, wp[108], a3);
      }
    }
  }
  float4 o; o.x = a0; o.y = a1; o.z = a2; o.w = a3;
  ((float4*)Zq)[coq * 65536 + sp] = o;
}

// ---------------- prep_all: blocks 0-3 VQ codebook prep, blocks 4-39 postq P-table ----------------
__global__ __launch_bounds__(256) void prep_all(const float* __restrict__ cb, double* __restrict__ cb64,
    double* __restrict__ cbn64, float* __restrict__ cbn32, unsigned short* __restrict__ cbh,
    unsigned short* __restrict__ cbl, int* __restrict__ flagcnt,
    const float* __restrict__ pw, float* __restrict__ P){
  int t = threadIdx.x;
  if (blockIdx.x < 4){
    int k = blockIdx.x * 256 + t;
    if (k == 0) flagcnt[0] = 0;
    double s = 0;
    for (int d = 0; d < 64; d++){
      float v = cb[k * 64 + d];
      cb64[(size_t)k * 64 + d] = (double)v;
      s = fma((double)v, (double)v, s);
      unsigned h = bf16rne(v);
      float hf = __uint_as_float(h << 16);
      unsigned l = bf16rne(v - hf);
      cbh[k * 64 + d] = (unsigned short)h;
      cbl[k * 64 + d] = (unsigned short)l;
    }
    cbn64[k] = s;
    cbn32[k] = (float)s;
  } else {
    int gid = (blockIdx.x - 4) * 256 + t;
    if (gid >= 9216) return;
    int k = gid / 9, tap = gid - k * 9;
    float a0 = 0.f, a1 = 0.f, a2 = 0.f, a3 = 0.f;
    const float* cp = cb + (k << 6);
    #pragma unroll 16
    for (int ci = 0; ci < 64; ci++){
      float c = cp[ci];
      a0 = fmaf(c, pw[(0 * 64 + ci) * 9 + tap], a0);
      a1 = fmaf(c, pw[(1 * 64 + ci) * 9 + tap], a1);
      a2 = fmaf(c, pw[(2 * 64 + ci) * 9 + tap], a2);
      a3 = fmaf(c, pw[(3 * 64 + ci) * 9 + tap], a3);
    }
    float4 o; o.x = a0; o.y = a1; o.z = a2; o.w = a3;
    ((float4*)P)[gid] = o;
  }
}

// ---------------- VQ screen via MFMA: per-step (128-code) partial bests + global merge ----------------
__global__ __launch_bounds__(256) void vq_screen_mfma(const float* __restrict__ Zq,
    const unsigned short* __restrict__ cbh, const unsigned short* __restrict__ cbl,
    const float* __restrict__ cbn32, int* __restrict__ idxout,
    int* __restrict__ flagcnt, int* __restrict__ flaglist, float* __restrict__ stepb){
  __shared__ unsigned short lcb[32 * 64 * 8];
  __shared__ float lcn[128];
  int t = threadIdx.x;
  int lane = t & 63;
  int w = t >> 6;
  int col = lane & 15, hg = lane >> 4;
  int pos0 = blockIdx.x * 128 + w * 32;
  int posA = pos0 + col, posB = pos0 + 16 + col;
  const float4* Zq4 = (const float4*)Zq;
  short8x zhA[2], zlA[2], zhB[2], zlB[2];
  #pragma unroll
  for (int kc = 0; kc < 2; kc++){
    #pragma unroll
    for (int tb = 0; tb < 2; tb++){
      int pos = tb ? posB : posA;
      float4 f0 = Zq4[(size_t)(8 * kc + 2 * hg) * 65536 + pos];
      float4 f1 = Zq4[(size_t)(8 * kc + 2 * hg + 1) * 65536 + pos];
      float zv[8] = {f0.x, f0.y, f0.z, f0.w, f1.x, f1.y, f1.z, f1.w};
      union { unsigned u[4]; short8x v; } H, L;
      #pragma unroll
      for (int j = 0; j < 4; j++){
        unsigned h0 = bf16rne(zv[2 * j]);
        unsigned h1 = bf16rne(zv[2 * j + 1]);
        float hf0 = __uint_as_float(h0 << 16);
        float hf1 = __uint_as_float(h1 << 16);
        unsigned l0 = bf16rne(zv[2 * j] - hf0);
        unsigned l1 = bf16rne(zv[2 * j + 1] - hf1);
        H.u[j] = h0 | (h1 << 16);
        L.u[j] = l0 | (l1 << 16);
      }
      if (tb){ zhB[kc] = H.v; zlB[kc] = L.v; } else { zhA[kc] = H.v; zlA[kc] = L.v; }
    }
  }
  float BA = 3.0e38f, SA = 3.0e38f, BB = 3.0e38f, SBt = 3.0e38f;
  int IA = 0, IB = 0;
  for (int step = 0; step < 8; step++){
    int code0 = step * 128;
    __syncthreads();
    #pragma unroll
    for (int i = 0; i < 8; i++){
      int piece = i * 256 + t;
      int fb = piece >> 6, pl = piece & 63;
      int g = fb >> 2, kc = (fb >> 1) & 1, sp = fb & 1;
      const unsigned short* src = (sp ? cbl : cbh)
          + ((size_t)(code0 + g * 16 + (pl & 15)) << 6) + kc * 32 + ((pl >> 4) << 3);
      *(uint4*)&lcb[piece * 8] = *(const uint4*)src;
    }
    if (t < 128) lcn[t] = cbn32[code0 + t];
    __syncthreads();
    float bA = 3.0e38f, sA = 3.0e38f, bB = 3.0e38f, sB = 3.0e38f;
    int iA = 0, iB = 0;
    #pragma unroll 2
    for (int g = 0; g < 8; g++){
      const short8x* lc8 = (const short8x*)lcb;
      short8x Ah0 = lc8[(g * 4 + 0) * 64 + lane];
      short8x Al0 = lc8[(g * 4 + 1) * 64 + lane];
      short8x Ah1 = lc8[(g * 4 + 2) * 64 + lane];
      short8x Al1 = lc8[(g * 4 + 3) * 64 + lane];
      f32x4 accA = {0.f, 0.f, 0.f, 0.f};
      f32x4 accB = {0.f, 0.f, 0.f, 0.f};
      accA = __builtin_amdgcn_mfma_f32_16x16x32_bf16(Ah0, zhA[0], accA, 0, 0, 0);
      accA = __builtin_amdgcn_mfma_f32_16x16x32_bf16(Ah1, zhA[1], accA, 0, 0, 0);
      accA = __builtin_amdgcn_mfma_f32_16x16x32_bf16(Ah0, zlA[0], accA, 0, 0, 0);
      accA = __builtin_amdgcn_mfma_f32_16x16x32_bf16(Ah1, zlA[1], accA, 0, 0, 0);
      accA = __builtin_amdgcn_mfma_f32_16x16x32_bf16(Al0, zhA[0], accA, 0, 0, 0);
      accA = __builtin_amdgcn_mfma_f32_16x16x32_bf16(Al1, zhA[1], accA, 0, 0, 0);
      accB = __builtin_amdgcn_mfma_f32_16x16x32_bf16(Ah0, zhB[0], accB, 0, 0, 0);
      accB = __builtin_amdgcn_mfma_f32_16x16x32_bf16(Ah1, zhB[1], accB, 0, 0, 0);
      accB = __builtin_amdgcn_mfma_f32_16x16x32_bf16(Ah0, zlB[0], accB, 0, 0, 0);
      accB = __builtin_amdgcn_mfma_f32_16x16x32_bf16(Ah1, zlB[1], accB, 0, 0, 0);
      accB = __builtin_amdgcn_mfma_f32_16x16x32_bf16(Al0, zhB[0], accB, 0, 0, 0);
      accB = __builtin_amdgcn_mfma_f32_16x16x32_bf16(Al1, zhB[1], accB, 0, 0, 0);
      int cbase = code0 + g * 16 + 4 * hg;
      #pragma unroll
      for (int r = 0; r < 4; r++){
        float cn = lcn[g * 16 + 4 * hg + r];
        float vA = fmaf(accA[r], -2.0f, cn);
        sA = fminf(sA, fmaxf(vA, bA));
        if (vA < bA){ bA = vA; iA = cbase + r; }
        float vB = fmaf(accB[r], -2.0f, cn);
        sB = fminf(sB, fmaxf(vB, bB));
        if (vB < bB){ bB = vB; iB = cbase + r; }
      }
    }
    // wave-reduce step bests over hg (off 16, 32)
    #pragma unroll
    for (int off = 16; off <= 32; off <<= 1){
      float ob = __shfl_xor(bA, off);
      float os = __shfl_xor(sA, off);
      int oi = __shfl_xor(iA, off);
      sA = fminf(fminf(sA, os), fmaxf(bA, ob));
      if (ob < bA){ bA = ob; iA = oi; }
      ob = __shfl_xor(bB, off);
      os = __shfl_xor(sB, off);
      oi = __shfl_xor(iB, off);
      sB = fminf(fminf(sB, os), fmaxf(bB, ob));
      if (ob < bB){ bB = ob; iB = oi; }
    }
    if (hg == 0){
      stepb[step * 65536 + posA] = bA;
      stepb[step * 65536 + posB] = bB;
    }
    // merge into global top-2
    if (bA < BA){ SA = fminf(BA, sA); BA = bA; IA = iA; } else SA = fminf(SA, bA);
    if (bB < BB){ SBt = fminf(BB, sB); BB = bB; IB = iB; } else SBt = fminf(SBt, bB);
  }
  if (hg == 0){
    idxout[posA] = IA;
    if (SA - BA < 1.2e-2f){
      int slot = atomicAdd(flagcnt, 1);
      flaglist[slot] = posA;
    }
    idxout[posB] = IB;
    if (SBt - BB < 1.2e-2f){
      int slot = atomicAdd(flagcnt, 1);
      flaglist[slot] = posB;
    }
  }
}

// ---------------- VQ refine: exact f64 re-rank over candidate steps only ----------------
__global__ __launch_bounds__(256) void vq_refine(const float* __restrict__ Zq, const double* __restrict__ cb64,
    const double* __restrict__ cbn64, const int* __restrict__ flagcnt, const int* __restrict__ flaglist,
    const float* __restrict__ stepb, int* __restrict__ idxout){
  int gw = (blockIdx.x * 256 + threadIdx.x) >> 6;
  int lane = threadIdx.x & 63;
  int nf = flagcnt[0];
  for (int f = gw; f < nf; f += 512){
    int pos = flaglist[f];
    float zr[64];
    #pragma unroll
    for (int q = 0; q < 16; q++){
      float4 v = ((const float4*)Zq)[q * 65536 + pos];
      zr[4 * q] = v.x; zr[4 * q + 1] = v.y; zr[4 * q + 2] = v.z; zr[4 * q + 3] = v.w;
    }
    float sb[8];
    float B = 3.0e38f;
    #pragma unroll
    for (int s = 0; s < 8; s++){ sb[s] = stepb[s * 65536 + pos]; B = fminf(B, sb[s]); }
    float lim = B + 1.2e-2f;
    double best = 1e300; int bi = 1 << 30;
    #pragma unroll
    for (int s = 0; s < 8; s++){
      if (sb[s] < lim){
        int k0 = s * 128 + 2 * lane;
        #pragma unroll
        for (int kk = 0; kk < 2; kk++){
          int k = k0 + kk;
          const double* c = cb64 + (size_t)k * 64;
          double a0 = 0, a1 = 0, a2 = 0, a3 = 0;
          #pragma unroll
          for (int d = 0; d < 64; d += 4){
            a0 = fma(c[d], (double)zr[d], a0);
            a1 = fma(c[d + 1], (double)zr[d + 1], a1);
            a2 = fma(c[d + 2], (double)zr[d + 2], a2);
            a3 = fma(c[d + 3], (double)zr[d + 3], a3);
          }
          double sc = cbn64[k] - 2.0 * ((a0 + a1) + (a2 + a3));
          if (sc < best){ best = sc; bi = k; }   // per-lane k ascending -> first-min
        }
      }
    }
    #pragma unroll
    for (int o = 32; o > 0; o >>= 1){
      double ob = __shfl_xor(best, o);
      int oi = __shfl_xor(bi, o);
      if (ob < best || (ob == best && oi < bi)){ best = ob; bi = oi; }
    }
    if (lane == 0) idxout[pos] = bi;
  }
}

// ---------------- postq gather: out[pos][co] = bias + sum_tap P[idx[nbr]][tap][co]; fused loss ----------------
__global__ __launch_bounds__(256) void postq_gather(const float* __restrict__ P, const int* __restrict__ idxm,
    const float* __restrict__ bias, float* __restrict__ out,
    const float* __restrict__ Zq, const float* __restrict__ cb, double* __restrict__ losspart){
  int gid = blockIdx.x * 256 + threadIdx.x;
  int sp = gid & 65535;
  int co = gid >> 16;
  co = __builtin_amdgcn_readfirstlane(co);
  int xx = sp & 63, yy = (sp >> 6) & 63, n = sp >> 12;
  float acc = bias[co];
  #pragma unroll
  for (int ky = 0; ky < 3; ky++){
    int iy = yy - 1 + ky; if ((unsigned)iy >= 64u) continue;
    #pragma unroll
    for (int kx = 0; kx < 3; kx++){
      int ix = xx - 1 + kx; if ((unsigned)ix >= 64u) continue;
      int spt = (n << 12) + (iy << 6) + ix;
      int k = idxm[spt];
      acc += P[(k * 9 + (ky * 3 + kx)) * 4 + co];
    }
  }
  out[((size_t)(n * 4 + co) << 12) + (yy << 6) + xx] = acc;
  if (co == 0){
    int k = idxm[sp];
    const float4* c4 = (const float4*)(cb + (k << 6));
    double l = 0;
    #pragma unroll
    for (int q = 0; q < 16; q++){
      float4 z = ((const float4*)Zq)[q * 65536 + sp];
      float4 c = c4[q];
      float d0 = z.x - c.x, d1 = z.y - c.y, d2 = z.z - c.z, d3 = z.w - c.w;
      l += (double)d0 * d0 + (double)d1 * d1 + (double)d2 * d2 + (double)d3 * d3;
    }
    __shared__ double sb[256];
    int t = threadIdx.x;
    sb[t] = l; __syncthreads();
    for (int o = 128; o > 0; o >>= 1){
      if (t < o) sb[t] += sb[t + o];
      __syncthreads();
    }
    if (t == 0) losspart[blockIdx.x] = sb[0];
  }
}

// ---------------- transposed conv k3 s2 p1 op1: 2-wide-x threads, float2 loads, float4 stores ----------------
template<int CI, int CO, int IHt, int IWt, bool APPLY>
__global__ __launch_bounds__(256) void convT_w2(const float* __restrict__ in, const float* __restrict__ w,
    const float* __restrict__ bias, const float* __restrict__ ssIn, float* __restrict__ out,
    double* __restrict__ part){
  constexpr int IWH = IWt / 2;
  constexpr int COG = CO / 8;
  constexpr int SB = IHt * IWH * COG / 256;
  constexpr int P = 16 * SB;
  const int OW = IWt * 2;
  int idx = blockIdx.x * 256 + threadIdx.x;
  int ixp = idx % IWH;
  int iy = (idx / IWH) % IHt;
  int cog = (idx / (IWH * IHt)) % COG;
  int n = idx / (IWH * IHt * COG);
  cog = __builtin_amdgcn_readfirstlane(cog);
  n   = __builtin_amdgcn_readfirstlane(n);
  float a[8][8];
  #pragma unroll
  for (int j = 0; j < 8; j++){
    float b = bias[cog * 8 + j];
    #pragma unroll
    for (int q = 0; q < 8; q++) a[j][q] = b;
  }
  bool oky = (iy + 1 < IHt);
  bool okx = (2 * ixp + 2 < IWt);
  int iyp = oky ? iy + 1 : iy;
  int xe = okx ? 2 : 0;
  const float* ip = in + (size_t)n * CI * IHt * IWt;
  #pragma unroll 4
  for (int ci = 0; ci < CI; ci++){
    const float* r0 = ip + ci * IHt * IWt + iy * IWt + 2 * ixp;
    const float* r1 = ip + ci * IHt * IWt + iyp * IWt + 2 * ixp;
    float2 va = *(const float2*)r0;
    float ve = r0[xe];
    float2 vb = *(const float2*)r1;
    float vf = r1[xe];
    if (APPLY){
      float sc = ssIn[ci], sh = ssIn[CI + ci];
      va.x = lrelu(fmaf(va.x, sc, sh));
      va.y = lrelu(fmaf(va.y, sc, sh));
      ve   = lrelu(fmaf(ve,   sc, sh));
      vb.x = lrelu(fmaf(vb.x, sc, sh));
      vb.y = lrelu(fmaf(vb.y, sc, sh));
      vf   = lrelu(fmaf(vf,   sc, sh));
    }
    if (!okx){ ve = 0.f; vf = 0.f; }
    if (!oky){ vb.x = 0.f; vb.y = 0.f; vf = 0.f; }
    const float* wp = w + ((size_t)ci * CO + cog * 8) * 9;
    #pragma unroll
    for (int j = 0; j < 8; j++){
      const float* q = wp + j * 9;
      // quad0 (input col 2ixp): v00=va.x v01=va.y v10=vb.x v11=vb.y
      a[j][0] = fmaf(q[4], va.x, a[j][0]);
      a[j][1] = fmaf(q[3], va.y, a[j][1]); a[j][1] = fmaf(q[5], va.x, a[j][1]);
      a[j][2] = fmaf(q[1], vb.x, a[j][2]); a[j][2] = fmaf(q[7], va.x, a[j][2]);
      a[j][3] = fmaf(q[0], vb.y, a[j][3]); a[j][3] = fmaf(q[2], vb.x, a[j][3]);
      a[j][3] = fmaf(q[6], va.y, a[j][3]); a[j][3] = fmaf(q[8], va.x, a[j][3]);
      // quad1 (input col 2ixp+1): v00=va.y v01=ve v10=vb.y v11=vf
      a[j][4] = fmaf(q[4], va.y, a[j][4]);
      a[j][5] = fmaf(q[3], ve,   a[j][5]); a[j][5] = fmaf(q[5], va.y, a[j][5]);
      a[j][6] = fmaf(q[1], vb.y, a[j][6]); a[j][6] = fmaf(q[7], va.y, a[j][6]);
      a[j][7] = fmaf(q[0], vf,   a[j][7]); a[j][7] = fmaf(q[2], vb.y, a[j][7]);
      a[j][7] = fmaf(q[6], ve,   a[j][7]); a[j][7] = fmaf(q[8], va.y, a[j][7]);
    }
  }
  float sums[8], sqs[8];
  #pragma unroll
  for (int j = 0; j < 8; j++){
    float4 R0; R0.x = a[j][0]; R0.y = a[j][1]; R0.z = a[j][4]; R0.w = a[j][5];
    float4 R1; R1.x = a[j][2]; R1.y = a[j][3]; R1.z = a[j][6]; R1.w = a[j][7];
    float* o = out + (((size_t)n * CO + cog * 8 + j) * (IHt * 2) + 2 * iy) * OW + 4 * ixp;
    *(float4*)o = R0;
    *(float4*)(o + OW) = R1;
    sums[j] = ((a[j][0] + a[j][1]) + (a[j][2] + a[j][3])) + ((a[j][4] + a[j][5]) + (a[j][6] + a[j][7]));
    sqs[j]  = ((a[j][0]*a[j][0] + a[j][1]*a[j][1]) + (a[j][2]*a[j][2] + a[j][3]*a[j][3]))
            + ((a[j][4]*a[j][4] + a[j][5]*a[j][5]) + (a[j][6]*a[j][6] + a[j][7]*a[j][7]));
  }
  __shared__ float sred[256 * 16];
  stats_epilogue<8>(sums, sqs, part, cog * 8, P, n * SB + (blockIdx.x % SB), sred);
}

// ---------------- d3: 32->3 @256x256, LDS-tiled (24 KB), fused bn4 + loss write ----------------
__global__ __launch_bounds__(256) void d3_tile(const float* __restrict__ F, const float* __restrict__ w,
    const float* __restrict__ bias, const float* __restrict__ ss, float* __restrict__ out,
    const double* __restrict__ losspart){
  __shared__ float st[4 * 6 * 256];
  int t = threadIdx.x;
  int xg = t & 63, r = t >> 6;
  int n = blockIdx.x >> 6, oyb = blockIdx.x & 63;
  int oy = oyb * 4 + r;
  if (blockIdx.x == 0 && t < 64){
    double s = losspart[t] + losspart[t + 64] + losspart[t + 128] + losspart[t + 192];
    #pragma unroll
    for (int o = 32; o > 0; o >>= 1) s += __shfl_xor(s, o);
    if (t == 0) out[3145728] = (float)(1.25 * s / (65536.0 * 64.0));
  }
  float acc[3][4];
  #pragma unroll
  for (int co = 0; co < 3; co++){
    float b = bias[co];
    #pragma unroll
    for (int j = 0; j < 4; j++) acc[co][j] = b;
  }
  const float* base = F + (size_t)n * 32 * 65536;
  for (int cc = 0; cc < 8; cc++){
    int cib = cc * 4;
    #pragma unroll
    for (int j = 0; j < 6; j++){
      int p = j * 256 + t;
      int cl = p / 384, rem = p - cl * 384;
      int rr = rem >> 6, xq = rem & 63;
      int g = oyb * 4 - 1 + rr;
      float4 v;
      if ((unsigned)g < 256u){
        v = *(const float4*)(base + ((size_t)(cib + cl) * 256 + g) * 256 + 4 * xq);
        float sc = ss[cib + cl], sh = ss[32 + cib + cl];
        v.x = lrelu(fmaf(v.x, sc, sh));
        v.y = lrelu(fmaf(v.y, sc, sh));
        v.z = lrelu(fmaf(v.z, sc, sh));
        v.w = lrelu(fmaf(v.w, sc, sh));
      } else {
        v.x = 0.f; v.y = 0.f; v.z = 0.f; v.w = 0.f;
      }
      *(float4*)&st[((cl * 6 + rr) << 8) | (4 * xq)] = v;
    }
    __syncthreads();
    #pragma unroll
    for (int cl = 0; cl < 4; cl++){
      #pragma unroll
      for (int ky = 0; ky < 3; ky++){
        int rr = r + ky;
        float4 A = *(const float4*)&st[((cl * 6 + rr) << 8) | (4 * xg)];
        float Lv = __shfl_up(A.w, 1);
        float Rv = __shfl_down(A.x, 1);
        float u0 = (xg == 0) ? 0.f : Lv;
        float u5 = (xg == 63) ? 0.f : Rv;
        float u[6] = {u0, A.x, A.y, A.z, A.w, u5};
        #pragma unroll
        for (int co = 0; co < 3; co++){
          const float* wp = w + ((co * 32 + cib + cl) * 9) + ky * 3;
          #pragma unroll
          for (int j = 0; j < 4; j++){
            acc[co][j] = fmaf(u[j],     wp[0], acc[co][j]);
            acc[co][j] = fmaf(u[j + 1], wp[1], acc[co][j]);
            acc[co][j] = fmaf(u[j + 2], wp[2], acc[co][j]);
          }
        }
      }
    }
    __syncthreads();
  }
  #pragma unroll
  for (int co = 0; co < 3; co++){
    float4 s0;
    s0.x = tanh_fast(acc[co][0]); s0.y = tanh_fast(acc[co][1]);
    s0.z = tanh_fast(acc[co][2]); s0.w = tanh_fast(acc[co][3]);
    float* o = out + ((size_t)(n * 3 + co) * 256 + oy) * 256 + 4 * xg;
    *(float4*)o = s0;
  }
}

// ---------------- launch ----------------
extern "C" void kernel_launch(void* const* d_in, const int* in_sizes, int n_in,
                              void* d_out, int out_size, void* d_ws, size_t ws_size,
                              hipStream_t stream){
  const float* x      = (const float*)d_in[0];
  const float* cb     = (const float*)d_in[1];
  const float* e1_w   = (const float*)d_in[2];
  const float* e1_b   = (const float*)d_in[3];
  const float* bn1_g  = (const float*)d_in[4];
  const float* bn1_b  = (const float*)d_in[5];
  const float* e2_w   = (const float*)d_in[6];
  const float* e2_b   = (const float*)d_in[7];
  const float* bn2_g  = (const float*)d_in[8];
  const float* bn2_b  = (const float*)d_in[9];
  const float* preq_w = (const float*)d_in[10];
  const float* preq_b = (const float*)d_in[11];
  const float* postq_w= (const float*)d_in[12];
  const float* postq_b= (const float*)d_in[13];
  const float* d1_w   = (const float*)d_in[14];
  const float* d1_b   = (const float*)d_in[15];
  const float* bn3_g  = (const float*)d_in[16];
  const float* bn3_b  = (const float*)d_in[17];
  const float* d2_w   = (const float*)d_in[18];
  const float* d2_b   = (const float*)d_in[19];
  const float* bn4_g  = (const float*)d_in[20];
  const float* bn4_b  = (const float*)d_in[21];
  const float* d3_w   = (const float*)d_in[22];
  const float* d3_b   = (const float*)d_in[23];
  float* out = (float*)d_out;
  char* ws = (char*)d_ws;

  double* losspart = (double*)ws;                        // 2048 B
  int*    flagcnt  = (int*)(ws + 2048);
  float*  ss       = (float*)(ws + 4096);
  double* cb64     = (double*)(ws + 8192);               // 512 KB
  double* cbn64    = (double*)(ws + 532480);             // 8 KB
  float*  cbn32    = (float*)(ws + 540672);              // 4 KB
  unsigned short* cbh = (unsigned short*)(ws + 544768);  // 128 KB
  unsigned short* cbl = (unsigned short*)(ws + 675840);  // 128 KB
  int*    flaglist = (int*)(ws + 806912);                // 256 KB
  int*    idx      = (int*)(ws + 1069056);               // 256 KB
  double* part_e1  = (double*)(ws + 1331200);            // 128 KB
  double* part_e2  = (double*)(ws + 1462272);            // 16 KB
  float*  Ptab     = (float*)(ws + 1478656);             // 147 KB (aliases part_d1; Ptab dead before d1 writes)
  double* part_d1  = (double*)(ws + 1478656);            // 64 KB
  float*  A        = (float*)(ws + 2097152);             // 16.78 MB
  float*  B        = (float*)(ws + 18874368);            // 1 MB
  float*  Zq       = (float*)(ws + 19922944);            // 16.78 MB
  double* part_d2  = (double*)(ws + 19922944);           // 1 MB, aliases Zq (dead after postq_gather)
  float*  F        = (float*)(ws + 36700160);            // 134.2 MB
  float*  stepb    = (float*)(ws + 36700160);            // 2 MB, aliases F head (dead before d2 writes F)

  float *ss1 = ss + 0, *ss2 = ss + 32, *ss3 = ss + 48, *ss4 = ss + 80;
  float* D = B;   // B dead after preq

  prep_all<<<40, 256, 0, stream>>>(cb, cb64, cbn64, cbn32, cbh, cbl, flagcnt, postq_w, Ptab);

  // encoder
  e1_conv<<<512, 256, 0, stream>>>(x, e1_w, e1_b, A, part_e1);
  bn_red_fin<<<16, 256, 0, stream>>>(part_e1, 512, bn1_g, bn1_b, ss1, 16, 262144.0);
  e2_conv<<<256, 256, 0, stream>>>(A, e2_w, e2_b, ss1, B, part_e2);
  bn_red_fin<<<4, 256, 0, stream>>>(part_e2, 256, bn2_g, bn2_b, ss2, 4, 65536.0);
  preq_conv<<<4096, 256, 0, stream>>>(B, preq_w, preq_b, ss2, Zq);

  // VQ
  vq_screen_mfma<<<512, 256, 0, stream>>>(Zq, cbh, cbl, cbn32, idx, flagcnt, flaglist, stepb);
  vq_refine<<<128, 256, 0, stream>>>(Zq, cb64, cbn64, flagcnt, flaglist, stepb, idx);

  // decoder (postq_gather also computes VQ loss partials; Zq dead after this)
  postq_gather<<<1024, 256, 0, stream>>>(Ptab, idx, postq_b, D, Zq, cb, losspart);
  convT_w2<4, 16, 64, 64, false><<<256, 256, 0, stream>>>(D, d1_w, d1_b, nullptr, A, part_d1);
  bn_red_fin<<<16, 256, 0, stream>>>(part_d1, 256, bn3_g, bn3_b, ss3, 16, 262144.0);
  convT_w2<16, 32, 128, 128, true><<<2048, 256, 0, stream>>>(A, d2_w, d2_b, ss3, F, part_d2);
  bn_red_fin<<<32, 256, 0, stream>>>(part_d2, 2048, bn4_g, bn4_b, ss4, 32, 1048576.0);
  d3_tile<<<1024, 256, 0, stream>>>(F, d3_w, d3_b, ss4, out, losspart);
}

// Round 9
// 283.075 us; speedup vs baseline: 5.5730x; 1.0658x over previous
//
#include <hip/hip_runtime.h>
#include <math.h>

#define EPSV 1e-5
#define SLOPE 0.1f

typedef __attribute__((ext_vector_type(4))) float f32x4;
typedef __attribute__((ext_vector_type(8))) short short8x;

__device__ __forceinline__ float lrelu(float x){ return x >= 0.f ? x : SLOPE * x; }
__device__ __forceinline__ float tanh_fast(float x){
  float e = __expf(2.f * x);
  return 1.f - 2.f / (e + 1.f);
}
__device__ __forceinline__ unsigned bf16rne(float f){
  unsigned u = __float_as_uint(f);
  u += 0x7fff + ((u >> 16) & 1);
  return u >> 16;
}

// ---- block BN-stats epilogue: per-thread CL channel sums/sqs -> f64 partials ----
template<int CL>
__device__ __forceinline__ void stats_epilogue(const float* sums, const float* sqs,
    double* __restrict__ part, int chbase, int P, int p, float* sred){
  const int C2 = 2 * CL;
  int t = threadIdx.x;
  #pragma unroll
  for (int c = 0; c < CL; c++){
    sred[t * C2 + c] = sums[c];
    sred[t * C2 + CL + c] = sqs[c];
  }
  __syncthreads();
  if (t < 64){
    int c = t % C2;
    int g = t / C2;
    const int G = 64 / C2;
    const int R = 256 / G;
    double s = 0;
    for (int r = g * R; r < (g + 1) * R; r++) s += (double)sred[r * C2 + c];
    #pragma unroll
    for (int off = C2; off < 64; off <<= 1) s += __shfl_xor(s, off);
    if (t < C2){
      int ch = chbase + (c < CL ? c : c - CL);
      part[(size_t)ch * 2 * P + (c < CL ? 0 : P) + p] = s;
    }
  }
}

// ---- reduce partials + finalize scale/shift ----
__global__ __launch_bounds__(256) void bn_red_fin(const double* __restrict__ part, int P,
    const float* __restrict__ g, const float* __restrict__ b, float* __restrict__ ss, int C, double count){
  int c = blockIdx.x;
  __shared__ double r0[256], r1[256];
  int t = threadIdx.x;
  double s = 0, q = 0;
  for (int p = t; p < P; p += 256){
    s += part[(size_t)c * 2 * P + p];
    q += part[(size_t)c * 2 * P + P + p];
  }
  r0[t] = s; r1[t] = q; __syncthreads();
  for (int o = 128; o > 0; o >>= 1){
    if (t < o){ r0[t] += r0[t + o]; r1[t] += r1[t + o]; }
    __syncthreads();
  }
  if (t == 0){
    double m = r0[0] / count;
    double var = r1[0] / count - m * m;
    double scale = (double)g[c] / sqrt(var + EPSV);
    ss[c] = (float)scale;
    ss[C + c] = (float)((double)b[c] - m * scale);
  }
}

// ---------------- e1: 3->16 s2, co-split x2 (8 co/thread), 2 x-outputs, fused bn1-stats ----------------
__global__ __launch_bounds__(256) void e1_conv(const float* __restrict__ x, const float* __restrict__ w,
    const float* __restrict__ bias, float* __restrict__ out, double* __restrict__ part){
  int idx = blockIdx.x * 256 + threadIdx.x;    // 262144 = 16n x 2cog x 128oy x 64ox2
  int ox2 = idx & 63, oy = (idx >> 6) & 127;
  int cog = (idx >> 13) & 1, n = idx >> 14;
  cog = __builtin_amdgcn_readfirstlane(cog);
  n   = __builtin_amdgcn_readfirstlane(n);
  float acc[8][2];
  #pragma unroll
  for (int co = 0; co < 8; co++){ float b = bias[cog * 8 + co]; acc[co][0] = b; acc[co][1] = b; }
  int ix0 = 4 * ox2 - 1;
  int lclamp = (ox2 > 0) ? ix0 : 0;
  const float* xp = x + (size_t)n * 3 * 65536;
  #pragma unroll
  for (int ci = 0; ci < 3; ci++){
    const float* pl = xp + ci * 65536;
    #pragma unroll
    for (int ky = 0; ky < 3; ky++){
      int iy = 2 * oy - 1 + ky;
      if (iy >= 0){
        const float* row = pl + iy * 256;
        float l = row[lclamp];
        float4 m = *(const float4*)(row + ix0 + 1);
        float v0 = (ox2 > 0) ? l : 0.f;
        #pragma unroll
        for (int co = 0; co < 8; co++){
          const float* wp = w + (((cog * 8 + co) * 3 + ci) * 3 + ky) * 3;
          acc[co][0] = fmaf(v0,  wp[0], acc[co][0]);
          acc[co][0] = fmaf(m.x, wp[1], acc[co][0]);
          acc[co][0] = fmaf(m.y, wp[2], acc[co][0]);
          acc[co][1] = fmaf(m.y, wp[0], acc[co][1]);
          acc[co][1] = fmaf(m.z, wp[1], acc[co][1]);
          acc[co][1] = fmaf(m.w, wp[2], acc[co][1]);
        }
      }
    }
  }
  float sums[8], sqs[8];
  #pragma unroll
  for (int co = 0; co < 8; co++){
    float2 st; st.x = acc[co][0]; st.y = acc[co][1];
    *(float2*)(out + ((size_t)(n * 16 + cog * 8 + co) * 128 + oy) * 128 + 2 * ox2) = st;
    sums[co] = acc[co][0] + acc[co][1];
    sqs[co] = acc[co][0] * acc[co][0] + acc[co][1] * acc[co][1];
  }
  __shared__ float sred[256 * 16];
  // p unique per (channel, block): blockIdx = n*64 + cog*32 + b5 -> p = n*32 + b5 in [0,512)
  int p = ((blockIdx.x >> 6) << 5) + (blockIdx.x & 31);
  stats_epilogue<8>(sums, sqs, part, cog * 8, 512, p, sred);
}

// ---------------- e2: 16->4 s2 with fused bn1-apply on loads + bn2-stats ----------------
__global__ __launch_bounds__(256) void e2_conv(const float* __restrict__ in, const float* __restrict__ w,
    const float* __restrict__ bias, const float* __restrict__ ssIn, float* __restrict__ out,
    double* __restrict__ part){
  int idx = blockIdx.x * 256 + threadIdx.x;
  int ox = idx & 63, oy = (idx >> 6) & 63, n = idx >> 12;
  float acc[4];
  #pragma unroll
  for (int j = 0; j < 4; j++) acc[j] = bias[j];
  int iy0 = oy * 2 - 1, ix0 = ox * 2 - 1;
  const float* ip = in + (size_t)n * 16 * 16384;
  #pragma unroll
  for (int ky = 0; ky < 3; ky++){
    int iy = iy0 + ky; if ((unsigned)iy >= 128u) continue;
    #pragma unroll
    for (int kx = 0; kx < 3; kx++){
      int ix = ix0 + kx; if ((unsigned)ix >= 128u) continue;
      const float* r = ip + iy * 128 + ix;
      #pragma unroll
      for (int ci = 0; ci < 16; ci++){
        float v = lrelu(fmaf(r[ci * 16384], ssIn[ci], ssIn[16 + ci]));
        #pragma unroll
        for (int co = 0; co < 4; co++)
          acc[co] = fmaf(v, w[(co * 16 + ci) * 9 + ky * 3 + kx], acc[co]);
      }
    }
  }
  float sums[4], sqs[4];
  #pragma unroll
  for (int co = 0; co < 4; co++){
    out[(((size_t)n * 4 + co) * 64 + oy) * 64 + ox] = acc[co];
    sums[co] = acc[co];
    sqs[co] = acc[co] * acc[co];
  }
  __shared__ float sred[256 * 8];
  stats_epilogue<4>(sums, sqs, part, 0, 256, blockIdx.x, sred);
}

// ---------------- preq: fused bn2-apply, output plane layout Zq[coq][pos][4] ----------------
__global__ __launch_bounds__(256) void preq_conv(const float* __restrict__ in, const float* __restrict__ w,
    const float* __restrict__ bias, const float* __restrict__ ssIn, float* __restrict__ Zq){
  int idx = blockIdx.x * 256 + threadIdx.x;
  int sp = idx & 65535;
  int coq = idx >> 16;
  int x = sp & 63, y = (sp >> 6) & 63, n = sp >> 12;
  float scv[4] = {ssIn[0], ssIn[1], ssIn[2], ssIn[3]};
  float shv[4] = {ssIn[4], ssIn[5], ssIn[6], ssIn[7]};
  float a0 = bias[coq * 4 + 0], a1 = bias[coq * 4 + 1], a2 = bias[coq * 4 + 2], a3 = bias[coq * 4 + 3];
  const float* ip = in + (size_t)n * 4 * 4096;
  #pragma unroll
  for (int ky = 0; ky < 3; ky++){
    int iy = y - 1 + ky; if ((unsigned)iy >= 64u) continue;
    #pragma unroll
    for (int kx = 0; kx < 3; kx++){
      int ix = x - 1 + kx; if ((unsigned)ix >= 64u) continue;
      #pragma unroll
      for (int ci = 0; ci < 4; ci++){
        float v = lrelu(fmaf(ip[ci * 4096 + iy * 64 + ix], scv[ci], shv[ci]));
        const float* wp = w + ((coq * 4) * 4 + ci) * 9 + ky * 3 + kx;
        a0 = fmaf(v, wp[0], a0);
        a1 = fmaf(v, wp[36], a1);
        a2 = fmaf(v, wp[72], a2);
        a3 = fmaf(v, wp[108], a3);
      }
    }
  }
  float4 o; o.x = a0; o.y = a1; o.z = a2; o.w = a3;
  ((float4*)Zq)[coq * 65536 + sp] = o;
}

// ---------------- prep_all: blocks 0-3 VQ codebook prep, blocks 4-39 postq P-table ----------------
__global__ __launch_bounds__(256) void prep_all(const float* __restrict__ cb, double* __restrict__ cb64,
    double* __restrict__ cbn64, float* __restrict__ cbn32, unsigned short* __restrict__ cbh,
    unsigned short* __restrict__ cbl, int* __restrict__ flagcnt,
    const float* __restrict__ pw, float* __restrict__ P){
  int t = threadIdx.x;
  if (blockIdx.x < 4){
    int k = blockIdx.x * 256 + t;
    if (k == 0) flagcnt[0] = 0;
    double s = 0;
    for (int d = 0; d < 64; d++){
      float v = cb[k * 64 + d];
      cb64[(size_t)k * 64 + d] = (double)v;
      s = fma((double)v, (double)v, s);
      unsigned h = bf16rne(v);
      float hf = __uint_as_float(h << 16);
      unsigned l = bf16rne(v - hf);
      cbh[k * 64 + d] = (unsigned short)h;
      cbl[k * 64 + d] = (unsigned short)l;
    }
    cbn64[k] = s;
    cbn32[k] = (float)s;
  } else {
    int gid = (blockIdx.x - 4) * 256 + t;
    if (gid >= 9216) return;
    int k = gid / 9, tap = gid - k * 9;
    float a0 = 0.f, a1 = 0.f, a2 = 0.f, a3 = 0.f;
    const float* cp = cb + (k << 6);
    #pragma unroll 16
    for (int ci = 0; ci < 64; ci++){
      float c = cp[ci];
      a0 = fmaf(c, pw[(0 * 64 + ci) * 9 + tap], a0);
      a1 = fmaf(c, pw[(1 * 64 + ci) * 9 + tap], a1);
      a2 = fmaf(c, pw[(2 * 64 + ci) * 9 + tap], a2);
      a3 = fmaf(c, pw[(3 * 64 + ci) * 9 + tap], a3);
    }
    float4 o; o.x = a0; o.y = a1; o.z = a2; o.w = a3;
    ((float4*)P)[gid] = o;
  }
}

// ---------------- VQ screen via MFMA: per-step (128-code) partial bests + global merge ----------------
__global__ __launch_bounds__(256) void vq_screen_mfma(const float* __restrict__ Zq,
    const unsigned short* __restrict__ cbh, const unsigned short* __restrict__ cbl,
    const float* __restrict__ cbn32, int* __restrict__ idxout,
    int* __restrict__ flagcnt, int* __restrict__ flaglist, float* __restrict__ stepb){
  __shared__ unsigned short lcb[32 * 64 * 8];
  __shared__ float lcn[128];
  int t = threadIdx.x;
  int lane = t & 63;
  int w = t >> 6;
  int col = lane & 15, hg = lane >> 4;
  int pos0 = blockIdx.x * 128 + w * 32;
  int posA = pos0 + col, posB = pos0 + 16 + col;
  const float4* Zq4 = (const float4*)Zq;
  short8x zhA[2], zlA[2], zhB[2], zlB[2];
  #pragma unroll
  for (int kc = 0; kc < 2; kc++){
    #pragma unroll
    for (int tb = 0; tb < 2; tb++){
      int pos = tb ? posB : posA;
      float4 f0 = Zq4[(size_t)(8 * kc + 2 * hg) * 65536 + pos];
      float4 f1 = Zq4[(size_t)(8 * kc + 2 * hg + 1) * 65536 + pos];
      float zv[8] = {f0.x, f0.y, f0.z, f0.w, f1.x, f1.y, f1.z, f1.w};
      union { unsigned u[4]; short8x v; } H, L;
      #pragma unroll
      for (int j = 0; j < 4; j++){
        unsigned h0 = bf16rne(zv[2 * j]);
        unsigned h1 = bf16rne(zv[2 * j + 1]);
        float hf0 = __uint_as_float(h0 << 16);
        float hf1 = __uint_as_float(h1 << 16);
        unsigned l0 = bf16rne(zv[2 * j] - hf0);
        unsigned l1 = bf16rne(zv[2 * j + 1] - hf1);
        H.u[j] = h0 | (h1 << 16);
        L.u[j] = l0 | (l1 << 16);
      }
      if (tb){ zhB[kc] = H.v; zlB[kc] = L.v; } else { zhA[kc] = H.v; zlA[kc] = L.v; }
    }
  }
  float BA = 3.0e38f, SA = 3.0e38f, BB = 3.0e38f, SBt = 3.0e38f;
  int IA = 0, IB = 0;
  for (int step = 0; step < 8; step++){
    int code0 = step * 128;
    __syncthreads();
    #pragma unroll
    for (int i = 0; i < 8; i++){
      int piece = i * 256 + t;
      int fb = piece >> 6, pl = piece & 63;
      int g = fb >> 2, kc = (fb >> 1) & 1, sp = fb & 1;
      const unsigned short* src = (sp ? cbl : cbh)
          + ((size_t)(code0 + g * 16 + (pl & 15)) << 6) + kc * 32 + ((pl >> 4) << 3);
      *(uint4*)&lcb[piece * 8] = *(const uint4*)src;
    }
    if (t < 128) lcn[t] = cbn32[code0 + t];
    __syncthreads();
    float bA = 3.0e38f, sA = 3.0e38f, bB = 3.0e38f, sB = 3.0e38f;
    int iA = 0, iB = 0;
    #pragma unroll 2
    for (int g = 0; g < 8; g++){
      const short8x* lc8 = (const short8x*)lcb;
      short8x Ah0 = lc8[(g * 4 + 0) * 64 + lane];
      short8x Al0 = lc8[(g * 4 + 1) * 64 + lane];
      short8x Ah1 = lc8[(g * 4 + 2) * 64 + lane];
      short8x Al1 = lc8[(g * 4 + 3) * 64 + lane];
      f32x4 accA = {0.f, 0.f, 0.f, 0.f};
      f32x4 accB = {0.f, 0.f, 0.f, 0.f};
      accA = __builtin_amdgcn_mfma_f32_16x16x32_bf16(Ah0, zhA[0], accA, 0, 0, 0);
      accA = __builtin_amdgcn_mfma_f32_16x16x32_bf16(Ah1, zhA[1], accA, 0, 0, 0);
      accA = __builtin_amdgcn_mfma_f32_16x16x32_bf16(Ah0, zlA[0], accA, 0, 0, 0);
      accA = __builtin_amdgcn_mfma_f32_16x16x32_bf16(Ah1, zlA[1], accA, 0, 0, 0);
      accA = __builtin_amdgcn_mfma_f32_16x16x32_bf16(Al0, zhA[0], accA, 0, 0, 0);
      accA = __builtin_amdgcn_mfma_f32_16x16x32_bf16(Al1, zhA[1], accA, 0, 0, 0);
      accB = __builtin_amdgcn_mfma_f32_16x16x32_bf16(Ah0, zhB[0], accB, 0, 0, 0);
      accB = __builtin_amdgcn_mfma_f32_16x16x32_bf16(Ah1, zhB[1], accB, 0, 0, 0);
      accB = __builtin_amdgcn_mfma_f32_16x16x32_bf16(Ah0, zlB[0], accB, 0, 0, 0);
      accB = __builtin_amdgcn_mfma_f32_16x16x32_bf16(Ah1, zlB[1], accB, 0, 0, 0);
      accB = __builtin_amdgcn_mfma_f32_16x16x32_bf16(Al0, zhB[0], accB, 0, 0, 0);
      accB = __builtin_amdgcn_mfma_f32_16x16x32_bf16(Al1, zhB[1], accB, 0, 0, 0);
      int cbase = code0 + g * 16 + 4 * hg;
      #pragma unroll
      for (int r = 0; r < 4; r++){
        float cn = lcn[g * 16 + 4 * hg + r];
        float vA = fmaf(accA[r], -2.0f, cn);
        sA = fminf(sA, fmaxf(vA, bA));
        if (vA < bA){ bA = vA; iA = cbase + r; }
        float vB = fmaf(accB[r], -2.0f, cn);
        sB = fminf(sB, fmaxf(vB, bB));
        if (vB < bB){ bB = vB; iB = cbase + r; }
      }
    }
    #pragma unroll
    for (int off = 16; off <= 32; off <<= 1){
      float ob = __shfl_xor(bA, off);
      float os = __shfl_xor(sA, off);
      int oi = __shfl_xor(iA, off);
      sA = fminf(fminf(sA, os), fmaxf(bA, ob));
      if (ob < bA){ bA = ob; iA = oi; }
      ob = __shfl_xor(bB, off);
      os = __shfl_xor(sB, off);
      oi = __shfl_xor(iB, off);
      sB = fminf(fminf(sB, os), fmaxf(bB, ob));
      if (ob < bB){ bB = ob; iB = oi; }
    }
    if (hg == 0){
      stepb[step * 65536 + posA] = bA;
      stepb[step * 65536 + posB] = bB;
    }
    if (bA < BA){ SA = fminf(BA, sA); BA = bA; IA = iA; } else SA = fminf(SA, bA);
    if (bB < BB){ SBt = fminf(BB, sB); BB = bB; IB = iB; } else SBt = fminf(SBt, bB);
  }
  if (hg == 0){
    idxout[posA] = IA;
    if (SA - BA < 1.2e-2f){
      int slot = atomicAdd(flagcnt, 1);
      flaglist[slot] = posA;
    }
    idxout[posB] = IB;
    if (SBt - BB < 1.2e-2f){
      int slot = atomicAdd(flagcnt, 1);
      flaglist[slot] = posB;
    }
  }
}

// ---------------- VQ refine: exact f64 re-rank over candidate steps only ----------------
__global__ __launch_bounds__(256) void vq_refine(const float* __restrict__ Zq, const double* __restrict__ cb64,
    const double* __restrict__ cbn64, const int* __restrict__ flagcnt, const int* __restrict__ flaglist,
    const float* __restrict__ stepb, int* __restrict__ idxout){
  int gw = (blockIdx.x * 256 + threadIdx.x) >> 6;
  int lane = threadIdx.x & 63;
  int nf = flagcnt[0];
  for (int f = gw; f < nf; f += 512){
    int pos = flaglist[f];
    float zr[64];
    #pragma unroll
    for (int q = 0; q < 16; q++){
      float4 v = ((const float4*)Zq)[q * 65536 + pos];
      zr[4 * q] = v.x; zr[4 * q + 1] = v.y; zr[4 * q + 2] = v.z; zr[4 * q + 3] = v.w;
    }
    float sb[8];
    float B = 3.0e38f;
    #pragma unroll
    for (int s = 0; s < 8; s++){ sb[s] = stepb[s * 65536 + pos]; B = fminf(B, sb[s]); }
    float lim = B + 1.2e-2f;
    double best = 1e300; int bi = 1 << 30;
    #pragma unroll
    for (int s = 0; s < 8; s++){
      if (sb[s] < lim){
        int k0 = s * 128 + 2 * lane;
        #pragma unroll
        for (int kk = 0; kk < 2; kk++){
          int k = k0 + kk;
          const double* c = cb64 + (size_t)k * 64;
          double a0 = 0, a1 = 0, a2 = 0, a3 = 0;
          #pragma unroll
          for (int d = 0; d < 64; d += 4){
            a0 = fma(c[d], (double)zr[d], a0);
            a1 = fma(c[d + 1], (double)zr[d + 1], a1);
            a2 = fma(c[d + 2], (double)zr[d + 2], a2);
            a3 = fma(c[d + 3], (double)zr[d + 3], a3);
          }
          double sc = cbn64[k] - 2.0 * ((a0 + a1) + (a2 + a3));
          if (sc < best){ best = sc; bi = k; }
        }
      }
    }
    #pragma unroll
    for (int o = 32; o > 0; o >>= 1){
      double ob = __shfl_xor(best, o);
      int oi = __shfl_xor(bi, o);
      if (ob < best || (ob == best && oi < bi)){ best = ob; bi = oi; }
    }
    if (lane == 0) idxout[pos] = bi;
  }
}

// ---------------- postq gather: out[pos][co] = bias + sum_tap P[idx[nbr]][tap][co]; fused loss ----------------
__global__ __launch_bounds__(256) void postq_gather(const float* __restrict__ P, const int* __restrict__ idxm,
    const float* __restrict__ bias, float* __restrict__ out,
    const float* __restrict__ Zq, const float* __restrict__ cb, double* __restrict__ losspart){
  int gid = blockIdx.x * 256 + threadIdx.x;
  int sp = gid & 65535;
  int co = gid >> 16;
  co = __builtin_amdgcn_readfirstlane(co);
  int xx = sp & 63, yy = (sp >> 6) & 63, n = sp >> 12;
  float acc = bias[co];
  #pragma unroll
  for (int ky = 0; ky < 3; ky++){
    int iy = yy - 1 + ky; if ((unsigned)iy >= 64u) continue;
    #pragma unroll
    for (int kx = 0; kx < 3; kx++){
      int ix = xx - 1 + kx; if ((unsigned)ix >= 64u) continue;
      int spt = (n << 12) + (iy << 6) + ix;
      int k = idxm[spt];
      acc += P[(k * 9 + (ky * 3 + kx)) * 4 + co];
    }
  }
  out[((size_t)(n * 4 + co) << 12) + (yy << 6) + xx] = acc;
  if (co == 0){
    int k = idxm[sp];
    const float4* c4 = (const float4*)(cb + (k << 6));
    double l = 0;
    #pragma unroll
    for (int q = 0; q < 16; q++){
      float4 z = ((const float4*)Zq)[q * 65536 + sp];
      float4 c = c4[q];
      float d0 = z.x - c.x, d1 = z.y - c.y, d2 = z.z - c.z, d3 = z.w - c.w;
      l += (double)d0 * d0 + (double)d1 * d1 + (double)d2 * d2 + (double)d3 * d3;
    }
    __shared__ double sb[256];
    int t = threadIdx.x;
    sb[t] = l; __syncthreads();
    for (int o = 128; o > 0; o >>= 1){
      if (t < o) sb[t] += sb[t + o];
      __syncthreads();
    }
    if (t == 0) losspart[blockIdx.x] = sb[0];
  }
}

// ---------------- transposed conv k3 s2 p1 op1, 8 co/thread, optional input-BN, fused stats ----------------
template<int CI, int CO, int IHt, int IWt, bool APPLY>
__global__ __launch_bounds__(256) void convT_cob8(const float* __restrict__ in, const float* __restrict__ w,
    const float* __restrict__ bias, const float* __restrict__ ssIn, float* __restrict__ out,
    double* __restrict__ part){
  constexpr int SB = IHt * IWt / 256;
  constexpr int COG = CO / 8;
  constexpr int P = 16 * SB;
  const int OW = IWt * 2;
  int idx = blockIdx.x * 256 + threadIdx.x;
  int ix = idx % IWt, iy = (idx / IWt) % IHt;
  int cog = (idx / (IWt * IHt)) % COG, n = idx / (IWt * IHt * COG);
  cog = __builtin_amdgcn_readfirstlane(cog);
  n   = __builtin_amdgcn_readfirstlane(n);
  float a00[8], a01[8], a10[8], a11[8];
  #pragma unroll
  for (int j = 0; j < 8; j++){ float b = bias[cog * 8 + j]; a00[j] = b; a01[j] = b; a10[j] = b; a11[j] = b; }
  bool okx = (ix + 1 < IWt), oky = (iy + 1 < IHt);
  int ixp = okx ? ix + 1 : ix, iyp = oky ? iy + 1 : iy;
  const float* ip = in + (size_t)n * CI * IHt * IWt;
  #pragma unroll 4
  for (int ci = 0; ci < CI; ci++){
    const float* p = ip + ci * IHt * IWt;
    float v00 = p[iy * IWt + ix];
    float v01 = p[iy * IWt + ixp];
    float v10 = p[iyp * IWt + ix];
    float v11 = p[iyp * IWt + ixp];
    if (APPLY){
      float sc = ssIn[ci], sh = ssIn[CI + ci];
      v00 = lrelu(fmaf(v00, sc, sh));
      v01 = lrelu(fmaf(v01, sc, sh));
      v10 = lrelu(fmaf(v10, sc, sh));
      v11 = lrelu(fmaf(v11, sc, sh));
    }
    if (!okx) v01 = 0.f;
    if (!oky) v10 = 0.f;
    if (!(okx && oky)) v11 = 0.f;
    const float* wp = w + ((size_t)ci * CO + cog * 8) * 9;
    #pragma unroll
    for (int j = 0; j < 8; j++){
      const float* q = wp + j * 9;
      a00[j] = fmaf(q[4], v00, a00[j]);
      a01[j] = fmaf(q[3], v01, a01[j]); a01[j] = fmaf(q[5], v00, a01[j]);
      a10[j] = fmaf(q[1], v10, a10[j]); a10[j] = fmaf(q[7], v00, a10[j]);
      a11[j] = fmaf(q[0], v11, a11[j]); a11[j] = fmaf(q[2], v10, a11[j]);
      a11[j] = fmaf(q[6], v01, a11[j]); a11[j] = fmaf(q[8], v00, a11[j]);
    }
  }
  float sums[8], sqs[8];
  #pragma unroll
  for (int j = 0; j < 8; j++){
    float* o = out + (((size_t)n * CO + cog * 8 + j) * (IHt * 2) + 2 * iy) * OW + 2 * ix;
    float2 r0; r0.x = a00[j]; r0.y = a01[j];
    float2 r1; r1.x = a10[j]; r1.y = a11[j];
    *(float2*)o = r0;
    *(float2*)(o + OW) = r1;
    sums[j] = (a00[j] + a01[j]) + (a10[j] + a11[j]);
    sqs[j] = (a00[j] * a00[j] + a01[j] * a01[j]) + (a10[j] * a10[j] + a11[j] * a11[j]);
  }
  __shared__ float sred[256 * 16];
  int sb = blockIdx.x % SB;
  stats_epilogue<8>(sums, sqs, part, cog * 8, P, n * SB + sb, sred);
}

// ---------------- d3: 32->3 @256x256, LDS-tiled (24 KB), fused bn4 + loss write ----------------
__global__ __launch_bounds__(256) void d3_tile(const float* __restrict__ F, const float* __restrict__ w,
    const float* __restrict__ bias, const float* __restrict__ ss, float* __restrict__ out,
    const double* __restrict__ losspart){
  __shared__ float st[4 * 6 * 256];
  int t = threadIdx.x;
  int xg = t & 63, r = t >> 6;
  int n = blockIdx.x >> 6, oyb = blockIdx.x & 63;
  int oy = oyb * 4 + r;
  if (blockIdx.x == 0 && t < 64){
    double s = losspart[t] + losspart[t + 64] + losspart[t + 128] + losspart[t + 192];
    #pragma unroll
    for (int o = 32; o > 0; o >>= 1) s += __shfl_xor(s, o);
    if (t == 0) out[3145728] = (float)(1.25 * s / (65536.0 * 64.0));
  }
  float acc[3][4];
  #pragma unroll
  for (int co = 0; co < 3; co++){
    float b = bias[co];
    #pragma unroll
    for (int j = 0; j < 4; j++) acc[co][j] = b;
  }
  const float* base = F + (size_t)n * 32 * 65536;
  for (int cc = 0; cc < 8; cc++){
    int cib = cc * 4;
    #pragma unroll
    for (int j = 0; j < 6; j++){
      int p = j * 256 + t;
      int cl = p / 384, rem = p - cl * 384;
      int rr = rem >> 6, xq = rem & 63;
      int g = oyb * 4 - 1 + rr;
      float4 v;
      if ((unsigned)g < 256u){
        v = *(const float4*)(base + ((size_t)(cib + cl) * 256 + g) * 256 + 4 * xq);
        float sc = ss[cib + cl], sh = ss[32 + cib + cl];
        v.x = lrelu(fmaf(v.x, sc, sh));
        v.y = lrelu(fmaf(v.y, sc, sh));
        v.z = lrelu(fmaf(v.z, sc, sh));
        v.w = lrelu(fmaf(v.w, sc, sh));
      } else {
        v.x = 0.f; v.y = 0.f; v.z = 0.f; v.w = 0.f;
      }
      *(float4*)&st[((cl * 6 + rr) << 8) | (4 * xq)] = v;
    }
    __syncthreads();
    #pragma unroll
    for (int cl = 0; cl < 4; cl++){
      #pragma unroll
      for (int ky = 0; ky < 3; ky++){
        int rr = r + ky;
        float4 A = *(const float4*)&st[((cl * 6 + rr) << 8) | (4 * xg)];
        float Lv = __shfl_up(A.w, 1);
        float Rv = __shfl_down(A.x, 1);
        float u0 = (xg == 0) ? 0.f : Lv;
        float u5 = (xg == 63) ? 0.f : Rv;
        float u[6] = {u0, A.x, A.y, A.z, A.w, u5};
        #pragma unroll
        for (int co = 0; co < 3; co++){
          const float* wp = w + ((co * 32 + cib + cl) * 9) + ky * 3;
          #pragma unroll
          for (int j = 0; j < 4; j++){
            acc[co][j] = fmaf(u[j],     wp[0], acc[co][j]);
            acc[co][j] = fmaf(u[j + 1], wp[1], acc[co][j]);
            acc[co][j] = fmaf(u[j + 2], wp[2], acc[co][j]);
          }
        }
      }
    }
    __syncthreads();
  }
  #pragma unroll
  for (int co = 0; co < 3; co++){
    float4 s0;
    s0.x = tanh_fast(acc[co][0]); s0.y = tanh_fast(acc[co][1]);
    s0.z = tanh_fast(acc[co][2]); s0.w = tanh_fast(acc[co][3]);
    float* o = out + ((size_t)(n * 3 + co) * 256 + oy) * 256 + 4 * xg;
    *(float4*)o = s0;
  }
}

// ---------------- launch ----------------
extern "C" void kernel_launch(void* const* d_in, const int* in_sizes, int n_in,
                              void* d_out, int out_size, void* d_ws, size_t ws_size,
                              hipStream_t stream){
  const float* x      = (const float*)d_in[0];
  const float* cb     = (const float*)d_in[1];
  const float* e1_w   = (const float*)d_in[2];
  const float* e1_b   = (const float*)d_in[3];
  const float* bn1_g  = (const float*)d_in[4];
  const float* bn1_b  = (const float*)d_in[5];
  const float* e2_w   = (const float*)d_in[6];
  const float* e2_b   = (const float*)d_in[7];
  const float* bn2_g  = (const float*)d_in[8];
  const float* bn2_b  = (const float*)d_in[9];
  const float* preq_w = (const float*)d_in[10];
  const float* preq_b = (const float*)d_in[11];
  const float* postq_w= (const float*)d_in[12];
  const float* postq_b= (const float*)d_in[13];
  const float* d1_w   = (const float*)d_in[14];
  const float* d1_b   = (const float*)d_in[15];
  const float* bn3_g  = (const float*)d_in[16];
  const float* bn3_b  = (const float*)d_in[17];
  const float* d2_w   = (const float*)d_in[18];
  const float* d2_b   = (const float*)d_in[19];
  const float* bn4_g  = (const float*)d_in[20];
  const float* bn4_b  = (const float*)d_in[21];
  const float* d3_w   = (const float*)d_in[22];
  const float* d3_b   = (const float*)d_in[23];
  float* out = (float*)d_out;
  char* ws = (char*)d_ws;

  double* losspart = (double*)ws;                        // 2048 B
  int*    flagcnt  = (int*)(ws + 2048);
  float*  ss       = (float*)(ws + 4096);
  double* cb64     = (double*)(ws + 8192);               // 512 KB
  double* cbn64    = (double*)(ws + 532480);             // 8 KB
  float*  cbn32    = (float*)(ws + 540672);              // 4 KB
  unsigned short* cbh = (unsigned short*)(ws + 544768);  // 128 KB
  unsigned short* cbl = (unsigned short*)(ws + 675840);  // 128 KB
  int*    flaglist = (int*)(ws + 806912);                // 256 KB
  int*    idx      = (int*)(ws + 1069056);               // 256 KB
  double* part_e1  = (double*)(ws + 1331200);            // 128 KB (16ch x 2 x 512)
  double* part_e2  = (double*)(ws + 1462272);            // 16 KB
  float*  Ptab     = (float*)(ws + 1478656);             // 147 KB (aliases part_d1; Ptab dead before d1 writes)
  double* part_d1  = (double*)(ws + 1478656);            // 64 KB
  float*  A        = (float*)(ws + 2097152);             // 16.78 MB
  float*  B        = (float*)(ws + 18874368);            // 1 MB
  float*  Zq       = (float*)(ws + 19922944);            // 16.78 MB
  double* part_d2  = (double*)(ws + 19922944);           // 512 KB, aliases Zq (dead after postq_gather)
  float*  F        = (float*)(ws + 36700160);            // 134.2 MB
  float*  stepb    = (float*)(ws + 36700160);            // 2 MB, aliases F head (dead before d2 writes F)

  float *ss1 = ss + 0, *ss2 = ss + 32, *ss3 = ss + 48, *ss4 = ss + 80;
  float* D = B;   // B dead after preq

  prep_all<<<40, 256, 0, stream>>>(cb, cb64, cbn64, cbn32, cbh, cbl, flagcnt, postq_w, Ptab);

  // encoder
  e1_conv<<<1024, 256, 0, stream>>>(x, e1_w, e1_b, A, part_e1);
  bn_red_fin<<<16, 256, 0, stream>>>(part_e1, 512, bn1_g, bn1_b, ss1, 16, 262144.0);
  e2_conv<<<256, 256, 0, stream>>>(A, e2_w, e2_b, ss1, B, part_e2);
  bn_red_fin<<<4, 256, 0, stream>>>(part_e2, 256, bn2_g, bn2_b, ss2, 4, 65536.0);
  preq_conv<<<4096, 256, 0, stream>>>(B, preq_w, preq_b, ss2, Zq);

  // VQ
  vq_screen_mfma<<<512, 256, 0, stream>>>(Zq, cbh, cbl, cbn32, idx, flagcnt, flaglist, stepb);
  vq_refine<<<128, 256, 0, stream>>>(Zq, cb64, cbn64, flagcnt, flaglist, stepb, idx);

  // decoder (postq_gather also computes VQ loss partials; Zq dead after this)
  postq_gather<<<1024, 256, 0, stream>>>(Ptab, idx, postq_b, D, Zq, cb, losspart);
  convT_cob8<4, 16, 64, 64, false><<<512, 256, 0, stream>>>(D, d1_w, d1_b, nullptr, A, part_d1);
  bn_red_fin<<<16, 256, 0, stream>>>(part_d1, 256, bn3_g, bn3_b, ss3, 16, 262144.0);
  convT_cob8<16, 32, 128, 128, true><<<4096, 256, 0, stream>>>(A, d2_w, d2_b, ss3, F, part_d2);
  bn_red_fin<<<32, 256, 0, stream>>>(part_d2, 1024, bn4_g, bn4_b, ss4, 32, 1048576.0);
  d3_tile<<<1024, 256, 0, stream>>>(F, d3_w, d3_b, ss4, out, losspart);
}